// Round 2
// baseline (905.672 us; speedup 1.0000x reference)
//
#include <hip/hip_runtime.h>

#define NN 50000
#define NE 800000
#define FIN 128
#define FH 256
#define FOUT 40
#define NPAD 50432   // > NN+1, multiple of 64

// ---------------- CSR build: histogram, inv-sqrt degree, scan, fill ----------------

__global__ void cnt_zero_kernel(int* __restrict__ cnt) {
    int i = blockIdx.x * 256 + threadIdx.x;
    if (i < NN) cnt[i] = 0;
}

__global__ void cnt_count_kernel(int* __restrict__ cnt, const int* __restrict__ dst) {
    int e = blockIdx.x * 256 + threadIdx.x;
    if (e < NE) atomicAdd(&cnt[dst[e]], 1);
}

__global__ void inv_kernel(const int* __restrict__ cnt, float* __restrict__ inv) {
    int i = blockIdx.x * 256 + threadIdx.x;
    if (i < NN) inv[i] = rsqrtf((float)(cnt[i] + 1));   // +1 self-loop
}

// Single-block exclusive scan over cnt[NN] -> row_start, cursor.
__global__ __launch_bounds__(1024) void scan_kernel(const int* __restrict__ cnt,
                                                    int* __restrict__ row_start,
                                                    int* __restrict__ cursor) {
    __shared__ int part[1024];
    const int t = threadIdx.x;
    const int CH = (NN + 1023) / 1024;   // 49
    int lo = t * CH;
    int hi = lo + CH; if (hi > NN) hi = NN;
    int s = 0;
    for (int i = lo; i < hi; ++i) s += cnt[i];
    part[t] = s;
    __syncthreads();
    // in-place inclusive Hillis-Steele scan
    for (int off = 1; off < 1024; off <<= 1) {
        int v = (t >= off) ? part[t - off] : 0;
        __syncthreads();
        part[t] += v;
        __syncthreads();
    }
    int base = part[t] - s;   // exclusive prefix for this chunk
    for (int i = lo; i < hi; ++i) {
        row_start[i] = base;
        cursor[i]    = base;
        base += cnt[i];
    }
    if (t == 0) row_start[NN] = NE;
}

// edata[pos] = {src index (bitcast), coef = inv[s]*inv[d]} sorted by dst.
__global__ void fill_kernel(const int* __restrict__ src, const int* __restrict__ dst,
                            const float* __restrict__ inv,
                            int* __restrict__ cursor, float2* __restrict__ edata) {
    int e = blockIdx.x * 256 + threadIdx.x;
    if (e >= NE) return;
    int s = src[e];
    int d = dst[e];
    int pos = atomicAdd(&cursor[d], 1);
    edata[pos] = make_float2(__int_as_float(s), inv[s] * inv[d]);
}

// ---------------- GEMM: C[M,N] = (relu?)A[M,K] @ B[K,N] ----------------
// BM=BN=128, BK=16, 256 threads, 8x8 microtile per thread.

template<bool RELU_IN>
__global__ __launch_bounds__(256, 2) void gemm_kernel(const float* __restrict__ A,
                                                      const float* __restrict__ B,
                                                      float* __restrict__ C,
                                                      int M, int K, int N) {
    __shared__ float As[16][132];  // [k][m]; pad 132 -> 2-way max on scatter writes (free)
    __shared__ float Bs[16][132];  // [k][n]

    const int tid = threadIdx.x;
    const int tx = tid & 15;       // 0..15 -> col group (8 cols each)
    const int ty = tid >> 4;       // 0..15 -> row group (8 rows each)
    const int row0 = blockIdx.x * 128;
    const int col0 = blockIdx.y * 128;

    float acc[8][8] = {};

    for (int k0 = 0; k0 < K; k0 += 16) {
        // A tile: 128 rows x 16 k. Each thread loads two float4 along K.
        {
            int r  = tid >> 2;            // 0..63
            int kc = (tid & 3) * 4;       // 0,4,8,12
            #pragma unroll
            for (int h = 0; h < 2; ++h) {
                int rr = r + h * 64;
                int grow = row0 + rr;
                float4 v = make_float4(0.f, 0.f, 0.f, 0.f);
                if (grow < M)
                    v = *reinterpret_cast<const float4*>(A + (size_t)grow * K + k0 + kc);
                if (RELU_IN) {
                    v.x = fmaxf(v.x, 0.f); v.y = fmaxf(v.y, 0.f);
                    v.z = fmaxf(v.z, 0.f); v.w = fmaxf(v.w, 0.f);
                }
                As[kc + 0][rr] = v.x;
                As[kc + 1][rr] = v.y;
                As[kc + 2][rr] = v.z;
                As[kc + 3][rr] = v.w;
            }
        }
        // B tile: 16 k x 128 n. Each thread loads two adjacent float4 along N.
        {
            int kr = tid >> 4;            // 0..15
            int nc = (tid & 15) * 8;      // 0..120
            const float* bp = B + (size_t)(k0 + kr) * N + col0 + nc;
            float4 u0 = *reinterpret_cast<const float4*>(bp);
            float4 u1 = *reinterpret_cast<const float4*>(bp + 4);
            *reinterpret_cast<float4*>(&Bs[kr][nc])     = u0;
            *reinterpret_cast<float4*>(&Bs[kr][nc + 4]) = u1;
        }
        __syncthreads();

        #pragma unroll
        for (int kk = 0; kk < 16; ++kk) {
            float4 a0 = *reinterpret_cast<const float4*>(&As[kk][ty * 8]);
            float4 a1 = *reinterpret_cast<const float4*>(&As[kk][ty * 8 + 4]);
            float4 b0 = *reinterpret_cast<const float4*>(&Bs[kk][tx * 8]);
            float4 b1 = *reinterpret_cast<const float4*>(&Bs[kk][tx * 8 + 4]);
            float a[8] = {a0.x, a0.y, a0.z, a0.w, a1.x, a1.y, a1.z, a1.w};
            float b[8] = {b0.x, b0.y, b0.z, b0.w, b1.x, b1.y, b1.z, b1.w};
            #pragma unroll
            for (int i = 0; i < 8; ++i)
                #pragma unroll
                for (int j = 0; j < 8; ++j)
                    acc[i][j] += a[i] * b[j];
        }
        __syncthreads();
    }

    #pragma unroll
    for (int i = 0; i < 8; ++i) {
        int gr = row0 + ty * 8 + i;
        if (gr < M) {
            float* cp = C + (size_t)gr * N + col0 + tx * 8;
            float4 o0 = make_float4(acc[i][0], acc[i][1], acc[i][2], acc[i][3]);
            float4 o1 = make_float4(acc[i][4], acc[i][5], acc[i][6], acc[i][7]);
            *reinterpret_cast<float4*>(cp)     = o0;
            *reinterpret_cast<float4*>(cp + 4) = o1;
        }
    }
}

// ---------------- gather: agg[d,:] = sum_e lin[src,:]*coef + lin[d,:]*inv[d]^2 + bias ----------------
// One wave per destination node; lane handles 4 consecutive features (64*4 = 256).
// Edge loop unrolled x4 with independent accumulators for memory-level parallelism.

__global__ __launch_bounds__(256) void gather_kernel(const float* __restrict__ lin,
                                                     const float2* __restrict__ edata,
                                                     const int* __restrict__ row_start,
                                                     const float* __restrict__ inv,
                                                     const float* __restrict__ bias,
                                                     float* __restrict__ out) {
    int node = blockIdx.x * 4 + (threadIdx.x >> 6);
    int lane = threadIdx.x & 63;
    if (node >= NN) return;

    int beg = row_start[node];
    int end = row_start[node + 1];

    float iv = inv[node];
    float c  = iv * iv;                           // self-loop weight 1/deg
    float4 v = *reinterpret_cast<const float4*>(lin + (size_t)node * FH + lane * 4);
    float4 b = *reinterpret_cast<const float4*>(bias + lane * 4);
    float4 a0 = make_float4(v.x * c + b.x, v.y * c + b.y, v.z * c + b.z, v.w * c + b.w);
    float4 a1 = make_float4(0.f, 0.f, 0.f, 0.f);
    float4 a2 = make_float4(0.f, 0.f, 0.f, 0.f);
    float4 a3 = make_float4(0.f, 0.f, 0.f, 0.f);

    int i = beg;
    for (; i + 4 <= end; i += 4) {
        float2 e0 = edata[i + 0];
        float2 e1 = edata[i + 1];
        float2 e2 = edata[i + 2];
        float2 e3 = edata[i + 3];
        float4 w0 = *reinterpret_cast<const float4*>(lin + (size_t)__float_as_int(e0.x) * FH + lane * 4);
        float4 w1 = *reinterpret_cast<const float4*>(lin + (size_t)__float_as_int(e1.x) * FH + lane * 4);
        float4 w2 = *reinterpret_cast<const float4*>(lin + (size_t)__float_as_int(e2.x) * FH + lane * 4);
        float4 w3 = *reinterpret_cast<const float4*>(lin + (size_t)__float_as_int(e3.x) * FH + lane * 4);
        a0.x += w0.x * e0.y; a0.y += w0.y * e0.y; a0.z += w0.z * e0.y; a0.w += w0.w * e0.y;
        a1.x += w1.x * e1.y; a1.y += w1.y * e1.y; a1.z += w1.z * e1.y; a1.w += w1.w * e1.y;
        a2.x += w2.x * e2.y; a2.y += w2.y * e2.y; a2.z += w2.z * e2.y; a2.w += w2.w * e2.y;
        a3.x += w3.x * e3.y; a3.y += w3.y * e3.y; a3.z += w3.z * e3.y; a3.w += w3.w * e3.y;
    }
    for (; i < end; ++i) {
        float2 e = edata[i];
        float4 w = *reinterpret_cast<const float4*>(lin + (size_t)__float_as_int(e.x) * FH + lane * 4);
        a0.x += w.x * e.y; a0.y += w.y * e.y; a0.z += w.z * e.y; a0.w += w.w * e.y;
    }

    float4 r = make_float4(a0.x + a1.x + a2.x + a3.x,
                           a0.y + a1.y + a2.y + a3.y,
                           a0.z + a1.z + a2.z + a3.z,
                           a0.w + a1.w + a2.w + a3.w);
    *reinterpret_cast<float4*>(out + (size_t)node * FH + lane * 4) = r;
}

// ---------------- mean pool + head ----------------

__global__ void colsum_zero_kernel(float* __restrict__ colsum) {
    colsum[threadIdx.x] = 0.0f;
}

__global__ void colsum_kernel(const float* __restrict__ h, float* __restrict__ colsum) {
    int f = threadIdx.x;                 // 256 features
    int r0 = blockIdx.x * 256;
    int r1 = r0 + 256; if (r1 > NN) r1 = NN;
    float s = 0.0f;
    for (int r = r0; r < r1; ++r) s += h[(size_t)r * FH + f];
    unsafeAtomicAdd(&colsum[f], s);
}

__global__ void head_kernel(const float* __restrict__ colsum,
                            const float* __restrict__ Wh,
                            const float* __restrict__ bh,
                            float* __restrict__ out) {
    int o = threadIdx.x;
    if (o >= FOUT) return;
    const float scale = 1.0f / (float)NN;
    float s = 0.0f;
    for (int f = 0; f < FH; ++f)
        s += colsum[f] * scale * Wh[f * FOUT + o];
    out[o] = s + bh[o];
}

// ---------------- launch ----------------

extern "C" void kernel_launch(void* const* d_in, const int* in_sizes, int n_in,
                              void* d_out, int out_size, void* d_ws, size_t ws_size,
                              hipStream_t stream) {
    const float* x   = (const float*)d_in[0];
    const int*   ei  = (const int*)d_in[1];
    const float* W0  = (const float*)d_in[2];
    const float* b0  = (const float*)d_in[3];
    const float* W1  = (const float*)d_in[4];
    const float* b1  = (const float*)d_in[5];
    const float* W2  = (const float*)d_in[6];
    const float* b2  = (const float*)d_in[7];
    const float* Wh  = (const float*)d_in[8];
    const float* bh  = (const float*)d_in[9];
    float* out = (float*)d_out;

    const int* src = ei;        // edge_index[0,:]
    const int* dst = ei + NE;   // edge_index[1,:]

    // workspace layout (all offsets multiples of 64 floats -> 256B aligned)
    float*  inv       = (float*)d_ws;                   // NPAD floats
    int*    cnt       = (int*)(inv + NPAD);             // NPAD ints
    int*    row_start = cnt + NPAD;                     // NN+1 used
    int*    cursor    = row_start + NPAD;               // NN used
    float2* edata     = (float2*)(cursor + NPAD);       // NE float2 (6.4 MB)
    float*  colsum    = (float*)(edata + NE);           // 256 floats
    float*  lin       = colsum + 256;                   // NN*FH
    float*  acc       = lin + (size_t)NN * FH;          // NN*FH

    const int nblk_n = (NN + 255) / 256;
    const int nblk_e = (NE + 255) / 256;
    const dim3 gemm_grid((NN + 127) / 128, FH / 128);
    const int nblk_g = (NN + 3) / 4;                    // 4 waves (nodes) per block

    // ---- CSR build (once per launch, reused by 3 layers) ----
    cnt_zero_kernel<<<nblk_n, 256, 0, stream>>>(cnt);
    cnt_count_kernel<<<nblk_e, 256, 0, stream>>>(cnt, dst);
    inv_kernel<<<nblk_n, 256, 0, stream>>>(cnt, inv);
    scan_kernel<<<1, 1024, 0, stream>>>(cnt, row_start, cursor);
    fill_kernel<<<nblk_e, 256, 0, stream>>>(src, dst, inv, cursor, edata);

    // layer 0: x[NN,FIN] @ W0 -> lin; gather -> acc
    gemm_kernel<false><<<gemm_grid, 256, 0, stream>>>(x, W0, lin, NN, FIN, FH);
    gather_kernel<<<nblk_g, 256, 0, stream>>>(lin, edata, row_start, inv, b0, acc);

    // layer 1: relu(acc) @ W1 -> lin; gather -> acc
    gemm_kernel<true><<<gemm_grid, 256, 0, stream>>>(acc, W1, lin, NN, FH, FH);
    gather_kernel<<<nblk_g, 256, 0, stream>>>(lin, edata, row_start, inv, b1, acc);

    // layer 2: relu(acc) @ W2 -> lin; gather -> acc
    gemm_kernel<true><<<gemm_grid, 256, 0, stream>>>(acc, W2, lin, NN, FH, FH);
    gather_kernel<<<nblk_g, 256, 0, stream>>>(lin, edata, row_start, inv, b2, acc);

    // global mean pool + head
    colsum_zero_kernel<<<1, 256, 0, stream>>>(colsum);
    colsum_kernel<<<(NN + 255) / 256, 256, 0, stream>>>(acc, colsum);
    head_kernel<<<1, 64, 0, stream>>>(colsum, Wh, bh, out);
}

// Round 3
// 834.159 us; speedup vs baseline: 1.0857x; 1.0857x over previous
//
#include <hip/hip_runtime.h>

#define NN 50000
#define NE 800000
#define FIN 128
#define FH 256
#define FOUT 40
#define NPAD 50432   // > NN+1, multiple of 64

// ---------------- CSR build: histogram, inv-sqrt degree, scan, fill ----------------

__global__ void cnt_zero_kernel(int* __restrict__ cnt) {
    int i = blockIdx.x * 256 + threadIdx.x;
    if (i < NN) cnt[i] = 0;
}

__global__ void cnt_count_kernel(int* __restrict__ cnt, const int* __restrict__ dst) {
    int e = blockIdx.x * 256 + threadIdx.x;
    if (e < NE) atomicAdd(&cnt[dst[e]], 1);
}

__global__ void inv_kernel(const int* __restrict__ cnt, float* __restrict__ inv) {
    int i = blockIdx.x * 256 + threadIdx.x;
    if (i < NN) inv[i] = rsqrtf((float)(cnt[i] + 1));   // +1 self-loop
}

// Single-block exclusive scan over cnt[NN] -> row_start, cursor.
__global__ __launch_bounds__(1024) void scan_kernel(const int* __restrict__ cnt,
                                                    int* __restrict__ row_start,
                                                    int* __restrict__ cursor) {
    __shared__ int part[1024];
    const int t = threadIdx.x;
    const int CH = (NN + 1023) / 1024;   // 49
    int lo = t * CH;
    int hi = lo + CH; if (hi > NN) hi = NN;
    int s = 0;
    for (int i = lo; i < hi; ++i) s += cnt[i];
    part[t] = s;
    __syncthreads();
    for (int off = 1; off < 1024; off <<= 1) {
        int v = (t >= off) ? part[t - off] : 0;
        __syncthreads();
        part[t] += v;
        __syncthreads();
    }
    int base = part[t] - s;   // exclusive prefix for this chunk
    for (int i = lo; i < hi; ++i) {
        row_start[i] = base;
        cursor[i]    = base;
        base += cnt[i];
    }
    if (t == 0) row_start[NN] = NE;
}

// edata[pos] = {src index (bitcast), coef = inv[s]*inv[d]} sorted by dst.
__global__ void fill_kernel(const int* __restrict__ src, const int* __restrict__ dst,
                            const float* __restrict__ inv,
                            int* __restrict__ cursor, float2* __restrict__ edata) {
    int e = blockIdx.x * 256 + threadIdx.x;
    if (e >= NE) return;
    int s = src[e];
    int d = dst[e];
    int pos = atomicAdd(&cursor[d], 1);
    edata[pos] = make_float2(__int_as_float(s), inv[s] * inv[d]);
}

// ---------------- GEMM: C[M,N] = (relu?)A[M,K] @ B[K,N] (+bias) ----------------
// BM=BN=128, BK=16, 256 threads, 8x8 microtile per thread, SPLIT layout:
// thread (tx,ty) owns rows {ty*4..+3} u {64+ty*4..+3}, cols {tx*4..+3} u {64+tx*4..+3}.
// -> LDS reads: As 4 distinct addrs/wave (+broadcast), Bs banks 0,4,..,60 (2-way, free).

template<bool RELU_IN, bool BIAS>
__global__ __launch_bounds__(256) void gemm_kernel(const float* __restrict__ A,
                                                   const float* __restrict__ B,
                                                   const float* __restrict__ bias,
                                                   float* __restrict__ C,
                                                   int M, int K, int N) {
    __shared__ float As[16][132];  // [k][m], pad 132 (132%32=4 spreads transpose writes)
    __shared__ float Bs[16][128];  // [k][n], no pad needed with split reads

    const int tid = threadIdx.x;
    const int tx = tid & 15;       // 0..15
    const int ty = tid >> 4;       // 0..15
    const int row0 = blockIdx.x * 128;
    const int col0 = blockIdx.y * 128;

    float acc[8][8] = {};

    for (int k0 = 0; k0 < K; k0 += 16) {
        // A tile: 128 rows x 16 k. Each thread loads two float4 along K (transpose to [k][m]).
        {
            int r  = tid >> 2;            // 0..63
            int kc = (tid & 3) * 4;       // 0,4,8,12
            #pragma unroll
            for (int h = 0; h < 2; ++h) {
                int rr = r + h * 64;
                int grow = row0 + rr;
                float4 v = make_float4(0.f, 0.f, 0.f, 0.f);
                if (grow < M)
                    v = *reinterpret_cast<const float4*>(A + (size_t)grow * K + k0 + kc);
                if (RELU_IN) {
                    v.x = fmaxf(v.x, 0.f); v.y = fmaxf(v.y, 0.f);
                    v.z = fmaxf(v.z, 0.f); v.w = fmaxf(v.w, 0.f);
                }
                As[kc + 0][rr] = v.x;
                As[kc + 1][rr] = v.y;
                As[kc + 2][rr] = v.z;
                As[kc + 3][rr] = v.w;
            }
        }
        // B tile: 16 k x 128 n. Split columns: nc and nc+64.
        {
            int kr = tid >> 4;            // 0..15
            int nc = (tid & 15) * 4;      // 0..60
            const float* bp = B + (size_t)(k0 + kr) * N + col0;
            *reinterpret_cast<float4*>(&Bs[kr][nc])      = *reinterpret_cast<const float4*>(bp + nc);
            *reinterpret_cast<float4*>(&Bs[kr][nc + 64]) = *reinterpret_cast<const float4*>(bp + nc + 64);
        }
        __syncthreads();

        #pragma unroll
        for (int kk = 0; kk < 16; ++kk) {
            float4 a0 = *reinterpret_cast<const float4*>(&As[kk][ty * 4]);
            float4 a1 = *reinterpret_cast<const float4*>(&As[kk][ty * 4 + 64]);
            float4 b0 = *reinterpret_cast<const float4*>(&Bs[kk][tx * 4]);
            float4 b1 = *reinterpret_cast<const float4*>(&Bs[kk][tx * 4 + 64]);
            float a[8] = {a0.x, a0.y, a0.z, a0.w, a1.x, a1.y, a1.z, a1.w};
            float b[8] = {b0.x, b0.y, b0.z, b0.w, b1.x, b1.y, b1.z, b1.w};
            #pragma unroll
            for (int i = 0; i < 8; ++i)
                #pragma unroll
                for (int j = 0; j < 8; ++j)
                    acc[i][j] += a[i] * b[j];
        }
        __syncthreads();
    }

    float4 bs0 = make_float4(0.f, 0.f, 0.f, 0.f);
    float4 bs1 = make_float4(0.f, 0.f, 0.f, 0.f);
    if (BIAS) {
        bs0 = *reinterpret_cast<const float4*>(bias + col0 + tx * 4);
        bs1 = *reinterpret_cast<const float4*>(bias + col0 + tx * 4 + 64);
    }

    #pragma unroll
    for (int ih = 0; ih < 2; ++ih) {
        #pragma unroll
        for (int i = 0; i < 4; ++i) {
            int gr = row0 + ih * 64 + ty * 4 + i;
            if (gr < M) {
                float* cp = C + (size_t)gr * N + col0;
                int ai = ih * 4 + i;
                float4 o0 = make_float4(acc[ai][0] + bs0.x, acc[ai][1] + bs0.y,
                                        acc[ai][2] + bs0.z, acc[ai][3] + bs0.w);
                float4 o1 = make_float4(acc[ai][4] + bs1.x, acc[ai][5] + bs1.y,
                                        acc[ai][6] + bs1.z, acc[ai][7] + bs1.w);
                *reinterpret_cast<float4*>(cp + tx * 4)      = o0;
                *reinterpret_cast<float4*>(cp + tx * 4 + 64) = o1;
            }
        }
    }
}

// ---------------- gather (FH=256): agg[d,:] = sum lin[src,:]*coef + lin[d,:]*inv^2 + bias ----------------
// One wave per destination node; lane handles 4 consecutive features.

__global__ __launch_bounds__(256) void gather_kernel(const float* __restrict__ lin,
                                                     const float2* __restrict__ edata,
                                                     const int* __restrict__ row_start,
                                                     const float* __restrict__ inv,
                                                     const float* __restrict__ bias,
                                                     float* __restrict__ out) {
    int node = blockIdx.x * 4 + (threadIdx.x >> 6);
    int lane = threadIdx.x & 63;
    if (node >= NN) return;

    int beg = row_start[node];
    int end = row_start[node + 1];

    float iv = inv[node];
    float c  = iv * iv;                           // self-loop weight 1/deg
    float4 v = *reinterpret_cast<const float4*>(lin + (size_t)node * FH + lane * 4);
    float4 b = *reinterpret_cast<const float4*>(bias + lane * 4);
    float4 acc = make_float4(v.x * c + b.x, v.y * c + b.y, v.z * c + b.z, v.w * c + b.w);

    for (int i = beg; i < end; ++i) {
        float2 ed = edata[i];                     // wave-uniform 8B broadcast
        int   s  = __float_as_int(ed.x);
        float cf = ed.y;
        float4 w = *reinterpret_cast<const float4*>(lin + (size_t)s * FH + lane * 4);
        acc.x += w.x * cf;
        acc.y += w.y * cf;
        acc.z += w.z * cf;
        acc.w += w.w * cf;
    }

    *reinterpret_cast<float4*>(out + (size_t)node * FH + lane * 4) = acc;
}

// ---------------- gather_x (FIN=128): aggx[d,:] = sum x[src,:]*coef + x[d,:]*inv^2 ----------------
// One wave per node; lane handles 2 consecutive features (64*2 = 128). No bias
// (bias b0 is folded into the following GEMM epilogue; agg commutes with @W0).

__global__ __launch_bounds__(256) void gather_x_kernel(const float* __restrict__ x,
                                                       const float2* __restrict__ edata,
                                                       const int* __restrict__ row_start,
                                                       const float* __restrict__ inv,
                                                       float* __restrict__ out) {
    int node = blockIdx.x * 4 + (threadIdx.x >> 6);
    int lane = threadIdx.x & 63;
    if (node >= NN) return;

    int beg = row_start[node];
    int end = row_start[node + 1];

    float iv = inv[node];
    float c  = iv * iv;
    float2 v = *reinterpret_cast<const float2*>(x + (size_t)node * FIN + lane * 2);
    float2 acc = make_float2(v.x * c, v.y * c);

    for (int i = beg; i < end; ++i) {
        float2 ed = edata[i];
        int   s  = __float_as_int(ed.x);
        float cf = ed.y;
        float2 w = *reinterpret_cast<const float2*>(x + (size_t)s * FIN + lane * 2);
        acc.x += w.x * cf;
        acc.y += w.y * cf;
    }

    *reinterpret_cast<float2*>(out + (size_t)node * FIN + lane * 2) = acc;
}

// ---------------- mean pool + head ----------------

__global__ void colsum_zero_kernel(float* __restrict__ colsum) {
    colsum[threadIdx.x] = 0.0f;
}

__global__ void colsum_kernel(const float* __restrict__ h, float* __restrict__ colsum) {
    int f = threadIdx.x;                 // 256 features
    int r0 = blockIdx.x * 256;
    int r1 = r0 + 256; if (r1 > NN) r1 = NN;
    float s = 0.0f;
    for (int r = r0; r < r1; ++r) s += h[(size_t)r * FH + f];
    unsafeAtomicAdd(&colsum[f], s);
}

__global__ void head_kernel(const float* __restrict__ colsum,
                            const float* __restrict__ Wh,
                            const float* __restrict__ bh,
                            float* __restrict__ out) {
    int o = threadIdx.x;
    if (o >= FOUT) return;
    const float scale = 1.0f / (float)NN;
    float s = 0.0f;
    for (int f = 0; f < FH; ++f)
        s += colsum[f] * scale * Wh[f * FOUT + o];
    out[o] = s + bh[o];
}

// ---------------- launch ----------------

extern "C" void kernel_launch(void* const* d_in, const int* in_sizes, int n_in,
                              void* d_out, int out_size, void* d_ws, size_t ws_size,
                              hipStream_t stream) {
    const float* x   = (const float*)d_in[0];
    const int*   ei  = (const int*)d_in[1];
    const float* W0  = (const float*)d_in[2];
    const float* b0  = (const float*)d_in[3];
    const float* W1  = (const float*)d_in[4];
    const float* b1  = (const float*)d_in[5];
    const float* W2  = (const float*)d_in[6];
    const float* b2  = (const float*)d_in[7];
    const float* Wh  = (const float*)d_in[8];
    const float* bh  = (const float*)d_in[9];
    float* out = (float*)d_out;

    const int* src = ei;        // edge_index[0,:]
    const int* dst = ei + NE;   // edge_index[1,:]

    // workspace layout
    float*  inv       = (float*)d_ws;                   // NPAD floats
    int*    cnt       = (int*)(inv + NPAD);             // NPAD ints
    int*    row_start = cnt + NPAD;                     // NN+1 used
    int*    cursor    = row_start + NPAD;               // NN used
    float2* edata     = (float2*)(cursor + NPAD);       // NE float2 (6.4 MB)
    float*  colsum    = (float*)(edata + NE);           // 256 floats
    float*  bufB      = colsum + 256;                   // NN*FH
    float*  bufC      = bufB + (size_t)NN * FH;         // NN*FH (first NN*FIN doubles as aggx)
    float*  aggx      = bufC;                           // aggx dead before bufC first written

    const int nblk_n = (NN + 255) / 256;
    const int nblk_e = (NE + 255) / 256;
    const dim3 gemm_grid((NN + 127) / 128, FH / 128);
    const int nblk_g = (NN + 3) / 4;                    // 4 waves (nodes) per block

    // ---- CSR build (once per launch, reused by 3 layers) ----
    cnt_zero_kernel<<<nblk_n, 256, 0, stream>>>(cnt);
    cnt_count_kernel<<<nblk_e, 256, 0, stream>>>(cnt, dst);
    inv_kernel<<<nblk_n, 256, 0, stream>>>(cnt, inv);
    scan_kernel<<<1, 1024, 0, stream>>>(cnt, row_start, cursor);
    fill_kernel<<<nblk_e, 256, 0, stream>>>(src, dst, inv, cursor, edata);

    // layer 0 (reordered via linearity): aggx = agg(x); h0 = aggx @ W0 + b0
    gather_x_kernel<<<nblk_g, 256, 0, stream>>>(x, edata, row_start, inv, aggx);
    gemm_kernel<false, true><<<gemm_grid, 256, 0, stream>>>(aggx, W0, b0, bufB, NN, FIN, FH);

    // layer 1: lin1 = relu(h0) @ W1; acc1 = agg(lin1) + b1
    gemm_kernel<true, false><<<gemm_grid, 256, 0, stream>>>(bufB, W1, nullptr, bufC, NN, FH, FH);
    gather_kernel<<<nblk_g, 256, 0, stream>>>(bufC, edata, row_start, inv, b1, bufB);

    // layer 2: lin2 = relu(acc1) @ W2; acc2 = agg(lin2) + b2
    gemm_kernel<true, false><<<gemm_grid, 256, 0, stream>>>(bufB, W2, nullptr, bufC, NN, FH, FH);
    gather_kernel<<<nblk_g, 256, 0, stream>>>(bufC, edata, row_start, inv, b2, bufB);

    // global mean pool + head
    colsum_zero_kernel<<<1, 256, 0, stream>>>(colsum);
    colsum_kernel<<<(NN + 255) / 256, 256, 0, stream>>>(bufB, colsum);
    head_kernel<<<1, 64, 0, stream>>>(colsum, Wh, bh, out);
}

// Round 4
// 712.266 us; speedup vs baseline: 1.2715x; 1.1711x over previous
//
#include <hip/hip_runtime.h>

#define NN 50000
#define NE 800000
#define FIN 128
#define FH 256
#define FOUT 40
#define NPAD 50432   // > NN+1, multiple of 64
#define NN2 50048    // NN rounded up to 128

typedef float f32x4 __attribute__((ext_vector_type(4)));
typedef short bf16x8 __attribute__((ext_vector_type(8)));

__device__ __forceinline__ ushort f2bf(float f) {
    unsigned u = __float_as_uint(f);
    unsigned r = (u + 0x7FFFu + ((u >> 16) & 1u)) >> 16;   // RNE
    return (ushort)r;
}
__device__ __forceinline__ float bf2f(ushort b) {
    return __uint_as_float(((unsigned)b) << 16);
}

// ---------------- CSR build: histogram, inv-sqrt degree, scan, fill ----------------

__global__ void cnt_zero_kernel(int* __restrict__ cnt) {
    int i = blockIdx.x * 256 + threadIdx.x;
    if (i < NN) cnt[i] = 0;
}

__global__ void cnt_count_kernel(int* __restrict__ cnt, const int* __restrict__ dst) {
    int e = blockIdx.x * 256 + threadIdx.x;
    if (e < NE) atomicAdd(&cnt[dst[e]], 1);
}

__global__ void inv_kernel(const int* __restrict__ cnt, float* __restrict__ inv) {
    int i = blockIdx.x * 256 + threadIdx.x;
    if (i < NN) inv[i] = rsqrtf((float)(cnt[i] + 1));   // +1 self-loop
}

__global__ __launch_bounds__(1024) void scan_kernel(const int* __restrict__ cnt,
                                                    int* __restrict__ row_start,
                                                    int* __restrict__ cursor) {
    __shared__ int part[1024];
    const int t = threadIdx.x;
    const int CH = (NN + 1023) / 1024;   // 49
    int lo = t * CH;
    int hi = lo + CH; if (hi > NN) hi = NN;
    int s = 0;
    for (int i = lo; i < hi; ++i) s += cnt[i];
    part[t] = s;
    __syncthreads();
    for (int off = 1; off < 1024; off <<= 1) {
        int v = (t >= off) ? part[t - off] : 0;
        __syncthreads();
        part[t] += v;
        __syncthreads();
    }
    int base = part[t] - s;
    for (int i = lo; i < hi; ++i) {
        row_start[i] = base;
        cursor[i]    = base;
        base += cnt[i];
    }
    if (t == 0) row_start[NN] = NE;
}

__global__ void fill_kernel(const int* __restrict__ src, const int* __restrict__ dst,
                            const float* __restrict__ inv,
                            int* __restrict__ cursor, float2* __restrict__ edata) {
    int e = blockIdx.x * 256 + threadIdx.x;
    if (e >= NE) return;
    int s = src[e];
    int d = dst[e];
    int pos = atomicAdd(&cursor[d], 1);
    edata[pos] = make_float2(__int_as_float(s), inv[s] * inv[d]);
}

// ---------------- weight split: Wt_hi/lo[n][k] = split(W[k][n]) ----------------

__global__ void wsplit_kernel(const float* __restrict__ W, int K, int N,
                              ushort* __restrict__ WtH, ushort* __restrict__ WtL) {
    int idx = blockIdx.x * 256 + threadIdx.x;
    if (idx >= K * N) return;
    int n = idx % N;
    int k = idx / N;
    float f = W[idx];                 // coalesced read of W[k][n]
    ushort h = f2bf(f);
    ushort l = f2bf(f - bf2f(h));
    WtH[(size_t)n * K + k] = h;
    WtL[(size_t)n * K + k] = l;
}

// ---------------- MFMA GEMM: out = A @ Bt^T  (A split bf16 [M][K], Bt split bf16 [256][K]) ----------------
// 128x128 tile, 4 waves (2x2), each wave 64x64 via 4x4 frags of 16x16x32.
// 3-term split product: Ah*Bh + Ah*Bl + Al*Bh (fp32 acc) ~= fp32 GEMM.
// EPI_SPLIT: out = split(relu(acc + bias)) -> outH/outL ; else out = acc -> outF.

template<bool EPI_SPLIT>
__global__ __launch_bounds__(256) void gemm_mfma_kernel(
    const ushort* __restrict__ AH, const ushort* __restrict__ AL,
    const ushort* __restrict__ BH, const ushort* __restrict__ BL,
    const float* __restrict__ bias,
    float* __restrict__ outF, ushort* __restrict__ outH, ushort* __restrict__ outL,
    int M, int K) {
    __shared__ ushort Ah[128][40], Al[128][40], Bh[128][40], Bl[128][40]; // pad 40 -> uniform banks

    const int tid  = threadIdx.x;
    const int lane = tid & 63;
    const int w    = tid >> 6;        // 0..3
    const int wr   = w >> 1;          // 0..1
    const int wc   = w & 1;           // 0..1
    const int row0 = blockIdx.x * 128;
    const int col0 = blockIdx.y * 128;

    f32x4 acc[4][4] = {};

    for (int k0 = 0; k0 < K; k0 += 32) {
        // stage A tile (hi+lo): 128 rows x 32 k, 16B chunks
        #pragma unroll
        for (int i = 0; i < 2; ++i) {
            int c  = i * 256 + tid;
            int r  = c >> 2;          // 0..127
            int cb = c & 3;           // 16B chunk
            int gr = row0 + r;
            uint4 vh = make_uint4(0u, 0u, 0u, 0u);
            uint4 vl = make_uint4(0u, 0u, 0u, 0u);
            if (gr < M) {
                vh = *reinterpret_cast<const uint4*>(AH + (size_t)gr * K + k0 + cb * 8);
                vl = *reinterpret_cast<const uint4*>(AL + (size_t)gr * K + k0 + cb * 8);
            }
            *reinterpret_cast<uint4*>(&Ah[r][cb * 8]) = vh;
            *reinterpret_cast<uint4*>(&Al[r][cb * 8]) = vl;
        }
        // stage B tile (hi+lo): 128 cols x 32 k (Bt is [256][K] row-major)
        #pragma unroll
        for (int i = 0; i < 2; ++i) {
            int c  = i * 256 + tid;
            int r  = c >> 2;
            int cb = c & 3;
            *reinterpret_cast<uint4*>(&Bh[r][cb * 8]) =
                *reinterpret_cast<const uint4*>(BH + (size_t)(col0 + r) * K + k0 + cb * 8);
            *reinterpret_cast<uint4*>(&Bl[r][cb * 8]) =
                *reinterpret_cast<const uint4*>(BL + (size_t)(col0 + r) * K + k0 + cb * 8);
        }
        __syncthreads();

        const int rsel = lane & 15;
        const int ksel = (lane >> 4) * 8;
        bf16x8 ah[4], al[4], bh[4], bl[4];
        #pragma unroll
        for (int m = 0; m < 4; ++m) {
            int ar = wr * 64 + m * 16 + rsel;
            ah[m] = *reinterpret_cast<const bf16x8*>(&Ah[ar][ksel]);
            al[m] = *reinterpret_cast<const bf16x8*>(&Al[ar][ksel]);
        }
        #pragma unroll
        for (int n = 0; n < 4; ++n) {
            int br = wc * 64 + n * 16 + rsel;
            bh[n] = *reinterpret_cast<const bf16x8*>(&Bh[br][ksel]);
            bl[n] = *reinterpret_cast<const bf16x8*>(&Bl[br][ksel]);
        }
        #pragma unroll
        for (int m = 0; m < 4; ++m)
            #pragma unroll
            for (int n = 0; n < 4; ++n) {
                acc[m][n] = __builtin_amdgcn_mfma_f32_16x16x32_bf16(ah[m], bh[n], acc[m][n], 0, 0, 0);
                acc[m][n] = __builtin_amdgcn_mfma_f32_16x16x32_bf16(ah[m], bl[n], acc[m][n], 0, 0, 0);
                acc[m][n] = __builtin_amdgcn_mfma_f32_16x16x32_bf16(al[m], bh[n], acc[m][n], 0, 0, 0);
            }
        __syncthreads();
    }

    // epilogue: C/D layout col=lane&15, row=4*(lane>>4)+i  [m89-verified]
    const int cl = lane & 15;
    const int rg = lane >> 4;
    #pragma unroll
    for (int m = 0; m < 4; ++m) {
        #pragma unroll
        for (int i = 0; i < 4; ++i) {
            int gr = row0 + wr * 64 + m * 16 + rg * 4 + i;
            if (gr < M) {
                #pragma unroll
                for (int n = 0; n < 4; ++n) {
                    int gc = col0 + wc * 64 + n * 16 + cl;
                    float o = acc[m][n][i];
                    if (EPI_SPLIT) {
                        o = fmaxf(o + bias[gc], 0.0f);
                        ushort h = f2bf(o);
                        ushort l = f2bf(o - bf2f(h));
                        outH[(size_t)gr * FH + gc] = h;
                        outL[(size_t)gr * FH + gc] = l;
                    } else {
                        outF[(size_t)gr * FH + gc] = o;
                    }
                }
            }
        }
    }
}

// ---------------- gather_x (FIN=128): split-bf16 out, no bias (b0 folded into GEMM0) ----------------

__global__ __launch_bounds__(256) void gather_x_kernel(const float* __restrict__ x,
                                                       const float2* __restrict__ edata,
                                                       const int* __restrict__ row_start,
                                                       const float* __restrict__ inv,
                                                       ushort* __restrict__ outH,
                                                       ushort* __restrict__ outL) {
    int node = blockIdx.x * 4 + (threadIdx.x >> 6);
    int lane = threadIdx.x & 63;
    if (node >= NN) return;

    int beg = row_start[node];
    int end = row_start[node + 1];

    float iv = inv[node];
    float c  = iv * iv;
    float2 v = *reinterpret_cast<const float2*>(x + (size_t)node * FIN + lane * 2);
    float2 acc = make_float2(v.x * c, v.y * c);

    for (int i = beg; i < end; ++i) {
        float2 ed = edata[i];
        int   s  = __float_as_int(ed.x);
        float cf = ed.y;
        float2 w = *reinterpret_cast<const float2*>(x + (size_t)s * FIN + lane * 2);
        acc.x += w.x * cf;
        acc.y += w.y * cf;
    }

    ushort h0 = f2bf(acc.x), h1 = f2bf(acc.y);
    ushort l0 = f2bf(acc.x - bf2f(h0)), l1 = f2bf(acc.y - bf2f(h1));
    size_t o = (size_t)node * FIN + lane * 2;
    *reinterpret_cast<ushort2*>(outH + o) = make_ushort2(h0, h1);
    *reinterpret_cast<ushort2*>(outL + o) = make_ushort2(l0, l1);
}

// ---------------- gather (FH=256): fp32 in; SPLIT_OUT ? relu+split bf16 : fp32 ----------------

template<bool SPLIT_OUT>
__global__ __launch_bounds__(256) void gather_kernel(const float* __restrict__ lin,
                                                     const float2* __restrict__ edata,
                                                     const int* __restrict__ row_start,
                                                     const float* __restrict__ inv,
                                                     const float* __restrict__ bias,
                                                     float* __restrict__ outF,
                                                     ushort* __restrict__ outH,
                                                     ushort* __restrict__ outL) {
    int node = blockIdx.x * 4 + (threadIdx.x >> 6);
    int lane = threadIdx.x & 63;
    if (node >= NN) return;

    int beg = row_start[node];
    int end = row_start[node + 1];

    float iv = inv[node];
    float c  = iv * iv;
    float4 v = *reinterpret_cast<const float4*>(lin + (size_t)node * FH + lane * 4);
    float4 b = *reinterpret_cast<const float4*>(bias + lane * 4);
    float4 acc = make_float4(v.x * c + b.x, v.y * c + b.y, v.z * c + b.z, v.w * c + b.w);

    for (int i = beg; i < end; ++i) {
        float2 ed = edata[i];
        int   s  = __float_as_int(ed.x);
        float cf = ed.y;
        float4 w = *reinterpret_cast<const float4*>(lin + (size_t)s * FH + lane * 4);
        acc.x += w.x * cf;
        acc.y += w.y * cf;
        acc.z += w.z * cf;
        acc.w += w.w * cf;
    }

    if (SPLIT_OUT) {
        float r0 = fmaxf(acc.x, 0.f), r1 = fmaxf(acc.y, 0.f);
        float r2 = fmaxf(acc.z, 0.f), r3 = fmaxf(acc.w, 0.f);
        ushort h0 = f2bf(r0), h1 = f2bf(r1), h2 = f2bf(r2), h3 = f2bf(r3);
        ushort l0 = f2bf(r0 - bf2f(h0)), l1 = f2bf(r1 - bf2f(h1));
        ushort l2 = f2bf(r2 - bf2f(h2)), l3 = f2bf(r3 - bf2f(h3));
        size_t o = (size_t)node * FH + lane * 4;
        *reinterpret_cast<ushort4*>(outH + o) = make_ushort4(h0, h1, h2, h3);
        *reinterpret_cast<ushort4*>(outL + o) = make_ushort4(l0, l1, l2, l3);
    } else {
        *reinterpret_cast<float4*>(outF + (size_t)node * FH + lane * 4) = acc;
    }
}

// ---------------- mean pool + head ----------------

__global__ void colsum_zero_kernel(float* __restrict__ colsum) {
    colsum[threadIdx.x] = 0.0f;
}

__global__ void colsum_kernel(const float* __restrict__ h, float* __restrict__ colsum) {
    int f = threadIdx.x;
    int r0 = blockIdx.x * 256;
    int r1 = r0 + 256; if (r1 > NN) r1 = NN;
    float s = 0.0f;
    for (int r = r0; r < r1; ++r) s += h[(size_t)r * FH + f];
    unsafeAtomicAdd(&colsum[f], s);
}

__global__ void head_kernel(const float* __restrict__ colsum,
                            const float* __restrict__ Wh,
                            const float* __restrict__ bh,
                            float* __restrict__ out) {
    int o = threadIdx.x;
    if (o >= FOUT) return;
    const float scale = 1.0f / (float)NN;
    float s = 0.0f;
    for (int f = 0; f < FH; ++f)
        s += colsum[f] * scale * Wh[f * FOUT + o];
    out[o] = s + bh[o];
}

// ---------------- launch ----------------

extern "C" void kernel_launch(void* const* d_in, const int* in_sizes, int n_in,
                              void* d_out, int out_size, void* d_ws, size_t ws_size,
                              hipStream_t stream) {
    const float* x   = (const float*)d_in[0];
    const int*   ei  = (const int*)d_in[1];
    const float* W0  = (const float*)d_in[2];
    const float* b0  = (const float*)d_in[3];
    const float* W1  = (const float*)d_in[4];
    const float* b1  = (const float*)d_in[5];
    const float* W2  = (const float*)d_in[6];
    const float* b2  = (const float*)d_in[7];
    const float* Wh  = (const float*)d_in[8];
    const float* bh  = (const float*)d_in[9];
    float* out = (float*)d_out;

    const int* src = ei;        // edge_index[0,:]
    const int* dst = ei + NE;   // edge_index[1,:]

    // workspace layout (all 16B-aligned)
    float*  inv       = (float*)d_ws;                   // NPAD
    int*    cnt       = (int*)(inv + NPAD);             // NPAD
    int*    row_start = cnt + NPAD;                     // NN+1 used
    int*    cursor    = row_start + NPAD;               // NN used
    float2* edata     = (float2*)(cursor + NPAD);       // NE (6.4 MB)
    float*  colsum    = (float*)(edata + NE);           // 256
    ushort* W0tH      = (ushort*)(colsum + 256);        // [256][128]
    ushort* W0tL      = W0tH + 256 * 128;
    ushort* W1tH      = W0tL + 256 * 128;               // [256][256]
    ushort* W1tL      = W1tH + 256 * 256;
    ushort* W2tH      = W1tL + 256 * 256;
    ushort* W2tL      = W2tH + 256 * 256;
    // region L (51.2 MB): aggx split planes, then lin1/lin2 fp32
    ushort* aggxH     = W2tL + 256 * 256;               // [NN2][128]
    ushort* aggxL     = aggxH + (size_t)NN2 * 128;
    float*  lin       = (float*)aggxH;                  // [NN2][256] fp32 (aggx dead by then)
    // region P1 (51.2 MB): h0 split planes, then acc2 fp32
    ushort* h0H       = (ushort*)(lin + (size_t)NN2 * 256);
    ushort* h0L       = h0H + (size_t)NN2 * 256;
    float*  acc2      = (float*)h0H;                    // (h0 dead by then)
    // region P2 (51.2 MB): a1 split planes
    ushort* a1H       = h0L + (size_t)NN2 * 256;
    ushort* a1L       = a1H + (size_t)NN2 * 256;

    const int nblk_n = (NN + 255) / 256;
    const int nblk_e = (NE + 255) / 256;
    const dim3 gemm_grid((NN + 127) / 128, 2);
    const int nblk_g = (NN + 3) / 4;

    // ---- CSR build + weight split ----
    cnt_zero_kernel<<<nblk_n, 256, 0, stream>>>(cnt);
    cnt_count_kernel<<<nblk_e, 256, 0, stream>>>(cnt, dst);
    inv_kernel<<<nblk_n, 256, 0, stream>>>(cnt, inv);
    scan_kernel<<<1, 1024, 0, stream>>>(cnt, row_start, cursor);
    fill_kernel<<<nblk_e, 256, 0, stream>>>(src, dst, inv, cursor, edata);
    wsplit_kernel<<<(FIN * FH + 255) / 256, 256, 0, stream>>>(W0, FIN, FH, W0tH, W0tL);
    wsplit_kernel<<<(FH * FH + 255) / 256, 256, 0, stream>>>(W1, FH, FH, W1tH, W1tL);
    wsplit_kernel<<<(FH * FH + 255) / 256, 256, 0, stream>>>(W2, FH, FH, W2tH, W2tL);

    // layer 0: aggx = agg(x) [split]; h0 = split(relu(aggx @ W0 + b0))
    gather_x_kernel<<<nblk_g, 256, 0, stream>>>(x, edata, row_start, inv, aggxH, aggxL);
    gemm_mfma_kernel<true><<<gemm_grid, 256, 0, stream>>>(aggxH, aggxL, W0tH, W0tL, b0,
                                                          nullptr, h0H, h0L, NN, FIN);

    // layer 1: lin1 = h0 @ W1 (fp32); a1 = split(relu(agg(lin1) + b1))
    gemm_mfma_kernel<false><<<gemm_grid, 256, 0, stream>>>(h0H, h0L, W1tH, W1tL, nullptr,
                                                           lin, nullptr, nullptr, NN, FH);
    gather_kernel<true><<<nblk_g, 256, 0, stream>>>(lin, edata, row_start, inv, b1,
                                                    nullptr, a1H, a1L);

    // layer 2: lin2 = a1 @ W2 (fp32); acc2 = agg(lin2) + b2 (fp32, no relu)
    gemm_mfma_kernel<false><<<gemm_grid, 256, 0, stream>>>(a1H, a1L, W2tH, W2tL, nullptr,
                                                           lin, nullptr, nullptr, NN, FH);
    gather_kernel<false><<<nblk_g, 256, 0, stream>>>(lin, edata, row_start, inv, b2,
                                                     acc2, nullptr, nullptr);

    // global mean pool + head
    colsum_zero_kernel<<<1, 256, 0, stream>>>(colsum);
    colsum_kernel<<<(NN + 255) / 256, 256, 0, stream>>>(acc2, colsum);
    head_kernel<<<1, 64, 0, stream>>>(colsum, Wh, bh, out);
}

// Round 5
// 621.095 us; speedup vs baseline: 1.4582x; 1.1468x over previous
//
#include <hip/hip_runtime.h>

#define NN 50000
#define NE 800000
#define FIN 128
#define FH 256
#define FOUT 40
#define NPAD 50432   // > NN+1, multiple of 64
#define NN2 50048    // NN rounded up to 128

typedef float f32x4 __attribute__((ext_vector_type(4)));
typedef short bf16x8 __attribute__((ext_vector_type(8)));

__device__ __forceinline__ ushort f2bf(float f) {
    unsigned u = __float_as_uint(f);
    unsigned r = (u + 0x7FFFu + ((u >> 16) & 1u)) >> 16;   // RNE
    return (ushort)r;
}
__device__ __forceinline__ float bf2f(ushort b) {
    return __uint_as_float(((unsigned)b) << 16);
}

// ---------------- CSR build: histogram, inv-sqrt degree, scan, fill ----------------

__global__ void cnt_zero_kernel(int* __restrict__ cnt) {
    int i = blockIdx.x * 256 + threadIdx.x;
    if (i < NN) cnt[i] = 0;
}

__global__ void cnt_count_kernel(int* __restrict__ cnt, const int* __restrict__ dst) {
    int e = blockIdx.x * 256 + threadIdx.x;
    if (e < NE) atomicAdd(&cnt[dst[e]], 1);
}

__global__ void inv_kernel(const int* __restrict__ cnt, float* __restrict__ inv) {
    int i = blockIdx.x * 256 + threadIdx.x;
    if (i < NN) inv[i] = rsqrtf((float)(cnt[i] + 1));   // +1 self-loop
}

__global__ __launch_bounds__(1024) void scan_kernel(const int* __restrict__ cnt,
                                                    int* __restrict__ row_start,
                                                    int* __restrict__ cursor) {
    __shared__ int part[1024];
    const int t = threadIdx.x;
    const int CH = (NN + 1023) / 1024;   // 49
    int lo = t * CH;
    int hi = lo + CH; if (hi > NN) hi = NN;
    int s = 0;
    for (int i = lo; i < hi; ++i) s += cnt[i];
    part[t] = s;
    __syncthreads();
    for (int off = 1; off < 1024; off <<= 1) {
        int v = (t >= off) ? part[t - off] : 0;
        __syncthreads();
        part[t] += v;
        __syncthreads();
    }
    int base = part[t] - s;
    for (int i = lo; i < hi; ++i) {
        row_start[i] = base;
        cursor[i]    = base;
        base += cnt[i];
    }
    if (t == 0) row_start[NN] = NE;
}

__global__ void fill_kernel(const int* __restrict__ src, const int* __restrict__ dst,
                            const float* __restrict__ inv,
                            int* __restrict__ cursor, float2* __restrict__ edata) {
    int e = blockIdx.x * 256 + threadIdx.x;
    if (e >= NE) return;
    int s = src[e];
    int d = dst[e];
    int pos = atomicAdd(&cursor[d], 1);
    edata[pos] = make_float2(__int_as_float(s), inv[s] * inv[d]);
}

// ---------------- weight split / transpose ----------------

__global__ void wsplit_kernel(const float* __restrict__ W, int K, int N,
                              ushort* __restrict__ WtH, ushort* __restrict__ WtL) {
    int idx = blockIdx.x * 256 + threadIdx.x;
    if (idx >= K * N) return;
    int n = idx % N;
    int k = idx / N;
    float f = W[idx];
    ushort h = f2bf(f);
    WtH[(size_t)n * K + k] = h;
    if (WtL) WtL[(size_t)n * K + k] = f2bf(f - bf2f(h));
}

// ---------------- MFMA GEMM: out_bf16 = A @ Bt^T ----------------
// 128x128 tile, 4 waves (2x2), each wave 64x64 via 4x4 frags of 16x16x32.
// TERMS=3: Ah*Bh + Ah*Bl + Al*Bh (split fp32-accurate); TERMS=1: Ah*Bh (bf16).
// Output is always a single bf16 plane; BIAS_RELU applies bias+relu first.

template<int TERMS, bool BIAS_RELU>
__global__ __launch_bounds__(256) void gemm_mfma_kernel(
    const ushort* __restrict__ AH, const ushort* __restrict__ AL,
    const ushort* __restrict__ BH, const ushort* __restrict__ BL,
    const float* __restrict__ bias,
    ushort* __restrict__ outB,
    int M, int K) {
    constexpr int NARR = (TERMS == 3) ? 4 : 2;
    __shared__ ushort smem[NARR * 128 * 40];   // pad 40 -> spread banks
    ushort* Ah = smem;
    ushort* Bh = smem + 128 * 40;
    ushort* Al = (TERMS == 3) ? smem + 2 * 128 * 40 : nullptr;
    ushort* Bl = (TERMS == 3) ? smem + 3 * 128 * 40 : nullptr;

    const int tid  = threadIdx.x;
    const int lane = tid & 63;
    const int w    = tid >> 6;
    const int wr   = w >> 1;
    const int wc   = w & 1;
    const int row0 = blockIdx.x * 128;
    const int col0 = blockIdx.y * 128;

    f32x4 acc[4][4] = {};

    for (int k0 = 0; k0 < K; k0 += 32) {
        #pragma unroll
        for (int i = 0; i < 2; ++i) {
            int c  = i * 256 + tid;
            int r  = c >> 2;          // 0..127
            int cb = c & 3;           // 16B chunk
            int gr = row0 + r;
            uint4 vh = make_uint4(0u, 0u, 0u, 0u);
            if (gr < M)
                vh = *reinterpret_cast<const uint4*>(AH + (size_t)gr * K + k0 + cb * 8);
            *reinterpret_cast<uint4*>(&Ah[r * 40 + cb * 8]) = vh;
            *reinterpret_cast<uint4*>(&Bh[r * 40 + cb * 8]) =
                *reinterpret_cast<const uint4*>(BH + (size_t)(col0 + r) * K + k0 + cb * 8);
            if (TERMS == 3) {
                uint4 vl = make_uint4(0u, 0u, 0u, 0u);
                if (gr < M)
                    vl = *reinterpret_cast<const uint4*>(AL + (size_t)gr * K + k0 + cb * 8);
                *reinterpret_cast<uint4*>(&Al[r * 40 + cb * 8]) = vl;
                *reinterpret_cast<uint4*>(&Bl[r * 40 + cb * 8]) =
                    *reinterpret_cast<const uint4*>(BL + (size_t)(col0 + r) * K + k0 + cb * 8);
            }
        }
        __syncthreads();

        const int rsel = lane & 15;
        const int ksel = (lane >> 4) * 8;
        bf16x8 ah[4], bh[4];
        #pragma unroll
        for (int m = 0; m < 4; ++m)
            ah[m] = *reinterpret_cast<const bf16x8*>(&Ah[(wr * 64 + m * 16 + rsel) * 40 + ksel]);
        #pragma unroll
        for (int n = 0; n < 4; ++n)
            bh[n] = *reinterpret_cast<const bf16x8*>(&Bh[(wc * 64 + n * 16 + rsel) * 40 + ksel]);

        if (TERMS == 3) {
            bf16x8 al[4], bl[4];
            #pragma unroll
            for (int m = 0; m < 4; ++m)
                al[m] = *reinterpret_cast<const bf16x8*>(&Al[(wr * 64 + m * 16 + rsel) * 40 + ksel]);
            #pragma unroll
            for (int n = 0; n < 4; ++n)
                bl[n] = *reinterpret_cast<const bf16x8*>(&Bl[(wc * 64 + n * 16 + rsel) * 40 + ksel]);
            #pragma unroll
            for (int m = 0; m < 4; ++m)
                #pragma unroll
                for (int n = 0; n < 4; ++n) {
                    acc[m][n] = __builtin_amdgcn_mfma_f32_16x16x32_bf16(ah[m], bh[n], acc[m][n], 0, 0, 0);
                    acc[m][n] = __builtin_amdgcn_mfma_f32_16x16x32_bf16(ah[m], bl[n], acc[m][n], 0, 0, 0);
                    acc[m][n] = __builtin_amdgcn_mfma_f32_16x16x32_bf16(al[m], bh[n], acc[m][n], 0, 0, 0);
                }
        } else {
            #pragma unroll
            for (int m = 0; m < 4; ++m)
                #pragma unroll
                for (int n = 0; n < 4; ++n)
                    acc[m][n] = __builtin_amdgcn_mfma_f32_16x16x32_bf16(ah[m], bh[n], acc[m][n], 0, 0, 0);
        }
        __syncthreads();
    }

    // epilogue: C/D layout col=lane&15, row=4*(lane>>4)+i
    const int cl = lane & 15;
    const int rg = lane >> 4;
    #pragma unroll
    for (int m = 0; m < 4; ++m) {
        #pragma unroll
        for (int i = 0; i < 4; ++i) {
            int gr = row0 + wr * 64 + m * 16 + rg * 4 + i;
            if (gr < M) {
                #pragma unroll
                for (int n = 0; n < 4; ++n) {
                    int gc = col0 + wc * 64 + n * 16 + cl;
                    float o = acc[m][n][i];
                    if (BIAS_RELU) o = fmaxf(o + bias[gc], 0.0f);
                    outB[(size_t)gr * FH + gc] = f2bf(o);
                }
            }
        }
    }
}

// ---------------- gather_x (FIN=128): fp32 in, split-bf16 out (feeds 3-term GEMM0) ----------------

__global__ __launch_bounds__(256) void gather_x_kernel(const float* __restrict__ x,
                                                       const float2* __restrict__ edata,
                                                       const int* __restrict__ row_start,
                                                       const float* __restrict__ inv,
                                                       ushort* __restrict__ outH,
                                                       ushort* __restrict__ outL) {
    int node = blockIdx.x * 4 + (threadIdx.x >> 6);
    int lane = threadIdx.x & 63;
    if (node >= NN) return;

    int beg = row_start[node];
    int end = row_start[node + 1];

    float iv = inv[node];
    float c  = iv * iv;
    float2 v = *reinterpret_cast<const float2*>(x + (size_t)node * FIN + lane * 2);
    float2 acc = make_float2(v.x * c, v.y * c);

    for (int i = beg; i < end; ++i) {
        float2 ed = edata[i];
        int   s  = __float_as_int(ed.x);
        float cf = ed.y;
        float2 w = *reinterpret_cast<const float2*>(x + (size_t)s * FIN + lane * 2);
        acc.x += w.x * cf;
        acc.y += w.y * cf;
    }

    ushort h0 = f2bf(acc.x), h1 = f2bf(acc.y);
    ushort l0 = f2bf(acc.x - bf2f(h0)), l1 = f2bf(acc.y - bf2f(h1));
    size_t o = (size_t)node * FIN + lane * 2;
    *reinterpret_cast<ushort2*>(outH + o) = make_ushort2(h0, h1);
    *reinterpret_cast<ushort2*>(outL + o) = make_ushort2(l0, l1);
}

// ---------------- gather (FH=256): bf16 in, fp32 accumulate ----------------
// OUT_BF16: out = bf16(relu(acc + bias)); else: out = fp32(acc + bias).

template<bool OUT_BF16>
__global__ __launch_bounds__(256) void gather_bf_kernel(const ushort* __restrict__ lin,
                                                        const float2* __restrict__ edata,
                                                        const int* __restrict__ row_start,
                                                        const float* __restrict__ inv,
                                                        const float* __restrict__ bias,
                                                        ushort* __restrict__ outB,
                                                        float* __restrict__ outF) {
    int node = blockIdx.x * 4 + (threadIdx.x >> 6);
    int lane = threadIdx.x & 63;
    if (node >= NN) return;

    int beg = row_start[node];
    int end = row_start[node + 1];

    float iv = inv[node];
    float c  = iv * iv;
    ushort4 sv = *reinterpret_cast<const ushort4*>(lin + (size_t)node * FH + lane * 4);
    float4 b = *reinterpret_cast<const float4*>(bias + lane * 4);
    float4 acc = make_float4(bf2f(sv.x) * c + b.x, bf2f(sv.y) * c + b.y,
                             bf2f(sv.z) * c + b.z, bf2f(sv.w) * c + b.w);

    for (int i = beg; i < end; ++i) {
        float2 ed = edata[i];
        int   s  = __float_as_int(ed.x);
        float cf = ed.y;
        ushort4 wv = *reinterpret_cast<const ushort4*>(lin + (size_t)s * FH + lane * 4);
        acc.x += bf2f(wv.x) * cf;
        acc.y += bf2f(wv.y) * cf;
        acc.z += bf2f(wv.z) * cf;
        acc.w += bf2f(wv.w) * cf;
    }

    if (OUT_BF16) {
        float r0 = fmaxf(acc.x, 0.f), r1 = fmaxf(acc.y, 0.f);
        float r2 = fmaxf(acc.z, 0.f), r3 = fmaxf(acc.w, 0.f);
        *reinterpret_cast<ushort4*>(outB + (size_t)node * FH + lane * 4) =
            make_ushort4(f2bf(r0), f2bf(r1), f2bf(r2), f2bf(r3));
    } else {
        *reinterpret_cast<float4*>(outF + (size_t)node * FH + lane * 4) = acc;
    }
}

// ---------------- mean pool + head ----------------

__global__ void colsum_zero_kernel(float* __restrict__ colsum) {
    colsum[threadIdx.x] = 0.0f;
}

__global__ void colsum_kernel(const float* __restrict__ h, float* __restrict__ colsum) {
    int f = threadIdx.x;
    int r0 = blockIdx.x * 256;
    int r1 = r0 + 256; if (r1 > NN) r1 = NN;
    float s = 0.0f;
    for (int r = r0; r < r1; ++r) s += h[(size_t)r * FH + f];
    unsafeAtomicAdd(&colsum[f], s);
}

__global__ void head_kernel(const float* __restrict__ colsum,
                            const float* __restrict__ Wh,
                            const float* __restrict__ bh,
                            float* __restrict__ out) {
    int o = threadIdx.x;
    if (o >= FOUT) return;
    const float scale = 1.0f / (float)NN;
    float s = 0.0f;
    for (int f = 0; f < FH; ++f)
        s += colsum[f] * scale * Wh[f * FOUT + o];
    out[o] = s + bh[o];
}

// ---------------- launch ----------------

extern "C" void kernel_launch(void* const* d_in, const int* in_sizes, int n_in,
                              void* d_out, int out_size, void* d_ws, size_t ws_size,
                              hipStream_t stream) {
    const float* x   = (const float*)d_in[0];
    const int*   ei  = (const int*)d_in[1];
    const float* W0  = (const float*)d_in[2];
    const float* b0  = (const float*)d_in[3];
    const float* W1  = (const float*)d_in[4];
    const float* b1  = (const float*)d_in[5];
    const float* W2  = (const float*)d_in[6];
    const float* b2  = (const float*)d_in[7];
    const float* Wh  = (const float*)d_in[8];
    const float* bh  = (const float*)d_in[9];
    float* out = (float*)d_out;

    const int* src = ei;        // edge_index[0,:]
    const int* dst = ei + NE;   // edge_index[1,:]

    // workspace layout (16B-aligned blocks)
    float*  inv       = (float*)d_ws;                   // NPAD
    int*    cnt       = (int*)(inv + NPAD);             // NPAD
    int*    row_start = cnt + NPAD;                     // NN+1 used
    int*    cursor    = row_start + NPAD;               // NN used
    float2* edata     = (float2*)(cursor + NPAD);       // NE (6.4 MB)
    float*  colsum    = (float*)(edata + NE);           // 256
    ushort* W0tH      = (ushort*)(colsum + 256);        // [256][128]
    ushort* W0tL      = W0tH + 256 * 128;
    ushort* W1tH      = W0tL + 256 * 128;               // [256][256]
    ushort* W2tH      = W1tH + 256 * 256;
    // aggx split planes (25.6 MB total) -> later reused as linb (bf16 lin1/lin2)
    ushort* aggxH     = W2tH + 256 * 256;               // [NN2][128]
    ushort* aggxL     = aggxH + (size_t)NN2 * 128;
    ushort* linb      = aggxH;                          // [NN2][256] bf16 (aggx dead)
    // h0 plane (25.6 MB) -> later reused as a1 plane
    ushort* h0H       = aggxL + (size_t)NN2 * 128;      // [NN2][256]
    ushort* a1H       = h0H;                            // (h0 dead after GEMM1)
    float*  acc2      = (float*)(h0H + (size_t)NN2 * 256);  // [NN2][256] fp32

    const int nblk_n = (NN + 255) / 256;
    const int nblk_e = (NE + 255) / 256;
    const dim3 gemm_grid((NN + 127) / 128, 2);
    const int nblk_g = (NN + 3) / 4;

    // ---- CSR build + weight split ----
    cnt_zero_kernel<<<nblk_n, 256, 0, stream>>>(cnt);
    cnt_count_kernel<<<nblk_e, 256, 0, stream>>>(cnt, dst);
    inv_kernel<<<nblk_n, 256, 0, stream>>>(cnt, inv);
    scan_kernel<<<1, 1024, 0, stream>>>(cnt, row_start, cursor);
    fill_kernel<<<nblk_e, 256, 0, stream>>>(src, dst, inv, cursor, edata);
    wsplit_kernel<<<(FIN * FH + 255) / 256, 256, 0, stream>>>(W0, FIN, FH, W0tH, W0tL);
    wsplit_kernel<<<(FH * FH + 255) / 256, 256, 0, stream>>>(W1, FH, FH, W1tH, nullptr);
    wsplit_kernel<<<(FH * FH + 255) / 256, 256, 0, stream>>>(W2, FH, FH, W2tH, nullptr);

    // layer 0: aggx = agg(x) [split]; h0 = bf16(relu(aggx @ W0 + b0))   (3-term, fp32-accurate)
    gather_x_kernel<<<nblk_g, 256, 0, stream>>>(x, edata, row_start, inv, aggxH, aggxL);
    gemm_mfma_kernel<3, true><<<gemm_grid, 256, 0, stream>>>(aggxH, aggxL, W0tH, W0tL, b0,
                                                             h0H, NN, FIN);

    // layer 1: lin1 = bf16(h0 @ W1); a1 = bf16(relu(agg(lin1) + b1))
    gemm_mfma_kernel<1, false><<<gemm_grid, 256, 0, stream>>>(h0H, nullptr, W1tH, nullptr, nullptr,
                                                              linb, NN, FH);
    gather_bf_kernel<true><<<nblk_g, 256, 0, stream>>>(linb, edata, row_start, inv, b1,
                                                       a1H, nullptr);

    // layer 2: lin2 = bf16(a1 @ W2); acc2 = agg(lin2) + b2 (fp32)
    gemm_mfma_kernel<1, false><<<gemm_grid, 256, 0, stream>>>(a1H, nullptr, W2tH, nullptr, nullptr,
                                                              linb, NN, FH);
    gather_bf_kernel<false><<<nblk_g, 256, 0, stream>>>(linb, edata, row_start, inv, b2,
                                                        nullptr, acc2);

    // global mean pool + head
    colsum_zero_kernel<<<1, 256, 0, stream>>>(colsum);
    colsum_kernel<<<(NN + 255) / 256, 256, 0, stream>>>(acc2, colsum);
    head_kernel<<<1, 64, 0, stream>>>(colsum, Wh, bh, out);
}

// Round 6
// 519.269 us; speedup vs baseline: 1.7441x; 1.1961x over previous
//
#include <hip/hip_runtime.h>

#define NN 50000
#define NE 800000
#define FIN 128
#define FH 256
#define FOUT 40
#define NPAD 50432   // > NN+1, multiple of 64
#define NN2 50048    // NN rounded up to 128
#define NBLK_S 196   // ceil((NN+1)/256)

typedef float f32x4 __attribute__((ext_vector_type(4)));
typedef short bf16x8 __attribute__((ext_vector_type(8)));

__device__ __forceinline__ ushort f2bf(float f) {
    unsigned u = __float_as_uint(f);
    unsigned r = (u + 0x7FFFu + ((u >> 16) & 1u)) >> 16;   // RNE
    return (ushort)r;
}
__device__ __forceinline__ float bf2f(ushort b) {
    return __uint_as_float(((unsigned)b) << 16);
}

// ---------------- CSR build: histogram, inv-sqrt degree, hierarchical scan, fill ----------------

__global__ void cnt_zero_kernel(int* __restrict__ cnt) {
    int i = blockIdx.x * 256 + threadIdx.x;
    if (i < NN) cnt[i] = 0;
}

__global__ void cnt_count_kernel(int* __restrict__ cnt, const int* __restrict__ dst) {
    int e = blockIdx.x * 256 + threadIdx.x;
    if (e < NE) atomicAdd(&cnt[dst[e]], 1);
}

__global__ void inv_kernel(const int* __restrict__ cnt, float* __restrict__ inv) {
    int i = blockIdx.x * 256 + threadIdx.x;
    if (i < NN) inv[i] = rsqrtf((float)(cnt[i] + 1));   // +1 self-loop
}

// scan stage 1: per-block sums of 256 counts
__global__ __launch_bounds__(256) void bsum_kernel(const int* __restrict__ cnt,
                                                   int* __restrict__ bsum) {
    __shared__ int sh[256];
    int i = blockIdx.x * 256 + threadIdx.x;
    sh[threadIdx.x] = (i < NN) ? cnt[i] : 0;
    __syncthreads();
    #pragma unroll
    for (int off = 128; off > 0; off >>= 1) {
        if (threadIdx.x < off) sh[threadIdx.x] += sh[threadIdx.x + off];
        __syncthreads();
    }
    if (threadIdx.x == 0) bsum[blockIdx.x] = sh[0];
}

// scan stage 2: exclusive scan of the NBLK_S partials (single small block)
__global__ __launch_bounds__(256) void bscan_kernel(int* __restrict__ bsum) {
    __shared__ int sh[256];
    int t = threadIdx.x;
    int v = (t < NBLK_S) ? bsum[t] : 0;
    sh[t] = v;
    __syncthreads();
    #pragma unroll
    for (int off = 1; off < 256; off <<= 1) {
        int u = (t >= off) ? sh[t - off] : 0;
        __syncthreads();
        sh[t] += u;
        __syncthreads();
    }
    if (t < NBLK_S) bsum[t] = sh[t] - v;   // exclusive
}

// scan stage 3: in-block exclusive scan + block offset -> row_start, cursor
__global__ __launch_bounds__(256) void emit_kernel(const int* __restrict__ cnt,
                                                   const int* __restrict__ bsum,
                                                   int* __restrict__ row_start,
                                                   int* __restrict__ cursor) {
    __shared__ int sh[256];
    int i = blockIdx.x * 256 + threadIdx.x;
    int v = (i < NN) ? cnt[i] : 0;
    sh[threadIdx.x] = v;
    __syncthreads();
    #pragma unroll
    for (int off = 1; off < 256; off <<= 1) {
        int u = (threadIdx.x >= off) ? sh[threadIdx.x - off] : 0;
        __syncthreads();
        sh[threadIdx.x] += u;
        __syncthreads();
    }
    int pos = bsum[blockIdx.x] + sh[threadIdx.x] - v;   // exclusive prefix
    if (i <= NN) row_start[i] = pos;                    // i==NN -> NE
    if (i < NN)  cursor[i]    = pos;
}

__global__ void fill_kernel(const int* __restrict__ src, const int* __restrict__ dst,
                            const float* __restrict__ inv,
                            int* __restrict__ cursor, float2* __restrict__ edata) {
    int e = blockIdx.x * 256 + threadIdx.x;
    if (e >= NE) return;
    int s = src[e];
    int d = dst[e];
    int pos = atomicAdd(&cursor[d], 1);
    edata[pos] = make_float2(__int_as_float(s), inv[s] * inv[d]);
}

// ---------------- weight split / transpose ----------------

__global__ void wsplit_kernel(const float* __restrict__ W, int K, int N,
                              ushort* __restrict__ WtH, ushort* __restrict__ WtL) {
    int idx = blockIdx.x * 256 + threadIdx.x;
    if (idx >= K * N) return;
    int n = idx % N;
    int k = idx / N;
    float f = W[idx];
    ushort h = f2bf(f);
    WtH[(size_t)n * K + k] = h;
    if (WtL) WtL[(size_t)n * K + k] = f2bf(f - bf2f(h));
}

// ---------------- MFMA GEMM: out_bf16 = A @ Bt^T ----------------
// 128x128 tile, 4 waves (2x2), each wave 64x64 via 4x4 frags of 16x16x32.
// TERMS=3: Ah*Bh + Ah*Bl + Al*Bh (split fp32-accurate); TERMS=1: Ah*Bh (bf16).

template<int TERMS, bool BIAS_RELU>
__global__ __launch_bounds__(256) void gemm_mfma_kernel(
    const ushort* __restrict__ AH, const ushort* __restrict__ AL,
    const ushort* __restrict__ BH, const ushort* __restrict__ BL,
    const float* __restrict__ bias,
    ushort* __restrict__ outB,
    int M, int K) {
    constexpr int NARR = (TERMS == 3) ? 4 : 2;
    __shared__ ushort smem[NARR * 128 * 40];   // pad 40 -> spread banks
    ushort* Ah = smem;
    ushort* Bh = smem + 128 * 40;
    ushort* Al = (TERMS == 3) ? smem + 2 * 128 * 40 : nullptr;
    ushort* Bl = (TERMS == 3) ? smem + 3 * 128 * 40 : nullptr;

    const int tid  = threadIdx.x;
    const int lane = tid & 63;
    const int w    = tid >> 6;
    const int wr   = w >> 1;
    const int wc   = w & 1;
    const int row0 = blockIdx.x * 128;
    const int col0 = blockIdx.y * 128;

    f32x4 acc[4][4] = {};

    for (int k0 = 0; k0 < K; k0 += 32) {
        #pragma unroll
        for (int i = 0; i < 2; ++i) {
            int c  = i * 256 + tid;
            int r  = c >> 2;          // 0..127
            int cb = c & 3;           // 16B chunk
            int gr = row0 + r;
            uint4 vh = make_uint4(0u, 0u, 0u, 0u);
            if (gr < M)
                vh = *reinterpret_cast<const uint4*>(AH + (size_t)gr * K + k0 + cb * 8);
            *reinterpret_cast<uint4*>(&Ah[r * 40 + cb * 8]) = vh;
            *reinterpret_cast<uint4*>(&Bh[r * 40 + cb * 8]) =
                *reinterpret_cast<const uint4*>(BH + (size_t)(col0 + r) * K + k0 + cb * 8);
            if (TERMS == 3) {
                uint4 vl = make_uint4(0u, 0u, 0u, 0u);
                if (gr < M)
                    vl = *reinterpret_cast<const uint4*>(AL + (size_t)gr * K + k0 + cb * 8);
                *reinterpret_cast<uint4*>(&Al[r * 40 + cb * 8]) = vl;
                *reinterpret_cast<uint4*>(&Bl[r * 40 + cb * 8]) =
                    *reinterpret_cast<const uint4*>(BL + (size_t)(col0 + r) * K + k0 + cb * 8);
            }
        }
        __syncthreads();

        const int rsel = lane & 15;
        const int ksel = (lane >> 4) * 8;
        bf16x8 ah[4], bh[4];
        #pragma unroll
        for (int m = 0; m < 4; ++m)
            ah[m] = *reinterpret_cast<const bf16x8*>(&Ah[(wr * 64 + m * 16 + rsel) * 40 + ksel]);
        #pragma unroll
        for (int n = 0; n < 4; ++n)
            bh[n] = *reinterpret_cast<const bf16x8*>(&Bh[(wc * 64 + n * 16 + rsel) * 40 + ksel]);

        if (TERMS == 3) {
            bf16x8 al[4], bl[4];
            #pragma unroll
            for (int m = 0; m < 4; ++m)
                al[m] = *reinterpret_cast<const bf16x8*>(&Al[(wr * 64 + m * 16 + rsel) * 40 + ksel]);
            #pragma unroll
            for (int n = 0; n < 4; ++n)
                bl[n] = *reinterpret_cast<const bf16x8*>(&Bl[(wc * 64 + n * 16 + rsel) * 40 + ksel]);
            #pragma unroll
            for (int m = 0; m < 4; ++m)
                #pragma unroll
                for (int n = 0; n < 4; ++n) {
                    acc[m][n] = __builtin_amdgcn_mfma_f32_16x16x32_bf16(ah[m], bh[n], acc[m][n], 0, 0, 0);
                    acc[m][n] = __builtin_amdgcn_mfma_f32_16x16x32_bf16(ah[m], bl[n], acc[m][n], 0, 0, 0);
                    acc[m][n] = __builtin_amdgcn_mfma_f32_16x16x32_bf16(al[m], bh[n], acc[m][n], 0, 0, 0);
                }
        } else {
            #pragma unroll
            for (int m = 0; m < 4; ++m)
                #pragma unroll
                for (int n = 0; n < 4; ++n)
                    acc[m][n] = __builtin_amdgcn_mfma_f32_16x16x32_bf16(ah[m], bh[n], acc[m][n], 0, 0, 0);
        }
        __syncthreads();
    }

    // epilogue: C/D layout col=lane&15, row=4*(lane>>4)+i
    const int cl = lane & 15;
    const int rg = lane >> 4;
    #pragma unroll
    for (int m = 0; m < 4; ++m) {
        #pragma unroll
        for (int i = 0; i < 4; ++i) {
            int gr = row0 + wr * 64 + m * 16 + rg * 4 + i;
            if (gr < M) {
                #pragma unroll
                for (int n = 0; n < 4; ++n) {
                    int gc = col0 + wc * 64 + n * 16 + cl;
                    float o = acc[m][n][i];
                    if (BIAS_RELU) o = fmaxf(o + bias[gc], 0.0f);
                    outB[(size_t)gr * FH + gc] = f2bf(o);
                }
            }
        }
    }
}

// ---------------- gather_x (FIN=128): fp32 in, split-bf16 out (feeds 3-term GEMM0) ----------------

__global__ __launch_bounds__(256) void gather_x_kernel(const float* __restrict__ x,
                                                       const float2* __restrict__ edata,
                                                       const int* __restrict__ row_start,
                                                       const float* __restrict__ inv,
                                                       ushort* __restrict__ outH,
                                                       ushort* __restrict__ outL) {
    int node = blockIdx.x * 4 + (threadIdx.x >> 6);
    int lane = threadIdx.x & 63;
    if (node >= NN) return;

    int beg = row_start[node];
    int end = row_start[node + 1];

    float iv = inv[node];
    float c  = iv * iv;
    float2 v = *reinterpret_cast<const float2*>(x + (size_t)node * FIN + lane * 2);
    float2 acc = make_float2(v.x * c, v.y * c);

    for (int i = beg; i < end; ++i) {
        float2 ed = edata[i];
        int   s  = __float_as_int(ed.x);
        float cf = ed.y;
        float2 w = *reinterpret_cast<const float2*>(x + (size_t)s * FIN + lane * 2);
        acc.x += w.x * cf;
        acc.y += w.y * cf;
    }

    ushort h0 = f2bf(acc.x), h1 = f2bf(acc.y);
    ushort l0 = f2bf(acc.x - bf2f(h0)), l1 = f2bf(acc.y - bf2f(h1));
    size_t o = (size_t)node * FIN + lane * 2;
    *reinterpret_cast<ushort2*>(outH + o) = make_ushort2(h0, h1);
    *reinterpret_cast<ushort2*>(outL + o) = make_ushort2(l0, l1);
}

// ---------------- gather (FH=256): bf16 in, fp32 accumulate ----------------

template<bool OUT_BF16>
__global__ __launch_bounds__(256) void gather_bf_kernel(const ushort* __restrict__ lin,
                                                        const float2* __restrict__ edata,
                                                        const int* __restrict__ row_start,
                                                        const float* __restrict__ inv,
                                                        const float* __restrict__ bias,
                                                        ushort* __restrict__ outB,
                                                        float* __restrict__ outF) {
    int node = blockIdx.x * 4 + (threadIdx.x >> 6);
    int lane = threadIdx.x & 63;
    if (node >= NN) return;

    int beg = row_start[node];
    int end = row_start[node + 1];

    float iv = inv[node];
    float c  = iv * iv;
    ushort4 sv = *reinterpret_cast<const ushort4*>(lin + (size_t)node * FH + lane * 4);
    float4 b = *reinterpret_cast<const float4*>(bias + lane * 4);
    float4 acc = make_float4(bf2f(sv.x) * c + b.x, bf2f(sv.y) * c + b.y,
                             bf2f(sv.z) * c + b.z, bf2f(sv.w) * c + b.w);

    for (int i = beg; i < end; ++i) {
        float2 ed = edata[i];
        int   s  = __float_as_int(ed.x);
        float cf = ed.y;
        ushort4 wv = *reinterpret_cast<const ushort4*>(lin + (size_t)s * FH + lane * 4);
        acc.x += bf2f(wv.x) * cf;
        acc.y += bf2f(wv.y) * cf;
        acc.z += bf2f(wv.z) * cf;
        acc.w += bf2f(wv.w) * cf;
    }

    if (OUT_BF16) {
        float r0 = fmaxf(acc.x, 0.f), r1 = fmaxf(acc.y, 0.f);
        float r2 = fmaxf(acc.z, 0.f), r3 = fmaxf(acc.w, 0.f);
        *reinterpret_cast<ushort4*>(outB + (size_t)node * FH + lane * 4) =
            make_ushort4(f2bf(r0), f2bf(r1), f2bf(r2), f2bf(r3));
    } else {
        *reinterpret_cast<float4*>(outF + (size_t)node * FH + lane * 4) = acc;
    }
}

// ---------------- mean pool + head ----------------

__global__ void colsum_zero_kernel(float* __restrict__ colsum) {
    colsum[threadIdx.x] = 0.0f;
}

__global__ void colsum_kernel(const float* __restrict__ h, float* __restrict__ colsum) {
    int f = threadIdx.x;
    int r0 = blockIdx.x * 256;
    int r1 = r0 + 256; if (r1 > NN) r1 = NN;
    float s = 0.0f;
    for (int r = r0; r < r1; ++r) s += h[(size_t)r * FH + f];
    unsafeAtomicAdd(&colsum[f], s);
}

__global__ void head_kernel(const float* __restrict__ colsum,
                            const float* __restrict__ Wh,
                            const float* __restrict__ bh,
                            float* __restrict__ out) {
    int o = threadIdx.x;
    if (o >= FOUT) return;
    const float scale = 1.0f / (float)NN;
    float s = 0.0f;
    for (int f = 0; f < FH; ++f)
        s += colsum[f] * scale * Wh[f * FOUT + o];
    out[o] = s + bh[o];
}

// ---------------- launch ----------------

extern "C" void kernel_launch(void* const* d_in, const int* in_sizes, int n_in,
                              void* d_out, int out_size, void* d_ws, size_t ws_size,
                              hipStream_t stream) {
    const float* x   = (const float*)d_in[0];
    const int*   ei  = (const int*)d_in[1];
    const float* W0  = (const float*)d_in[2];
    const float* b0  = (const float*)d_in[3];
    const float* W1  = (const float*)d_in[4];
    const float* b1  = (const float*)d_in[5];
    const float* W2  = (const float*)d_in[6];
    const float* b2  = (const float*)d_in[7];
    const float* Wh  = (const float*)d_in[8];
    const float* bh  = (const float*)d_in[9];
    float* out = (float*)d_out;

    const int* src = ei;        // edge_index[0,:]
    const int* dst = ei + NE;   // edge_index[1,:]

    // workspace layout (16B-aligned blocks)
    float*  inv       = (float*)d_ws;                   // NPAD
    int*    cnt       = (int*)(inv + NPAD);             // NPAD
    int*    row_start = cnt + NPAD;                     // NN+1 used
    int*    cursor    = row_start + NPAD;               // NN used
    int*    bsum      = cursor + NPAD;                  // 256 (NBLK_S used)
    float2* edata     = (float2*)(bsum + 256);          // NE (6.4 MB)
    float*  colsum    = (float*)(edata + NE);           // 256
    ushort* W0tH      = (ushort*)(colsum + 256);        // [256][128]
    ushort* W0tL      = W0tH + 256 * 128;
    ushort* W1tH      = W0tL + 256 * 128;               // [256][256]
    ushort* W2tH      = W1tH + 256 * 256;
    // aggx split planes (25.6 MB total) -> later reused as linb (bf16 lin1/lin2)
    ushort* aggxH     = W2tH + 256 * 256;               // [NN2][128]
    ushort* aggxL     = aggxH + (size_t)NN2 * 128;
    ushort* linb      = aggxH;                          // [NN2][256] bf16 (aggx dead)
    // h0 plane (25.6 MB) -> later reused as a1 plane
    ushort* h0H       = aggxL + (size_t)NN2 * 128;      // [NN2][256]
    ushort* a1H       = h0H;                            // (h0 dead after GEMM1)
    float*  acc2      = (float*)(h0H + (size_t)NN2 * 256);  // [NN2][256] fp32

    const int nblk_n = (NN + 255) / 256;
    const int nblk_e = (NE + 255) / 256;
    const dim3 gemm_grid((NN + 127) / 128, 2);
    const int nblk_g = (NN + 3) / 4;

    // ---- CSR build + weight split ----
    cnt_zero_kernel<<<nblk_n, 256, 0, stream>>>(cnt);
    cnt_count_kernel<<<nblk_e, 256, 0, stream>>>(cnt, dst);
    inv_kernel<<<nblk_n, 256, 0, stream>>>(cnt, inv);
    bsum_kernel<<<NBLK_S, 256, 0, stream>>>(cnt, bsum);
    bscan_kernel<<<1, 256, 0, stream>>>(bsum);
    emit_kernel<<<NBLK_S, 256, 0, stream>>>(cnt, bsum, row_start, cursor);
    fill_kernel<<<nblk_e, 256, 0, stream>>>(src, dst, inv, cursor, edata);
    wsplit_kernel<<<(FIN * FH + 255) / 256, 256, 0, stream>>>(W0, FIN, FH, W0tH, W0tL);
    wsplit_kernel<<<(FH * FH + 255) / 256, 256, 0, stream>>>(W1, FH, FH, W1tH, nullptr);
    wsplit_kernel<<<(FH * FH + 255) / 256, 256, 0, stream>>>(W2, FH, FH, W2tH, nullptr);

    // layer 0: aggx = agg(x) [split]; h0 = bf16(relu(aggx @ W0 + b0))   (3-term, fp32-accurate)
    gather_x_kernel<<<nblk_g, 256, 0, stream>>>(x, edata, row_start, inv, aggxH, aggxL);
    gemm_mfma_kernel<3, true><<<gemm_grid, 256, 0, stream>>>(aggxH, aggxL, W0tH, W0tL, b0,
                                                             h0H, NN, FIN);

    // layer 1: lin1 = bf16(h0 @ W1); a1 = bf16(relu(agg(lin1) + b1))
    gemm_mfma_kernel<1, false><<<gemm_grid, 256, 0, stream>>>(h0H, nullptr, W1tH, nullptr, nullptr,
                                                              linb, NN, FH);
    gather_bf_kernel<true><<<nblk_g, 256, 0, stream>>>(linb, edata, row_start, inv, b1,
                                                       a1H, nullptr);

    // layer 2: lin2 = bf16(a1 @ W2); acc2 = agg(lin2) + b2 (fp32)
    gemm_mfma_kernel<1, false><<<gemm_grid, 256, 0, stream>>>(a1H, nullptr, W2tH, nullptr, nullptr,
                                                              linb, NN, FH);
    gather_bf_kernel<false><<<nblk_g, 256, 0, stream>>>(linb, edata, row_start, inv, b2,
                                                        nullptr, acc2);

    // global mean pool + head
    colsum_zero_kernel<<<1, 256, 0, stream>>>(colsum);
    colsum_kernel<<<(NN + 255) / 256, 256, 0, stream>>>(acc2, colsum);
    head_kernel<<<1, 64, 0, stream>>>(colsum, Wh, bh, out);
}

// Round 7
// 434.041 us; speedup vs baseline: 2.0866x; 1.1964x over previous
//
#include <hip/hip_runtime.h>

#define NN 50000
#define NE 800000
#define FIN 128
#define FH 256
#define FOUT 40
#define NPAD 50432   // > NN+1, multiple of 64
#define NN2 50048    // NN rounded up to 128
#define NBLK_S 196   // ceil((NN+1)/256)

typedef float f32x4 __attribute__((ext_vector_type(4)));
typedef short bf16x8 __attribute__((ext_vector_type(8)));

__device__ __forceinline__ ushort f2bf(float f) {
    unsigned u = __float_as_uint(f);
    unsigned r = (u + 0x7FFFu + ((u >> 16) & 1u)) >> 16;   // RNE
    return (ushort)r;
}
__device__ __forceinline__ float bf2f(ushort b) {
    return __uint_as_float(((unsigned)b) << 16);
}

// ---------------- CSR build: histogram, inv-sqrt degree, hierarchical scan, fill ----------------

__global__ void cnt_zero_kernel(int* __restrict__ cnt) {
    int i = blockIdx.x * 256 + threadIdx.x;
    if (i < NN) cnt[i] = 0;
}

__global__ void cnt_count_kernel(int* __restrict__ cnt, const int* __restrict__ dst) {
    int e = blockIdx.x * 256 + threadIdx.x;
    if (e < NE) atomicAdd(&cnt[dst[e]], 1);
}

__global__ void inv_kernel(const int* __restrict__ cnt, float* __restrict__ inv) {
    int i = blockIdx.x * 256 + threadIdx.x;
    if (i < NN) inv[i] = rsqrtf((float)(cnt[i] + 1));   // +1 self-loop
}

// scan stage 1: per-block sums of 256 counts
__global__ __launch_bounds__(256) void bsum_kernel(const int* __restrict__ cnt,
                                                   int* __restrict__ bsum) {
    __shared__ int sh[256];
    int i = blockIdx.x * 256 + threadIdx.x;
    sh[threadIdx.x] = (i < NN) ? cnt[i] : 0;
    __syncthreads();
    #pragma unroll
    for (int off = 128; off > 0; off >>= 1) {
        if (threadIdx.x < off) sh[threadIdx.x] += sh[threadIdx.x + off];
        __syncthreads();
    }
    if (threadIdx.x == 0) bsum[blockIdx.x] = sh[0];
}

// scan stage 2: exclusive scan of the NBLK_S partials (single small block)
__global__ __launch_bounds__(256) void bscan_kernel(int* __restrict__ bsum) {
    __shared__ int sh[256];
    int t = threadIdx.x;
    int v = (t < NBLK_S) ? bsum[t] : 0;
    sh[t] = v;
    __syncthreads();
    #pragma unroll
    for (int off = 1; off < 256; off <<= 1) {
        int u = (t >= off) ? sh[t - off] : 0;
        __syncthreads();
        sh[t] += u;
        __syncthreads();
    }
    if (t < NBLK_S) bsum[t] = sh[t] - v;   // exclusive
}

// scan stage 3: in-block exclusive scan + block offset -> row_start, cursor
__global__ __launch_bounds__(256) void emit_kernel(const int* __restrict__ cnt,
                                                   const int* __restrict__ bsum,
                                                   int* __restrict__ row_start,
                                                   int* __restrict__ cursor) {
    __shared__ int sh[256];
    int i = blockIdx.x * 256 + threadIdx.x;
    int v = (i < NN) ? cnt[i] : 0;
    sh[threadIdx.x] = v;
    __syncthreads();
    #pragma unroll
    for (int off = 1; off < 256; off <<= 1) {
        int u = (threadIdx.x >= off) ? sh[threadIdx.x - off] : 0;
        __syncthreads();
        sh[threadIdx.x] += u;
        __syncthreads();
    }
    int pos = bsum[blockIdx.x] + sh[threadIdx.x] - v;   // exclusive prefix
    if (i <= NN) row_start[i] = pos;                    // i==NN -> NE
    if (i < NN)  cursor[i]    = pos;
}

__global__ void fill_kernel(const int* __restrict__ src, const int* __restrict__ dst,
                            const float* __restrict__ inv,
                            int* __restrict__ cursor, float2* __restrict__ edata) {
    int e = blockIdx.x * 256 + threadIdx.x;
    if (e >= NE) return;
    int s = src[e];
    int d = dst[e];
    int pos = atomicAdd(&cursor[d], 1);
    edata[pos] = make_float2(__int_as_float(s), inv[s] * inv[d]);
}

// ---------------- weight split / transpose ----------------

__global__ void wsplit_kernel(const float* __restrict__ W, int K, int N,
                              ushort* __restrict__ WtH, ushort* __restrict__ WtL) {
    int idx = blockIdx.x * 256 + threadIdx.x;
    if (idx >= K * N) return;
    int n = idx % N;
    int k = idx / N;
    float f = W[idx];
    ushort h = f2bf(f);
    WtH[(size_t)n * K + k] = h;
    if (WtL) WtL[(size_t)n * K + k] = f2bf(f - bf2f(h));
}

// ---------------- MFMA GEMM: out_bf16 = A @ Bt^T ----------------
// 128x128 tile, 4 waves (2x2), each wave 64x64 via 4x4 frags of 16x16x32.
// TERMS=3: Ah*Bh + Ah*Bl + Al*Bh (split fp32-accurate); TERMS=1: Ah*Bh (bf16).

template<int TERMS, bool BIAS_RELU>
__global__ __launch_bounds__(256) void gemm_mfma_kernel(
    const ushort* __restrict__ AH, const ushort* __restrict__ AL,
    const ushort* __restrict__ BH, const ushort* __restrict__ BL,
    const float* __restrict__ bias,
    ushort* __restrict__ outB,
    int M, int K) {
    constexpr int NARR = (TERMS == 3) ? 4 : 2;
    __shared__ ushort smem[NARR * 128 * 40];   // pad 40 -> spread banks
    ushort* Ah = smem;
    ushort* Bh = smem + 128 * 40;
    ushort* Al = (TERMS == 3) ? smem + 2 * 128 * 40 : nullptr;
    ushort* Bl = (TERMS == 3) ? smem + 3 * 128 * 40 : nullptr;

    const int tid  = threadIdx.x;
    const int lane = tid & 63;
    const int w    = tid >> 6;
    const int wr   = w >> 1;
    const int wc   = w & 1;
    const int row0 = blockIdx.x * 128;
    const int col0 = blockIdx.y * 128;

    f32x4 acc[4][4] = {};

    for (int k0 = 0; k0 < K; k0 += 32) {
        #pragma unroll
        for (int i = 0; i < 2; ++i) {
            int c  = i * 256 + tid;
            int r  = c >> 2;          // 0..127
            int cb = c & 3;           // 16B chunk
            int gr = row0 + r;
            uint4 vh = make_uint4(0u, 0u, 0u, 0u);
            if (gr < M)
                vh = *reinterpret_cast<const uint4*>(AH + (size_t)gr * K + k0 + cb * 8);
            *reinterpret_cast<uint4*>(&Ah[r * 40 + cb * 8]) = vh;
            *reinterpret_cast<uint4*>(&Bh[r * 40 + cb * 8]) =
                *reinterpret_cast<const uint4*>(BH + (size_t)(col0 + r) * K + k0 + cb * 8);
            if (TERMS == 3) {
                uint4 vl = make_uint4(0u, 0u, 0u, 0u);
                if (gr < M)
                    vl = *reinterpret_cast<const uint4*>(AL + (size_t)gr * K + k0 + cb * 8);
                *reinterpret_cast<uint4*>(&Al[r * 40 + cb * 8]) = vl;
                *reinterpret_cast<uint4*>(&Bl[r * 40 + cb * 8]) =
                    *reinterpret_cast<const uint4*>(BL + (size_t)(col0 + r) * K + k0 + cb * 8);
            }
        }
        __syncthreads();

        const int rsel = lane & 15;
        const int ksel = (lane >> 4) * 8;
        bf16x8 ah[4], bh[4];
        #pragma unroll
        for (int m = 0; m < 4; ++m)
            ah[m] = *reinterpret_cast<const bf16x8*>(&Ah[(wr * 64 + m * 16 + rsel) * 40 + ksel]);
        #pragma unroll
        for (int n = 0; n < 4; ++n)
            bh[n] = *reinterpret_cast<const bf16x8*>(&Bh[(wc * 64 + n * 16 + rsel) * 40 + ksel]);

        if (TERMS == 3) {
            bf16x8 al[4], bl[4];
            #pragma unroll
            for (int m = 0; m < 4; ++m)
                al[m] = *reinterpret_cast<const bf16x8*>(&Al[(wr * 64 + m * 16 + rsel) * 40 + ksel]);
            #pragma unroll
            for (int n = 0; n < 4; ++n)
                bl[n] = *reinterpret_cast<const bf16x8*>(&Bl[(wc * 64 + n * 16 + rsel) * 40 + ksel]);
            #pragma unroll
            for (int m = 0; m < 4; ++m)
                #pragma unroll
                for (int n = 0; n < 4; ++n) {
                    acc[m][n] = __builtin_amdgcn_mfma_f32_16x16x32_bf16(ah[m], bh[n], acc[m][n], 0, 0, 0);
                    acc[m][n] = __builtin_amdgcn_mfma_f32_16x16x32_bf16(ah[m], bl[n], acc[m][n], 0, 0, 0);
                    acc[m][n] = __builtin_amdgcn_mfma_f32_16x16x32_bf16(al[m], bh[n], acc[m][n], 0, 0, 0);
                }
        } else {
            #pragma unroll
            for (int m = 0; m < 4; ++m)
                #pragma unroll
                for (int n = 0; n < 4; ++n)
                    acc[m][n] = __builtin_amdgcn_mfma_f32_16x16x32_bf16(ah[m], bh[n], acc[m][n], 0, 0, 0);
        }
        __syncthreads();
    }

    // epilogue: C/D layout col=lane&15, row=4*(lane>>4)+i
    const int cl = lane & 15;
    const int rg = lane >> 4;
    #pragma unroll
    for (int m = 0; m < 4; ++m) {
        #pragma unroll
        for (int i = 0; i < 4; ++i) {
            int gr = row0 + wr * 64 + m * 16 + rg * 4 + i;
            if (gr < M) {
                #pragma unroll
                for (int n = 0; n < 4; ++n) {
                    int gc = col0 + wc * 64 + n * 16 + cl;
                    float o = acc[m][n][i];
                    if (BIAS_RELU) o = fmaxf(o + bias[gc], 0.0f);
                    outB[(size_t)gr * FH + gc] = f2bf(o);
                }
            }
        }
    }
}

// ---------------- gather_x (FIN=128): fp32 in, split-bf16 out (feeds 3-term GEMM0) ----------------
// Edge loop unrolled x4: batched wave-uniform edata loads + 4 independent row loads.

__global__ __launch_bounds__(256) void gather_x_kernel(const float* __restrict__ x,
                                                       const float2* __restrict__ edata,
                                                       const int* __restrict__ row_start,
                                                       const float* __restrict__ inv,
                                                       ushort* __restrict__ outH,
                                                       ushort* __restrict__ outL) {
    int node = blockIdx.x * 4 + (threadIdx.x >> 6);
    int lane = threadIdx.x & 63;
    if (node >= NN) return;

    int beg = row_start[node];
    int end = row_start[node + 1];

    float iv = inv[node];
    float c  = iv * iv;
    float2 v = *reinterpret_cast<const float2*>(x + (size_t)node * FIN + lane * 2);
    float2 a0 = make_float2(v.x * c, v.y * c);
    float2 a1 = make_float2(0.f, 0.f);
    float2 a2 = make_float2(0.f, 0.f);
    float2 a3 = make_float2(0.f, 0.f);

    int i = beg;
    int pre = (4 - (beg & 3)) & 3;
    int pe = beg + pre; if (pe > end) pe = end;
    for (; i < pe; ++i) {
        float2 ed = edata[i];
        float2 w = *reinterpret_cast<const float2*>(x + (size_t)__float_as_int(ed.x) * FIN + lane * 2);
        a0.x += w.x * ed.y; a0.y += w.y * ed.y;
    }
    for (; i + 4 <= end; i += 4) {
        float4 e01 = *reinterpret_cast<const float4*>(&edata[i]);       // 16B-aligned now
        float4 e23 = *reinterpret_cast<const float4*>(&edata[i + 2]);
        const float* p0 = x + (size_t)__float_as_int(e01.x) * FIN + lane * 2;
        const float* p1 = x + (size_t)__float_as_int(e01.z) * FIN + lane * 2;
        const float* p2 = x + (size_t)__float_as_int(e23.x) * FIN + lane * 2;
        const float* p3 = x + (size_t)__float_as_int(e23.z) * FIN + lane * 2;
        float2 w0 = *reinterpret_cast<const float2*>(p0);
        float2 w1 = *reinterpret_cast<const float2*>(p1);
        float2 w2 = *reinterpret_cast<const float2*>(p2);
        float2 w3 = *reinterpret_cast<const float2*>(p3);
        a0.x += w0.x * e01.y; a0.y += w0.y * e01.y;
        a1.x += w1.x * e01.w; a1.y += w1.y * e01.w;
        a2.x += w2.x * e23.y; a2.y += w2.y * e23.y;
        a3.x += w3.x * e23.w; a3.y += w3.y * e23.w;
    }
    for (; i < end; ++i) {
        float2 ed = edata[i];
        float2 w = *reinterpret_cast<const float2*>(x + (size_t)__float_as_int(ed.x) * FIN + lane * 2);
        a0.x += w.x * ed.y; a0.y += w.y * ed.y;
    }

    float ax = a0.x + a1.x + a2.x + a3.x;
    float ay = a0.y + a1.y + a2.y + a3.y;
    ushort h0 = f2bf(ax), h1 = f2bf(ay);
    ushort l0 = f2bf(ax - bf2f(h0)), l1 = f2bf(ay - bf2f(h1));
    size_t o = (size_t)node * FIN + lane * 2;
    *reinterpret_cast<ushort2*>(outH + o) = make_ushort2(h0, h1);
    *reinterpret_cast<ushort2*>(outL + o) = make_ushort2(l0, l1);
}

// ---------------- gather (FH=256): bf16 in, fp32 accumulate; x4 unroll ----------------

template<bool OUT_BF16>
__global__ __launch_bounds__(256) void gather_bf_kernel(const ushort* __restrict__ lin,
                                                        const float2* __restrict__ edata,
                                                        const int* __restrict__ row_start,
                                                        const float* __restrict__ inv,
                                                        const float* __restrict__ bias,
                                                        ushort* __restrict__ outB,
                                                        float* __restrict__ outF) {
    int node = blockIdx.x * 4 + (threadIdx.x >> 6);
    int lane = threadIdx.x & 63;
    if (node >= NN) return;

    int beg = row_start[node];
    int end = row_start[node + 1];

    float iv = inv[node];
    float c  = iv * iv;
    ushort4 sv = *reinterpret_cast<const ushort4*>(lin + (size_t)node * FH + lane * 4);
    float4 b = *reinterpret_cast<const float4*>(bias + lane * 4);
    float4 a0 = make_float4(bf2f(sv.x) * c + b.x, bf2f(sv.y) * c + b.y,
                            bf2f(sv.z) * c + b.z, bf2f(sv.w) * c + b.w);
    float4 a1 = make_float4(0.f, 0.f, 0.f, 0.f);
    float4 a2 = make_float4(0.f, 0.f, 0.f, 0.f);
    float4 a3 = make_float4(0.f, 0.f, 0.f, 0.f);

    int i = beg;
    int pre = (4 - (beg & 3)) & 3;
    int pe = beg + pre; if (pe > end) pe = end;
    for (; i < pe; ++i) {
        float2 ed = edata[i];
        float cf = ed.y;
        ushort4 wv = *reinterpret_cast<const ushort4*>(lin + (size_t)__float_as_int(ed.x) * FH + lane * 4);
        a0.x += bf2f(wv.x) * cf; a0.y += bf2f(wv.y) * cf;
        a0.z += bf2f(wv.z) * cf; a0.w += bf2f(wv.w) * cf;
    }
    for (; i + 4 <= end; i += 4) {
        float4 e01 = *reinterpret_cast<const float4*>(&edata[i]);       // 16B-aligned
        float4 e23 = *reinterpret_cast<const float4*>(&edata[i + 2]);
        const ushort* p0 = lin + (size_t)__float_as_int(e01.x) * FH + lane * 4;
        const ushort* p1 = lin + (size_t)__float_as_int(e01.z) * FH + lane * 4;
        const ushort* p2 = lin + (size_t)__float_as_int(e23.x) * FH + lane * 4;
        const ushort* p3 = lin + (size_t)__float_as_int(e23.z) * FH + lane * 4;
        ushort4 w0 = *reinterpret_cast<const ushort4*>(p0);
        ushort4 w1 = *reinterpret_cast<const ushort4*>(p1);
        ushort4 w2 = *reinterpret_cast<const ushort4*>(p2);
        ushort4 w3 = *reinterpret_cast<const ushort4*>(p3);
        a0.x += bf2f(w0.x) * e01.y; a0.y += bf2f(w0.y) * e01.y;
        a0.z += bf2f(w0.z) * e01.y; a0.w += bf2f(w0.w) * e01.y;
        a1.x += bf2f(w1.x) * e01.w; a1.y += bf2f(w1.y) * e01.w;
        a1.z += bf2f(w1.z) * e01.w; a1.w += bf2f(w1.w) * e01.w;
        a2.x += bf2f(w2.x) * e23.y; a2.y += bf2f(w2.y) * e23.y;
        a2.z += bf2f(w2.z) * e23.y; a2.w += bf2f(w2.w) * e23.y;
        a3.x += bf2f(w3.x) * e23.w; a3.y += bf2f(w3.y) * e23.w;
        a3.z += bf2f(w3.z) * e23.w; a3.w += bf2f(w3.w) * e23.w;
    }
    for (; i < end; ++i) {
        float2 ed = edata[i];
        float cf = ed.y;
        ushort4 wv = *reinterpret_cast<const ushort4*>(lin + (size_t)__float_as_int(ed.x) * FH + lane * 4);
        a0.x += bf2f(wv.x) * cf; a0.y += bf2f(wv.y) * cf;
        a0.z += bf2f(wv.z) * cf; a0.w += bf2f(wv.w) * cf;
    }

    float4 acc = make_float4(a0.x + a1.x + a2.x + a3.x,
                             a0.y + a1.y + a2.y + a3.y,
                             a0.z + a1.z + a2.z + a3.z,
                             a0.w + a1.w + a2.w + a3.w);

    if (OUT_BF16) {
        float r0 = fmaxf(acc.x, 0.f), r1 = fmaxf(acc.y, 0.f);
        float r2 = fmaxf(acc.z, 0.f), r3 = fmaxf(acc.w, 0.f);
        *reinterpret_cast<ushort4*>(outB + (size_t)node * FH + lane * 4) =
            make_ushort4(f2bf(r0), f2bf(r1), f2bf(r2), f2bf(r3));
    } else {
        *reinterpret_cast<float4*>(outF + (size_t)node * FH + lane * 4) = acc;
    }
}

// ---------------- mean pool + head ----------------

__global__ void colsum_zero_kernel(float* __restrict__ colsum) {
    colsum[threadIdx.x] = 0.0f;
}

__global__ void colsum_kernel(const float* __restrict__ h, float* __restrict__ colsum) {
    int f = threadIdx.x;
    int r0 = blockIdx.x * 256;
    int r1 = r0 + 256; if (r1 > NN) r1 = NN;
    float s = 0.0f;
    for (int r = r0; r < r1; ++r) s += h[(size_t)r * FH + f];
    unsafeAtomicAdd(&colsum[f], s);
}

__global__ void head_kernel(const float* __restrict__ colsum,
                            const float* __restrict__ Wh,
                            const float* __restrict__ bh,
                            float* __restrict__ out) {
    int o = threadIdx.x;
    if (o >= FOUT) return;
    const float scale = 1.0f / (float)NN;
    float s = 0.0f;
    for (int f = 0; f < FH; ++f)
        s += colsum[f] * scale * Wh[f * FOUT + o];
    out[o] = s + bh[o];
}

// ---------------- launch ----------------

extern "C" void kernel_launch(void* const* d_in, const int* in_sizes, int n_in,
                              void* d_out, int out_size, void* d_ws, size_t ws_size,
                              hipStream_t stream) {
    const float* x   = (const float*)d_in[0];
    const int*   ei  = (const int*)d_in[1];
    const float* W0  = (const float*)d_in[2];
    const float* b0  = (const float*)d_in[3];
    const float* W1  = (const float*)d_in[4];
    const float* b1  = (const float*)d_in[5];
    const float* W2  = (const float*)d_in[6];
    const float* b2  = (const float*)d_in[7];
    const float* Wh  = (const float*)d_in[8];
    const float* bh  = (const float*)d_in[9];
    float* out = (float*)d_out;

    const int* src = ei;        // edge_index[0,:]
    const int* dst = ei + NE;   // edge_index[1,:]

    // workspace layout (16B-aligned blocks)
    float*  inv       = (float*)d_ws;                   // NPAD
    int*    cnt       = (int*)(inv + NPAD);             // NPAD
    int*    row_start = cnt + NPAD;                     // NN+1 used
    int*    cursor    = row_start + NPAD;               // NN used
    int*    bsum      = cursor + NPAD;                  // 256 (NBLK_S used)
    float2* edata     = (float2*)(bsum + 256);          // NE (6.4 MB)
    float*  colsum    = (float*)(edata + NE);           // 256
    ushort* W0tH      = (ushort*)(colsum + 256);        // [256][128]
    ushort* W0tL      = W0tH + 256 * 128;
    ushort* W1tH      = W0tL + 256 * 128;               // [256][256]
    ushort* W2tH      = W1tH + 256 * 256;
    // aggx split planes (25.6 MB total) -> later reused as linb (bf16 lin1/lin2)
    ushort* aggxH     = W2tH + 256 * 256;               // [NN2][128]
    ushort* aggxL     = aggxH + (size_t)NN2 * 128;
    ushort* linb      = aggxH;                          // [NN2][256] bf16 (aggx dead)
    // h0 plane (25.6 MB) -> later reused as a1 plane
    ushort* h0H       = aggxL + (size_t)NN2 * 128;      // [NN2][256]
    ushort* a1H       = h0H;                            // (h0 dead after GEMM1)
    float*  acc2      = (float*)(h0H + (size_t)NN2 * 256);  // [NN2][256] fp32

    const int nblk_n = (NN + 255) / 256;
    const int nblk_e = (NE + 255) / 256;
    const dim3 gemm_grid((NN + 127) / 128, 2);
    const int nblk_g = (NN + 3) / 4;

    // ---- CSR build + weight split ----
    cnt_zero_kernel<<<nblk_n, 256, 0, stream>>>(cnt);
    cnt_count_kernel<<<nblk_e, 256, 0, stream>>>(cnt, dst);
    inv_kernel<<<nblk_n, 256, 0, stream>>>(cnt, inv);
    bsum_kernel<<<NBLK_S, 256, 0, stream>>>(cnt, bsum);
    bscan_kernel<<<1, 256, 0, stream>>>(bsum);
    emit_kernel<<<NBLK_S, 256, 0, stream>>>(cnt, bsum, row_start, cursor);
    fill_kernel<<<nblk_e, 256, 0, stream>>>(src, dst, inv, cursor, edata);
    wsplit_kernel<<<(FIN * FH + 255) / 256, 256, 0, stream>>>(W0, FIN, FH, W0tH, W0tL);
    wsplit_kernel<<<(FH * FH + 255) / 256, 256, 0, stream>>>(W1, FH, FH, W1tH, nullptr);
    wsplit_kernel<<<(FH * FH + 255) / 256, 256, 0, stream>>>(W2, FH, FH, W2tH, nullptr);

    // layer 0: aggx = agg(x) [split]; h0 = bf16(relu(aggx @ W0 + b0))   (3-term, fp32-accurate)
    gather_x_kernel<<<nblk_g, 256, 0, stream>>>(x, edata, row_start, inv, aggxH, aggxL);
    gemm_mfma_kernel<3, true><<<gemm_grid, 256, 0, stream>>>(aggxH, aggxL, W0tH, W0tL, b0,
                                                             h0H, NN, FIN);

    // layer 1: lin1 = bf16(h0 @ W1); a1 = bf16(relu(agg(lin1) + b1))
    gemm_mfma_kernel<1, false><<<gemm_grid, 256, 0, stream>>>(h0H, nullptr, W1tH, nullptr, nullptr,
                                                              linb, NN, FH);
    gather_bf_kernel<true><<<nblk_g, 256, 0, stream>>>(linb, edata, row_start, inv, b1,
                                                       a1H, nullptr);

    // layer 2: lin2 = bf16(a1 @ W2); acc2 = agg(lin2) + b2 (fp32)
    gemm_mfma_kernel<1, false><<<gemm_grid, 256, 0, stream>>>(a1H, nullptr, W2tH, nullptr, nullptr,
                                                              linb, NN, FH);
    gather_bf_kernel<false><<<nblk_g, 256, 0, stream>>>(linb, edata, row_start, inv, b2,
                                                        nullptr, acc2);

    // global mean pool + head
    colsum_zero_kernel<<<1, 256, 0, stream>>>(colsum);
    colsum_kernel<<<(NN + 255) / 256, 256, 0, stream>>>(acc2, colsum);
    head_kernel<<<1, 64, 0, stream>>>(colsum, Wh, bh, out);
}

// Round 8
// 361.617 us; speedup vs baseline: 2.5045x; 1.2003x over previous
//
#include <hip/hip_runtime.h>

#define NN 50000
#define NE 800000
#define FIN 128
#define FH 256
#define FOUT 40
#define NPAD 50432   // > NN+1, multiple of 64
#define NN2 50048    // NN rounded up to 128
#define NBLK_S 196   // ceil((NN+1)/256)

typedef float f32x4 __attribute__((ext_vector_type(4)));
typedef short bf16x8 __attribute__((ext_vector_type(8)));

__device__ __forceinline__ ushort f2bf(float f) {
    unsigned u = __float_as_uint(f);
    unsigned r = (u + 0x7FFFu + ((u >> 16) & 1u)) >> 16;   // RNE
    return (ushort)r;
}
__device__ __forceinline__ float bf2f(ushort b) {
    return __uint_as_float(((unsigned)b) << 16);
}

// ---------------- CSR build: histogram, inv-sqrt degree, hierarchical scan, fill ----------------

__global__ void cnt_zero_kernel(int* __restrict__ cnt, float* __restrict__ wsum) {
    int i = blockIdx.x * 256 + threadIdx.x;
    if (i < NN) { cnt[i] = 0; wsum[i] = 0.0f; }
}

__global__ void cnt_count_kernel(int* __restrict__ cnt, const int* __restrict__ dst) {
    int e = blockIdx.x * 256 + threadIdx.x;
    if (e < NE) atomicAdd(&cnt[dst[e]], 1);
}

__global__ void inv_kernel(const int* __restrict__ cnt, float* __restrict__ inv) {
    int i = blockIdx.x * 256 + threadIdx.x;
    if (i < NN) inv[i] = rsqrtf((float)(cnt[i] + 1));   // +1 self-loop
}

// scan stage 1: per-block sums of 256 counts
__global__ __launch_bounds__(256) void bsum_kernel(const int* __restrict__ cnt,
                                                   int* __restrict__ bsum) {
    __shared__ int sh[256];
    int i = blockIdx.x * 256 + threadIdx.x;
    sh[threadIdx.x] = (i < NN) ? cnt[i] : 0;
    __syncthreads();
    #pragma unroll
    for (int off = 128; off > 0; off >>= 1) {
        if (threadIdx.x < off) sh[threadIdx.x] += sh[threadIdx.x + off];
        __syncthreads();
    }
    if (threadIdx.x == 0) bsum[blockIdx.x] = sh[0];
}

// scan stage 2: exclusive scan of the NBLK_S partials (single small block)
__global__ __launch_bounds__(256) void bscan_kernel(int* __restrict__ bsum) {
    __shared__ int sh[256];
    int t = threadIdx.x;
    int v = (t < NBLK_S) ? bsum[t] : 0;
    sh[t] = v;
    __syncthreads();
    #pragma unroll
    for (int off = 1; off < 256; off <<= 1) {
        int u = (t >= off) ? sh[t - off] : 0;
        __syncthreads();
        sh[t] += u;
        __syncthreads();
    }
    if (t < NBLK_S) bsum[t] = sh[t] - v;   // exclusive
}

// scan stage 3: in-block exclusive scan + block offset -> row_start, cursor
__global__ __launch_bounds__(256) void emit_kernel(const int* __restrict__ cnt,
                                                   const int* __restrict__ bsum,
                                                   int* __restrict__ row_start,
                                                   int* __restrict__ cursor) {
    __shared__ int sh[256];
    int i = blockIdx.x * 256 + threadIdx.x;
    int v = (i < NN) ? cnt[i] : 0;
    sh[threadIdx.x] = v;
    __syncthreads();
    #pragma unroll
    for (int off = 1; off < 256; off <<= 1) {
        int u = (threadIdx.x >= off) ? sh[threadIdx.x - off] : 0;
        __syncthreads();
        sh[threadIdx.x] += u;
        __syncthreads();
    }
    int pos = bsum[blockIdx.x] + sh[threadIdx.x] - v;   // exclusive prefix
    if (i <= NN) row_start[i] = pos;                    // i==NN -> NE
    if (i < NN)  cursor[i]    = pos;
}

// also accumulates wsum[src] += coef (for the collapsed final layer)
__global__ void fill_kernel(const int* __restrict__ src, const int* __restrict__ dst,
                            const float* __restrict__ inv,
                            int* __restrict__ cursor, float2* __restrict__ edata,
                            float* __restrict__ wsum) {
    int e = blockIdx.x * 256 + threadIdx.x;
    if (e >= NE) return;
    int s = src[e];
    int d = dst[e];
    float coef = inv[s] * inv[d];
    int pos = atomicAdd(&cursor[d], 1);
    edata[pos] = make_float2(__int_as_float(s), coef);
    unsafeAtomicAdd(&wsum[s], coef);
}

// ---------------- weight split / transpose ----------------

__global__ void wsplit_kernel(const float* __restrict__ W, int K, int N,
                              ushort* __restrict__ WtH, ushort* __restrict__ WtL) {
    int idx = blockIdx.x * 256 + threadIdx.x;
    if (idx >= K * N) return;
    int n = idx % N;
    int k = idx / N;
    float f = W[idx];
    ushort h = f2bf(f);
    WtH[(size_t)n * K + k] = h;
    if (WtL) WtL[(size_t)n * K + k] = f2bf(f - bf2f(h));
}

// ---------------- MFMA GEMM: out_bf16 = A @ Bt^T ----------------
// 128x128 tile, 4 waves (2x2), each wave 64x64 via 4x4 frags of 16x16x32.
// TERMS=3: Ah*Bh + Ah*Bl + Al*Bh (split fp32-accurate); TERMS=1: Ah*Bh (bf16).

template<int TERMS, bool BIAS_RELU>
__global__ __launch_bounds__(256) void gemm_mfma_kernel(
    const ushort* __restrict__ AH, const ushort* __restrict__ AL,
    const ushort* __restrict__ BH, const ushort* __restrict__ BL,
    const float* __restrict__ bias,
    ushort* __restrict__ outB,
    int M, int K) {
    constexpr int NARR = (TERMS == 3) ? 4 : 2;
    __shared__ ushort smem[NARR * 128 * 40];   // pad 40 -> spread banks
    ushort* Ah = smem;
    ushort* Bh = smem + 128 * 40;
    ushort* Al = (TERMS == 3) ? smem + 2 * 128 * 40 : nullptr;
    ushort* Bl = (TERMS == 3) ? smem + 3 * 128 * 40 : nullptr;

    const int tid  = threadIdx.x;
    const int lane = tid & 63;
    const int w    = tid >> 6;
    const int wr   = w >> 1;
    const int wc   = w & 1;
    const int row0 = blockIdx.x * 128;
    const int col0 = blockIdx.y * 128;

    f32x4 acc[4][4] = {};

    for (int k0 = 0; k0 < K; k0 += 32) {
        #pragma unroll
        for (int i = 0; i < 2; ++i) {
            int c  = i * 256 + tid;
            int r  = c >> 2;          // 0..127
            int cb = c & 3;           // 16B chunk
            int gr = row0 + r;
            uint4 vh = make_uint4(0u, 0u, 0u, 0u);
            if (gr < M)
                vh = *reinterpret_cast<const uint4*>(AH + (size_t)gr * K + k0 + cb * 8);
            *reinterpret_cast<uint4*>(&Ah[r * 40 + cb * 8]) = vh;
            *reinterpret_cast<uint4*>(&Bh[r * 40 + cb * 8]) =
                *reinterpret_cast<const uint4*>(BH + (size_t)(col0 + r) * K + k0 + cb * 8);
            if (TERMS == 3) {
                uint4 vl = make_uint4(0u, 0u, 0u, 0u);
                if (gr < M)
                    vl = *reinterpret_cast<const uint4*>(AL + (size_t)gr * K + k0 + cb * 8);
                *reinterpret_cast<uint4*>(&Al[r * 40 + cb * 8]) = vl;
                *reinterpret_cast<uint4*>(&Bl[r * 40 + cb * 8]) =
                    *reinterpret_cast<const uint4*>(BL + (size_t)(col0 + r) * K + k0 + cb * 8);
            }
        }
        __syncthreads();

        const int rsel = lane & 15;
        const int ksel = (lane >> 4) * 8;
        bf16x8 ah[4], bh[4];
        #pragma unroll
        for (int m = 0; m < 4; ++m)
            ah[m] = *reinterpret_cast<const bf16x8*>(&Ah[(wr * 64 + m * 16 + rsel) * 40 + ksel]);
        #pragma unroll
        for (int n = 0; n < 4; ++n)
            bh[n] = *reinterpret_cast<const bf16x8*>(&Bh[(wc * 64 + n * 16 + rsel) * 40 + ksel]);

        if (TERMS == 3) {
            bf16x8 al[4], bl[4];
            #pragma unroll
            for (int m = 0; m < 4; ++m)
                al[m] = *reinterpret_cast<const bf16x8*>(&Al[(wr * 64 + m * 16 + rsel) * 40 + ksel]);
            #pragma unroll
            for (int n = 0; n < 4; ++n)
                bl[n] = *reinterpret_cast<const bf16x8*>(&Bl[(wc * 64 + n * 16 + rsel) * 40 + ksel]);
            #pragma unroll
            for (int m = 0; m < 4; ++m)
                #pragma unroll
                for (int n = 0; n < 4; ++n) {
                    acc[m][n] = __builtin_amdgcn_mfma_f32_16x16x32_bf16(ah[m], bh[n], acc[m][n], 0, 0, 0);
                    acc[m][n] = __builtin_amdgcn_mfma_f32_16x16x32_bf16(ah[m], bl[n], acc[m][n], 0, 0, 0);
                    acc[m][n] = __builtin_amdgcn_mfma_f32_16x16x32_bf16(al[m], bh[n], acc[m][n], 0, 0, 0);
                }
        } else {
            #pragma unroll
            for (int m = 0; m < 4; ++m)
                #pragma unroll
                for (int n = 0; n < 4; ++n)
                    acc[m][n] = __builtin_amdgcn_mfma_f32_16x16x32_bf16(ah[m], bh[n], acc[m][n], 0, 0, 0);
        }
        __syncthreads();
    }

    // epilogue: C/D layout col=lane&15, row=4*(lane>>4)+i
    const int cl = lane & 15;
    const int rg = lane >> 4;
    #pragma unroll
    for (int m = 0; m < 4; ++m) {
        #pragma unroll
        for (int i = 0; i < 4; ++i) {
            int gr = row0 + wr * 64 + m * 16 + rg * 4 + i;
            if (gr < M) {
                #pragma unroll
                for (int n = 0; n < 4; ++n) {
                    int gc = col0 + wc * 64 + n * 16 + cl;
                    float o = acc[m][n][i];
                    if (BIAS_RELU) o = fmaxf(o + bias[gc], 0.0f);
                    outB[(size_t)gr * FH + gc] = f2bf(o);
                }
            }
        }
    }
}

// ---------------- gather_x (FIN=128): fp32 in, split-bf16 out (feeds 3-term GEMM0) ----------------
// Edge loop unrolled x4: batched wave-uniform edata loads + 4 independent row loads.

__global__ __launch_bounds__(256) void gather_x_kernel(const float* __restrict__ x,
                                                       const float2* __restrict__ edata,
                                                       const int* __restrict__ row_start,
                                                       const float* __restrict__ inv,
                                                       ushort* __restrict__ outH,
                                                       ushort* __restrict__ outL) {
    int node = blockIdx.x * 4 + (threadIdx.x >> 6);
    int lane = threadIdx.x & 63;
    if (node >= NN) return;

    int beg = row_start[node];
    int end = row_start[node + 1];

    float iv = inv[node];
    float c  = iv * iv;
    float2 v = *reinterpret_cast<const float2*>(x + (size_t)node * FIN + lane * 2);
    float2 a0 = make_float2(v.x * c, v.y * c);
    float2 a1 = make_float2(0.f, 0.f);
    float2 a2 = make_float2(0.f, 0.f);
    float2 a3 = make_float2(0.f, 0.f);

    int i = beg;
    int pre = (4 - (beg & 3)) & 3;
    int pe = beg + pre; if (pe > end) pe = end;
    for (; i < pe; ++i) {
        float2 ed = edata[i];
        float2 w = *reinterpret_cast<const float2*>(x + (size_t)__float_as_int(ed.x) * FIN + lane * 2);
        a0.x += w.x * ed.y; a0.y += w.y * ed.y;
    }
    for (; i + 4 <= end; i += 4) {
        float4 e01 = *reinterpret_cast<const float4*>(&edata[i]);       // 16B-aligned
        float4 e23 = *reinterpret_cast<const float4*>(&edata[i + 2]);
        const float* p0 = x + (size_t)__float_as_int(e01.x) * FIN + lane * 2;
        const float* p1 = x + (size_t)__float_as_int(e01.z) * FIN + lane * 2;
        const float* p2 = x + (size_t)__float_as_int(e23.x) * FIN + lane * 2;
        const float* p3 = x + (size_t)__float_as_int(e23.z) * FIN + lane * 2;
        float2 w0 = *reinterpret_cast<const float2*>(p0);
        float2 w1 = *reinterpret_cast<const float2*>(p1);
        float2 w2 = *reinterpret_cast<const float2*>(p2);
        float2 w3 = *reinterpret_cast<const float2*>(p3);
        a0.x += w0.x * e01.y; a0.y += w0.y * e01.y;
        a1.x += w1.x * e01.w; a1.y += w1.y * e01.w;
        a2.x += w2.x * e23.y; a2.y += w2.y * e23.y;
        a3.x += w3.x * e23.w; a3.y += w3.y * e23.w;
    }
    for (; i < end; ++i) {
        float2 ed = edata[i];
        float2 w = *reinterpret_cast<const float2*>(x + (size_t)__float_as_int(ed.x) * FIN + lane * 2);
        a0.x += w.x * ed.y; a0.y += w.y * ed.y;
    }

    float ax = a0.x + a1.x + a2.x + a3.x;
    float ay = a0.y + a1.y + a2.y + a3.y;
    ushort h0 = f2bf(ax), h1 = f2bf(ay);
    ushort l0 = f2bf(ax - bf2f(h0)), l1 = f2bf(ay - bf2f(h1));
    size_t o = (size_t)node * FIN + lane * 2;
    *reinterpret_cast<ushort2*>(outH + o) = make_ushort2(h0, h1);
    *reinterpret_cast<ushort2*>(outL + o) = make_ushort2(l0, l1);
}

// ---------------- gather (FH=256): bf16 in, fp32 accumulate; x4 unroll; bf16 relu out ----------------

__global__ __launch_bounds__(256) void gather_bf_kernel(const ushort* __restrict__ lin,
                                                        const float2* __restrict__ edata,
                                                        const int* __restrict__ row_start,
                                                        const float* __restrict__ inv,
                                                        const float* __restrict__ bias,
                                                        ushort* __restrict__ outB) {
    int node = blockIdx.x * 4 + (threadIdx.x >> 6);
    int lane = threadIdx.x & 63;
    if (node >= NN) return;

    int beg = row_start[node];
    int end = row_start[node + 1];

    float iv = inv[node];
    float c  = iv * iv;
    ushort4 sv = *reinterpret_cast<const ushort4*>(lin + (size_t)node * FH + lane * 4);
    float4 b = *reinterpret_cast<const float4*>(bias + lane * 4);
    float4 a0 = make_float4(bf2f(sv.x) * c + b.x, bf2f(sv.y) * c + b.y,
                            bf2f(sv.z) * c + b.z, bf2f(sv.w) * c + b.w);
    float4 a1 = make_float4(0.f, 0.f, 0.f, 0.f);
    float4 a2 = make_float4(0.f, 0.f, 0.f, 0.f);
    float4 a3 = make_float4(0.f, 0.f, 0.f, 0.f);

    int i = beg;
    int pre = (4 - (beg & 3)) & 3;
    int pe = beg + pre; if (pe > end) pe = end;
    for (; i < pe; ++i) {
        float2 ed = edata[i];
        float cf = ed.y;
        ushort4 wv = *reinterpret_cast<const ushort4*>(lin + (size_t)__float_as_int(ed.x) * FH + lane * 4);
        a0.x += bf2f(wv.x) * cf; a0.y += bf2f(wv.y) * cf;
        a0.z += bf2f(wv.z) * cf; a0.w += bf2f(wv.w) * cf;
    }
    for (; i + 4 <= end; i += 4) {
        float4 e01 = *reinterpret_cast<const float4*>(&edata[i]);       // 16B-aligned
        float4 e23 = *reinterpret_cast<const float4*>(&edata[i + 2]);
        const ushort* p0 = lin + (size_t)__float_as_int(e01.x) * FH + lane * 4;
        const ushort* p1 = lin + (size_t)__float_as_int(e01.z) * FH + lane * 4;
        const ushort* p2 = lin + (size_t)__float_as_int(e23.x) * FH + lane * 4;
        const ushort* p3 = lin + (size_t)__float_as_int(e23.z) * FH + lane * 4;
        ushort4 w0 = *reinterpret_cast<const ushort4*>(p0);
        ushort4 w1 = *reinterpret_cast<const ushort4*>(p1);
        ushort4 w2 = *reinterpret_cast<const ushort4*>(p2);
        ushort4 w3 = *reinterpret_cast<const ushort4*>(p3);
        a0.x += bf2f(w0.x) * e01.y; a0.y += bf2f(w0.y) * e01.y;
        a0.z += bf2f(w0.z) * e01.y; a0.w += bf2f(w0.w) * e01.y;
        a1.x += bf2f(w1.x) * e01.w; a1.y += bf2f(w1.y) * e01.w;
        a1.z += bf2f(w1.z) * e01.w; a1.w += bf2f(w1.w) * e01.w;
        a2.x += bf2f(w2.x) * e23.y; a2.y += bf2f(w2.y) * e23.y;
        a2.z += bf2f(w2.z) * e23.y; a2.w += bf2f(w2.w) * e23.y;
        a3.x += bf2f(w3.x) * e23.w; a3.y += bf2f(w3.y) * e23.w;
        a3.z += bf2f(w3.z) * e23.w; a3.w += bf2f(w3.w) * e23.w;
    }
    for (; i < end; ++i) {
        float2 ed = edata[i];
        float cf = ed.y;
        ushort4 wv = *reinterpret_cast<const ushort4*>(lin + (size_t)__float_as_int(ed.x) * FH + lane * 4);
        a0.x += bf2f(wv.x) * cf; a0.y += bf2f(wv.y) * cf;
        a0.z += bf2f(wv.z) * cf; a0.w += bf2f(wv.w) * cf;
    }

    float4 acc = make_float4(a0.x + a1.x + a2.x + a3.x,
                             a0.y + a1.y + a2.y + a3.y,
                             a0.z + a1.z + a2.z + a3.z,
                             a0.w + a1.w + a2.w + a3.w);

    float r0 = fmaxf(acc.x, 0.f), r1 = fmaxf(acc.y, 0.f);
    float r2 = fmaxf(acc.z, 0.f), r3 = fmaxf(acc.w, 0.f);
    *reinterpret_cast<ushort4*>(outB + (size_t)node * FH + lane * 4) =
        make_ushort4(f2bf(r0), f2bf(r1), f2bf(r2), f2bf(r3));
}

// ---------------- collapsed layer 2 + mean pool: v[f] = sum_n w_n * a1[n][f] ----------------
// w_n = inv[n]^2 + wsum[n] (total outgoing edge weight + self-loop weight).

__global__ void vzero_kernel(float* __restrict__ v) {
    v[threadIdx.x] = 0.0f;
}

__global__ __launch_bounds__(256) void colsumw_kernel(const ushort* __restrict__ a1,
                                                      const float* __restrict__ wsum,
                                                      const float* __restrict__ inv,
                                                      float* __restrict__ v) {
    __shared__ float sh[4][256];
    int wid  = threadIdx.x >> 6;
    int lane = threadIdx.x & 63;
    int r0 = blockIdx.x * 256;
    int r1 = r0 + 256; if (r1 > NN) r1 = NN;

    float4 acc = make_float4(0.f, 0.f, 0.f, 0.f);
    for (int r = r0 + wid; r < r1; r += 4) {
        float iv = inv[r];
        float wr = wsum[r] + iv * iv;
        ushort4 u = *reinterpret_cast<const ushort4*>(a1 + (size_t)r * FH + lane * 4);
        acc.x += bf2f(u.x) * wr;
        acc.y += bf2f(u.y) * wr;
        acc.z += bf2f(u.z) * wr;
        acc.w += bf2f(u.w) * wr;
    }
    *reinterpret_cast<float4*>(&sh[wid][lane * 4]) = acc;
    __syncthreads();
    if (wid == 0) {
        float4 s1 = *reinterpret_cast<const float4*>(&sh[1][lane * 4]);
        float4 s2 = *reinterpret_cast<const float4*>(&sh[2][lane * 4]);
        float4 s3 = *reinterpret_cast<const float4*>(&sh[3][lane * 4]);
        unsafeAtomicAdd(&v[lane * 4 + 0], acc.x + s1.x + s2.x + s3.x);
        unsafeAtomicAdd(&v[lane * 4 + 1], acc.y + s1.y + s2.y + s3.y);
        unsafeAtomicAdd(&v[lane * 4 + 2], acc.z + s1.z + s2.z + s3.z);
        unsafeAtomicAdd(&v[lane * 4 + 3], acc.w + s1.w + s2.w + s3.w);
    }
}

// out = ((v/NN) @ W2 + b2) @ Wh + bh
__global__ __launch_bounds__(256) void head2_kernel(const float* __restrict__ v,
                                                    const float* __restrict__ W2,
                                                    const float* __restrict__ b2,
                                                    const float* __restrict__ Wh,
                                                    const float* __restrict__ bh,
                                                    float* __restrict__ out) {
    __shared__ float m[FH];
    int t = threadIdx.x;
    const float scale = 1.0f / (float)NN;
    float s = 0.0f;
    for (int f = 0; f < FH; ++f)
        s += v[f] * W2[f * FH + t];
    m[t] = s * scale + b2[t];
    __syncthreads();
    if (t < FOUT) {
        float o = 0.0f;
        for (int f = 0; f < FH; ++f)
            o += m[f] * Wh[f * FOUT + t];
        out[t] = o + bh[t];
    }
}

// ---------------- launch ----------------

extern "C" void kernel_launch(void* const* d_in, const int* in_sizes, int n_in,
                              void* d_out, int out_size, void* d_ws, size_t ws_size,
                              hipStream_t stream) {
    const float* x   = (const float*)d_in[0];
    const int*   ei  = (const int*)d_in[1];
    const float* W0  = (const float*)d_in[2];
    const float* b0  = (const float*)d_in[3];
    const float* W1  = (const float*)d_in[4];
    const float* b1  = (const float*)d_in[5];
    const float* W2  = (const float*)d_in[6];
    const float* b2  = (const float*)d_in[7];
    const float* Wh  = (const float*)d_in[8];
    const float* bh  = (const float*)d_in[9];
    float* out = (float*)d_out;

    const int* src = ei;        // edge_index[0,:]
    const int* dst = ei + NE;   // edge_index[1,:]

    // workspace layout (16B-aligned blocks)
    float*  inv       = (float*)d_ws;                   // NPAD
    int*    cnt       = (int*)(inv + NPAD);             // NPAD
    int*    row_start = cnt + NPAD;                     // NN+1 used
    int*    cursor    = row_start + NPAD;               // NN used
    int*    bsum      = cursor + NPAD;                  // 256 (NBLK_S used)
    float*  wsum      = (float*)(bsum + 256);           // NPAD
    float2* edata     = (float2*)(wsum + NPAD);         // NE (6.4 MB)
    float*  vbuf      = (float*)(edata + NE);           // 256
    ushort* W0tH      = (ushort*)(vbuf + 256);          // [256][128]
    ushort* W0tL      = W0tH + 256 * 128;
    ushort* W1tH      = W0tL + 256 * 128;               // [256][256]
    // aggx split planes (25.6 MB total) -> later reused as linb (bf16 lin1)
    ushort* aggxH     = W1tH + 256 * 256;               // [NN2][128]
    ushort* aggxL     = aggxH + (size_t)NN2 * 128;
    ushort* linb      = aggxH;                          // [NN2][256] bf16 (aggx dead)
    // h0 plane (25.6 MB) -> later reused as a1 plane
    ushort* h0H       = aggxL + (size_t)NN2 * 128;      // [NN2][256]
    ushort* a1H       = h0H;                            // (h0 dead after GEMM1)

    const int nblk_n = (NN + 255) / 256;
    const int nblk_e = (NE + 255) / 256;
    const dim3 gemm_grid((NN + 127) / 128, 2);
    const int nblk_g = (NN + 3) / 4;

    // ---- CSR build + weight split ----
    cnt_zero_kernel<<<nblk_n, 256, 0, stream>>>(cnt, wsum);
    cnt_count_kernel<<<nblk_e, 256, 0, stream>>>(cnt, dst);
    inv_kernel<<<nblk_n, 256, 0, stream>>>(cnt, inv);
    bsum_kernel<<<NBLK_S, 256, 0, stream>>>(cnt, bsum);
    bscan_kernel<<<1, 256, 0, stream>>>(bsum);
    emit_kernel<<<NBLK_S, 256, 0, stream>>>(cnt, bsum, row_start, cursor);
    fill_kernel<<<nblk_e, 256, 0, stream>>>(src, dst, inv, cursor, edata, wsum);
    wsplit_kernel<<<(FIN * FH + 255) / 256, 256, 0, stream>>>(W0, FIN, FH, W0tH, W0tL);
    wsplit_kernel<<<(FH * FH + 255) / 256, 256, 0, stream>>>(W1, FH, FH, W1tH, nullptr);

    // layer 0: aggx = agg(x) [split]; h0 = bf16(relu(aggx @ W0 + b0))   (3-term, fp32-accurate)
    gather_x_kernel<<<nblk_g, 256, 0, stream>>>(x, edata, row_start, inv, aggxH, aggxL);
    gemm_mfma_kernel<3, true><<<gemm_grid, 256, 0, stream>>>(aggxH, aggxL, W0tH, W0tL, b0,
                                                             h0H, NN, FIN);

    // layer 1: lin1 = bf16(h0 @ W1); a1 = bf16(relu(agg(lin1) + b1))
    gemm_mfma_kernel<1, false><<<gemm_grid, 256, 0, stream>>>(h0H, nullptr, W1tH, nullptr, nullptr,
                                                              linb, NN, FH);
    gather_bf_kernel<<<nblk_g, 256, 0, stream>>>(linb, edata, row_start, inv, b1, a1H);

    // collapsed layer 2 + mean pool + head:
    // mean_n(agg(a1@W2)+b2) = [(1/NN) sum_n w_n a1[n]] @ W2 + b2, then @ Wh + bh
    vzero_kernel<<<1, 256, 0, stream>>>(vbuf);
    colsumw_kernel<<<NBLK_S, 256, 0, stream>>>(a1H, wsum, inv, vbuf);
    head2_kernel<<<1, 256, 0, stream>>>(vbuf, W2, b2, Wh, bh, out);
}

// Round 9
// 347.511 us; speedup vs baseline: 2.6062x; 1.0406x over previous
//
#include <hip/hip_runtime.h>

#define NN 50000
#define NE 800000
#define FIN 128
#define FH 256
#define FOUT 40
#define NPAD 50432   // > NN+1, multiple of 64
#define NN2 50048    // NN rounded up to 128
#define NBLK_S 196   // ceil((NN+1)/256)
#define NB 256       // dst buckets for the edge sort
#define BSPAN 196    // ceil(NN/NB)
#define EBLK 4096    // edges per binA block
#define NBLK_A 196   // ceil(NE/EBLK)

typedef float f32x4 __attribute__((ext_vector_type(4)));
typedef short bf16x8 __attribute__((ext_vector_type(8)));

__device__ __forceinline__ ushort f2bf(float f) {
    unsigned u = __float_as_uint(f);
    unsigned r = (u + 0x7FFFu + ((u >> 16) & 1u)) >> 16;   // RNE
    return (ushort)r;
}
__device__ __forceinline__ float bf2f(ushort b) {
    return __uint_as_float(((unsigned)b) << 16);
}

// ---------------- CSR build: histogram, inv-sqrt degree, hierarchical scan ----------------

__global__ void cnt_zero_kernel(int* __restrict__ cnt, float* __restrict__ wsum) {
    int i = blockIdx.x * 256 + threadIdx.x;
    if (i < NN) { cnt[i] = 0; wsum[i] = 0.0f; }
}

__global__ void cnt_count_kernel(int* __restrict__ cnt, const int* __restrict__ dst) {
    int e = blockIdx.x * 256 + threadIdx.x;
    if (e < NE) atomicAdd(&cnt[dst[e]], 1);
}

__global__ void inv_kernel(const int* __restrict__ cnt, float* __restrict__ inv) {
    int i = blockIdx.x * 256 + threadIdx.x;
    if (i < NN) inv[i] = rsqrtf((float)(cnt[i] + 1));   // +1 self-loop
}

// scan stage 1: per-block sums of 256 counts
__global__ __launch_bounds__(256) void bsum_kernel(const int* __restrict__ cnt,
                                                   int* __restrict__ bsum) {
    __shared__ int sh[256];
    int i = blockIdx.x * 256 + threadIdx.x;
    sh[threadIdx.x] = (i < NN) ? cnt[i] : 0;
    __syncthreads();
    #pragma unroll
    for (int off = 128; off > 0; off >>= 1) {
        if (threadIdx.x < off) sh[threadIdx.x] += sh[threadIdx.x + off];
        __syncthreads();
    }
    if (threadIdx.x == 0) bsum[blockIdx.x] = sh[0];
}

// scan stage 2: exclusive scan of the NBLK_S partials (single small block)
__global__ __launch_bounds__(256) void bscan_kernel(int* __restrict__ bsum) {
    __shared__ int sh[256];
    int t = threadIdx.x;
    int v = (t < NBLK_S) ? bsum[t] : 0;
    sh[t] = v;
    __syncthreads();
    #pragma unroll
    for (int off = 1; off < 256; off <<= 1) {
        int u = (t >= off) ? sh[t - off] : 0;
        __syncthreads();
        sh[t] += u;
        __syncthreads();
    }
    if (t < NBLK_S) bsum[t] = sh[t] - v;   // exclusive
}

// scan stage 3: in-block exclusive scan + block offset -> row_start
__global__ __launch_bounds__(256) void emit_kernel(const int* __restrict__ cnt,
                                                   const int* __restrict__ bsum,
                                                   int* __restrict__ row_start) {
    __shared__ int sh[256];
    int i = blockIdx.x * 256 + threadIdx.x;
    int v = (i < NN) ? cnt[i] : 0;
    sh[threadIdx.x] = v;
    __syncthreads();
    #pragma unroll
    for (int off = 1; off < 256; off <<= 1) {
        int u = (threadIdx.x >= off) ? sh[threadIdx.x - off] : 0;
        __syncthreads();
        sh[threadIdx.x] += u;
        __syncthreads();
    }
    int pos = bsum[blockIdx.x] + sh[threadIdx.x] - v;   // exclusive prefix
    if (i <= NN) row_start[i] = pos;                    // i==NN -> NE
}

// ---------------- edge sort: LDS-regrouped two-pass counting sort ----------------

__global__ void bcur_init_kernel(const int* __restrict__ row_start, int* __restrict__ bcur) {
    int b = threadIdx.x;   // 256
    int n = b * BSPAN; if (n > NN) n = NN;
    bcur[b] = row_start[n];
}

// pass A: bucket edges by dst/BSPAN; all global writes coalesced (4B records grouped per bucket)
__global__ __launch_bounds__(256) void binA_kernel(const int* __restrict__ src,
                                                   const int* __restrict__ dst,
                                                   int* __restrict__ bcur,
                                                   unsigned* __restrict__ inter) {
    __shared__ int hcnt[NB];
    __shared__ int hoff[NB];           // block-local exclusive bucket start
    __shared__ int lcur[NB];           // running cursor for regroup
    __shared__ int gbase[NB];          // global base of this block's chunk
    __shared__ unsigned stage[EBLK];   // records grouped by bucket (16 KB)

    const int t  = threadIdx.x;
    const int e0 = blockIdx.x * EBLK;
    const int n  = min(EBLK, NE - e0);

    hcnt[t] = 0;
    __syncthreads();
    for (int i = t; i < n; i += 256)
        atomicAdd(&hcnt[dst[e0 + i] / BSPAN], 1);
    __syncthreads();
    // exclusive scan hcnt -> hoff (Hillis-Steele over 256)
    int v = hcnt[t];
    hoff[t] = v;
    __syncthreads();
    #pragma unroll
    for (int off = 1; off < NB; off <<= 1) {
        int u = (t >= off) ? hoff[t - off] : 0;
        __syncthreads();
        hoff[t] += u;
        __syncthreads();
    }
    int excl = hoff[t] - v;
    __syncthreads();
    hoff[t] = excl;
    lcur[t] = excl;
    if (v > 0) gbase[t] = atomicAdd(&bcur[t], v);
    __syncthreads();
    // regroup records into stage, grouped by bucket (LDS scatter: free)
    for (int i = t; i < n; i += 256) {
        int d = dst[e0 + i];
        int s = src[e0 + i];
        int b = d / BSPAN;
        int idx = atomicAdd(&lcur[b], 1);
        stage[idx] = ((unsigned)d << 16) | (unsigned)s;   // both < 65536
    }
    __syncthreads();
    // stream out: consecutive i -> consecutive global pos within a bucket (coalesced)
    for (int i = t; i < n; i += 256) {
        unsigned rec = stage[i];
        int b = (int)(rec >> 16) / BSPAN;
        inter[gbase[b] + (i - hoff[b])] = rec;
    }
}

// pass B: one block per bucket; final in-node positions via LDS cursors; writes confined
// to the bucket's contiguous edata range (single-XCD write-combining). Also wsum.
__global__ __launch_bounds__(256) void binB_kernel(const unsigned* __restrict__ inter,
                                                   const int* __restrict__ row_start,
                                                   const float* __restrict__ inv,
                                                   float2* __restrict__ edata,
                                                   float* __restrict__ wsum) {
    __shared__ int lcur[BSPAN];
    const int b   = blockIdx.x;
    const int nlo = b * BSPAN;
    const int nhi = min(nlo + BSPAN, NN);
    const int nn  = nhi - nlo;
    const int base = row_start[nlo];
    const int cnt  = row_start[nhi] - base;
    const int t = threadIdx.x;

    for (int i = t; i < nn; i += 256) lcur[i] = row_start[nlo + i];
    __syncthreads();
    for (int i = t; i < cnt; i += 256) {
        unsigned rec = inter[base + i];
        int d = (int)(rec >> 16);
        int s = (int)(rec & 0xFFFFu);
        float coef = inv[s] * inv[d];
        int pos = atomicAdd(&lcur[d - nlo], 1);
        edata[pos] = make_float2(__int_as_float(s), coef);
        unsafeAtomicAdd(&wsum[s], coef);
    }
}

// ---------------- weight split / transpose ----------------

__global__ void wsplit_kernel(const float* __restrict__ W, int K, int N,
                              ushort* __restrict__ WtH, ushort* __restrict__ WtL) {
    int idx = blockIdx.x * 256 + threadIdx.x;
    if (idx >= K * N) return;
    int n = idx % N;
    int k = idx / N;
    float f = W[idx];
    ushort h = f2bf(f);
    WtH[(size_t)n * K + k] = h;
    if (WtL) WtL[(size_t)n * K + k] = f2bf(f - bf2f(h));
}

// ---------------- MFMA GEMM: out_bf16 = A @ Bt^T ----------------
// 128x128 tile, 4 waves (2x2), each wave 64x64 via 4x4 frags of 16x16x32.
// TERMS=3: Ah*Bh + Ah*Bl + Al*Bh (split fp32-accurate); TERMS=1: Ah*Bh (bf16).

template<int TERMS, bool BIAS_RELU>
__global__ __launch_bounds__(256) void gemm_mfma_kernel(
    const ushort* __restrict__ AH, const ushort* __restrict__ AL,
    const ushort* __restrict__ BH, const ushort* __restrict__ BL,
    const float* __restrict__ bias,
    ushort* __restrict__ outB,
    int M, int K) {
    constexpr int NARR = (TERMS == 3) ? 4 : 2;
    __shared__ ushort smem[NARR * 128 * 40];   // pad 40 -> spread banks
    ushort* Ah = smem;
    ushort* Bh = smem + 128 * 40;
    ushort* Al = (TERMS == 3) ? smem + 2 * 128 * 40 : nullptr;
    ushort* Bl = (TERMS == 3) ? smem + 3 * 128 * 40 : nullptr;

    const int tid  = threadIdx.x;
    const int lane = tid & 63;
    const int w    = tid >> 6;
    const int wr   = w >> 1;
    const int wc   = w & 1;
    const int row0 = blockIdx.x * 128;
    const int col0 = blockIdx.y * 128;

    f32x4 acc[4][4] = {};

    for (int k0 = 0; k0 < K; k0 += 32) {
        #pragma unroll
        for (int i = 0; i < 2; ++i) {
            int c  = i * 256 + tid;
            int r  = c >> 2;          // 0..127
            int cb = c & 3;           // 16B chunk
            int gr = row0 + r;
            uint4 vh = make_uint4(0u, 0u, 0u, 0u);
            if (gr < M)
                vh = *reinterpret_cast<const uint4*>(AH + (size_t)gr * K + k0 + cb * 8);
            *reinterpret_cast<uint4*>(&Ah[r * 40 + cb * 8]) = vh;
            *reinterpret_cast<uint4*>(&Bh[r * 40 + cb * 8]) =
                *reinterpret_cast<const uint4*>(BH + (size_t)(col0 + r) * K + k0 + cb * 8);
            if (TERMS == 3) {
                uint4 vl = make_uint4(0u, 0u, 0u, 0u);
                if (gr < M)
                    vl = *reinterpret_cast<const uint4*>(AL + (size_t)gr * K + k0 + cb * 8);
                *reinterpret_cast<uint4*>(&Al[r * 40 + cb * 8]) = vl;
                *reinterpret_cast<uint4*>(&Bl[r * 40 + cb * 8]) =
                    *reinterpret_cast<const uint4*>(BL + (size_t)(col0 + r) * K + k0 + cb * 8);
            }
        }
        __syncthreads();

        const int rsel = lane & 15;
        const int ksel = (lane >> 4) * 8;
        bf16x8 ah[4], bh[4];
        #pragma unroll
        for (int m = 0; m < 4; ++m)
            ah[m] = *reinterpret_cast<const bf16x8*>(&Ah[(wr * 64 + m * 16 + rsel) * 40 + ksel]);
        #pragma unroll
        for (int n = 0; n < 4; ++n)
            bh[n] = *reinterpret_cast<const bf16x8*>(&Bh[(wc * 64 + n * 16 + rsel) * 40 + ksel]);

        if (TERMS == 3) {
            bf16x8 al[4], bl[4];
            #pragma unroll
            for (int m = 0; m < 4; ++m)
                al[m] = *reinterpret_cast<const bf16x8*>(&Al[(wr * 64 + m * 16 + rsel) * 40 + ksel]);
            #pragma unroll
            for (int n = 0; n < 4; ++n)
                bl[n] = *reinterpret_cast<const bf16x8*>(&Bl[(wc * 64 + n * 16 + rsel) * 40 + ksel]);
            #pragma unroll
            for (int m = 0; m < 4; ++m)
                #pragma unroll
                for (int n = 0; n < 4; ++n) {
                    acc[m][n] = __builtin_amdgcn_mfma_f32_16x16x32_bf16(ah[m], bh[n], acc[m][n], 0, 0, 0);
                    acc[m][n] = __builtin_amdgcn_mfma_f32_16x16x32_bf16(ah[m], bl[n], acc[m][n], 0, 0, 0);
                    acc[m][n] = __builtin_amdgcn_mfma_f32_16x16x32_bf16(al[m], bh[n], acc[m][n], 0, 0, 0);
                }
        } else {
            #pragma unroll
            for (int m = 0; m < 4; ++m)
                #pragma unroll
                for (int n = 0; n < 4; ++n)
                    acc[m][n] = __builtin_amdgcn_mfma_f32_16x16x32_bf16(ah[m], bh[n], acc[m][n], 0, 0, 0);
        }
        __syncthreads();
    }

    // epilogue: C/D layout col=lane&15, row=4*(lane>>4)+i
    const int cl = lane & 15;
    const int rg = lane >> 4;
    #pragma unroll
    for (int m = 0; m < 4; ++m) {
        #pragma unroll
        for (int i = 0; i < 4; ++i) {
            int gr = row0 + wr * 64 + m * 16 + rg * 4 + i;
            if (gr < M) {
                #pragma unroll
                for (int n = 0; n < 4; ++n) {
                    int gc = col0 + wc * 64 + n * 16 + cl;
                    float o = acc[m][n][i];
                    if (BIAS_RELU) o = fmaxf(o + bias[gc], 0.0f);
                    outB[(size_t)gr * FH + gc] = f2bf(o);
                }
            }
        }
    }
}

// ---------------- gather_x (FIN=128): fp32 in, split-bf16 out (feeds 3-term GEMM0) ----------------

__global__ __launch_bounds__(256) void gather_x_kernel(const float* __restrict__ x,
                                                       const float2* __restrict__ edata,
                                                       const int* __restrict__ row_start,
                                                       const float* __restrict__ inv,
                                                       ushort* __restrict__ outH,
                                                       ushort* __restrict__ outL) {
    int node = blockIdx.x * 4 + (threadIdx.x >> 6);
    int lane = threadIdx.x & 63;
    if (node >= NN) return;

    int beg = row_start[node];
    int end = row_start[node + 1];

    float iv = inv[node];
    float c  = iv * iv;
    float2 v = *reinterpret_cast<const float2*>(x + (size_t)node * FIN + lane * 2);
    float2 a0 = make_float2(v.x * c, v.y * c);
    float2 a1 = make_float2(0.f, 0.f);
    float2 a2 = make_float2(0.f, 0.f);
    float2 a3 = make_float2(0.f, 0.f);

    int i = beg;
    int pre = (4 - (beg & 3)) & 3;
    int pe = beg + pre; if (pe > end) pe = end;
    for (; i < pe; ++i) {
        float2 ed = edata[i];
        float2 w = *reinterpret_cast<const float2*>(x + (size_t)__float_as_int(ed.x) * FIN + lane * 2);
        a0.x += w.x * ed.y; a0.y += w.y * ed.y;
    }
    for (; i + 4 <= end; i += 4) {
        float4 e01 = *reinterpret_cast<const float4*>(&edata[i]);       // 16B-aligned
        float4 e23 = *reinterpret_cast<const float4*>(&edata[i + 2]);
        const float* p0 = x + (size_t)__float_as_int(e01.x) * FIN + lane * 2;
        const float* p1 = x + (size_t)__float_as_int(e01.z) * FIN + lane * 2;
        const float* p2 = x + (size_t)__float_as_int(e23.x) * FIN + lane * 2;
        const float* p3 = x + (size_t)__float_as_int(e23.z) * FIN + lane * 2;
        float2 w0 = *reinterpret_cast<const float2*>(p0);
        float2 w1 = *reinterpret_cast<const float2*>(p1);
        float2 w2 = *reinterpret_cast<const float2*>(p2);
        float2 w3 = *reinterpret_cast<const float2*>(p3);
        a0.x += w0.x * e01.y; a0.y += w0.y * e01.y;
        a1.x += w1.x * e01.w; a1.y += w1.y * e01.w;
        a2.x += w2.x * e23.y; a2.y += w2.y * e23.y;
        a3.x += w3.x * e23.w; a3.y += w3.y * e23.w;
    }
    for (; i < end; ++i) {
        float2 ed = edata[i];
        float2 w = *reinterpret_cast<const float2*>(x + (size_t)__float_as_int(ed.x) * FIN + lane * 2);
        a0.x += w.x * ed.y; a0.y += w.y * ed.y;
    }

    float ax = a0.x + a1.x + a2.x + a3.x;
    float ay = a0.y + a1.y + a2.y + a3.y;
    ushort h0 = f2bf(ax), h1 = f2bf(ay);
    ushort l0 = f2bf(ax - bf2f(h0)), l1 = f2bf(ay - bf2f(h1));
    size_t o = (size_t)node * FIN + lane * 2;
    *reinterpret_cast<ushort2*>(outH + o) = make_ushort2(h0, h1);
    *reinterpret_cast<ushort2*>(outL + o) = make_ushort2(l0, l1);
}

// ---------------- gather (FH=256): bf16 in, fp32 accumulate; x4 unroll; bf16 relu out ----------------

__global__ __launch_bounds__(256) void gather_bf_kernel(const ushort* __restrict__ lin,
                                                        const float2* __restrict__ edata,
                                                        const int* __restrict__ row_start,
                                                        const float* __restrict__ inv,
                                                        const float* __restrict__ bias,
                                                        ushort* __restrict__ outB) {
    int node = blockIdx.x * 4 + (threadIdx.x >> 6);
    int lane = threadIdx.x & 63;
    if (node >= NN) return;

    int beg = row_start[node];
    int end = row_start[node + 1];

    float iv = inv[node];
    float c  = iv * iv;
    ushort4 sv = *reinterpret_cast<const ushort4*>(lin + (size_t)node * FH + lane * 4);
    float4 b = *reinterpret_cast<const float4*>(bias + lane * 4);
    float4 a0 = make_float4(bf2f(sv.x) * c + b.x, bf2f(sv.y) * c + b.y,
                            bf2f(sv.z) * c + b.z, bf2f(sv.w) * c + b.w);
    float4 a1 = make_float4(0.f, 0.f, 0.f, 0.f);
    float4 a2 = make_float4(0.f, 0.f, 0.f, 0.f);
    float4 a3 = make_float4(0.f, 0.f, 0.f, 0.f);

    int i = beg;
    int pre = (4 - (beg & 3)) & 3;
    int pe = beg + pre; if (pe > end) pe = end;
    for (; i < pe; ++i) {
        float2 ed = edata[i];
        float cf = ed.y;
        ushort4 wv = *reinterpret_cast<const ushort4*>(lin + (size_t)__float_as_int(ed.x) * FH + lane * 4);
        a0.x += bf2f(wv.x) * cf; a0.y += bf2f(wv.y) * cf;
        a0.z += bf2f(wv.z) * cf; a0.w += bf2f(wv.w) * cf;
    }
    for (; i + 4 <= end; i += 4) {
        float4 e01 = *reinterpret_cast<const float4*>(&edata[i]);       // 16B-aligned
        float4 e23 = *reinterpret_cast<const float4*>(&edata[i + 2]);
        const ushort* p0 = lin + (size_t)__float_as_int(e01.x) * FH + lane * 4;
        const ushort* p1 = lin + (size_t)__float_as_int(e01.z) * FH + lane * 4;
        const ushort* p2 = lin + (size_t)__float_as_int(e23.x) * FH + lane * 4;
        const ushort* p3 = lin + (size_t)__float_as_int(e23.z) * FH + lane * 4;
        ushort4 w0 = *reinterpret_cast<const ushort4*>(p0);
        ushort4 w1 = *reinterpret_cast<const ushort4*>(p1);
        ushort4 w2 = *reinterpret_cast<const ushort4*>(p2);
        ushort4 w3 = *reinterpret_cast<const ushort4*>(p3);
        a0.x += bf2f(w0.x) * e01.y; a0.y += bf2f(w0.y) * e01.y;
        a0.z += bf2f(w0.z) * e01.y; a0.w += bf2f(w0.w) * e01.y;
        a1.x += bf2f(w1.x) * e01.w; a1.y += bf2f(w1.y) * e01.w;
        a1.z += bf2f(w1.z) * e01.w; a1.w += bf2f(w1.w) * e01.w;
        a2.x += bf2f(w2.x) * e23.y; a2.y += bf2f(w2.y) * e23.y;
        a2.z += bf2f(w2.z) * e23.y; a2.w += bf2f(w2.w) * e23.y;
        a3.x += bf2f(w3.x) * e23.w; a3.y += bf2f(w3.y) * e23.w;
        a3.z += bf2f(w3.z) * e23.w; a3.w += bf2f(w3.w) * e23.w;
    }
    for (; i < end; ++i) {
        float2 ed = edata[i];
        float cf = ed.y;
        ushort4 wv = *reinterpret_cast<const ushort4*>(lin + (size_t)__float_as_int(ed.x) * FH + lane * 4);
        a0.x += bf2f(wv.x) * cf; a0.y += bf2f(wv.y) * cf;
        a0.z += bf2f(wv.z) * cf; a0.w += bf2f(wv.w) * cf;
    }

    float4 acc = make_float4(a0.x + a1.x + a2.x + a3.x,
                             a0.y + a1.y + a2.y + a3.y,
                             a0.z + a1.z + a2.z + a3.z,
                             a0.w + a1.w + a2.w + a3.w);

    float r0 = fmaxf(acc.x, 0.f), r1 = fmaxf(acc.y, 0.f);
    float r2 = fmaxf(acc.z, 0.f), r3 = fmaxf(acc.w, 0.f);
    *reinterpret_cast<ushort4*>(outB + (size_t)node * FH + lane * 4) =
        make_ushort4(f2bf(r0), f2bf(r1), f2bf(r2), f2bf(r3));
}

// ---------------- collapsed layer 2 + mean pool: v[f] = sum_n w_n * a1[n][f] ----------------

__global__ void vzero_kernel(float* __restrict__ v) {
    v[threadIdx.x] = 0.0f;
}

__global__ __launch_bounds__(256) void colsumw_kernel(const ushort* __restrict__ a1,
                                                      const float* __restrict__ wsum,
                                                      const float* __restrict__ inv,
                                                      float* __restrict__ v) {
    __shared__ float sh[4][256];
    int wid  = threadIdx.x >> 6;
    int lane = threadIdx.x & 63;
    int r0 = blockIdx.x * 256;
    int r1 = r0 + 256; if (r1 > NN) r1 = NN;

    float4 acc = make_float4(0.f, 0.f, 0.f, 0.f);
    for (int r = r0 + wid; r < r1; r += 4) {
        float iv = inv[r];
        float wr = wsum[r] + iv * iv;
        ushort4 u = *reinterpret_cast<const ushort4*>(a1 + (size_t)r * FH + lane * 4);
        acc.x += bf2f(u.x) * wr;
        acc.y += bf2f(u.y) * wr;
        acc.z += bf2f(u.z) * wr;
        acc.w += bf2f(u.w) * wr;
    }
    *reinterpret_cast<float4*>(&sh[wid][lane * 4]) = acc;
    __syncthreads();
    if (wid == 0) {
        float4 s1 = *reinterpret_cast<const float4*>(&sh[1][lane * 4]);
        float4 s2 = *reinterpret_cast<const float4*>(&sh[2][lane * 4]);
        float4 s3 = *reinterpret_cast<const float4*>(&sh[3][lane * 4]);
        unsafeAtomicAdd(&v[lane * 4 + 0], acc.x + s1.x + s2.x + s3.x);
        unsafeAtomicAdd(&v[lane * 4 + 1], acc.y + s1.y + s2.y + s3.y);
        unsafeAtomicAdd(&v[lane * 4 + 2], acc.z + s1.z + s2.z + s3.z);
        unsafeAtomicAdd(&v[lane * 4 + 3], acc.w + s1.w + s2.w + s3.w);
    }
}

// out = ((v/NN) @ W2 + b2) @ Wh + bh
__global__ __launch_bounds__(256) void head2_kernel(const float* __restrict__ v,
                                                    const float* __restrict__ W2,
                                                    const float* __restrict__ b2,
                                                    const float* __restrict__ Wh,
                                                    const float* __restrict__ bh,
                                                    float* __restrict__ out) {
    __shared__ float m[FH];
    int t = threadIdx.x;
    const float scale = 1.0f / (float)NN;
    float s = 0.0f;
    for (int f = 0; f < FH; ++f)
        s += v[f] * W2[f * FH + t];
    m[t] = s * scale + b2[t];
    __syncthreads();
    if (t < FOUT) {
        float o = 0.0f;
        for (int f = 0; f < FH; ++f)
            o += m[f] * Wh[f * FOUT + t];
        out[t] = o + bh[t];
    }
}

// ---------------- launch ----------------

extern "C" void kernel_launch(void* const* d_in, const int* in_sizes, int n_in,
                              void* d_out, int out_size, void* d_ws, size_t ws_size,
                              hipStream_t stream) {
    const float* x   = (const float*)d_in[0];
    const int*   ei  = (const int*)d_in[1];
    const float* W0  = (const float*)d_in[2];
    const float* b0  = (const float*)d_in[3];
    const float* W1  = (const float*)d_in[4];
    const float* b1  = (const float*)d_in[5];
    const float* W2  = (const float*)d_in[6];
    const float* b2  = (const float*)d_in[7];
    const float* Wh  = (const float*)d_in[8];
    const float* bh  = (const float*)d_in[9];
    float* out = (float*)d_out;

    const int* src = ei;        // edge_index[0,:]
    const int* dst = ei + NE;   // edge_index[1,:]

    // workspace layout (16B-aligned blocks)
    float*    inv       = (float*)d_ws;                 // NPAD
    int*      cnt       = (int*)(inv + NPAD);           // NPAD
    int*      row_start = cnt + NPAD;                   // NN+1 used
    int*      bsum      = row_start + NPAD;             // 256 (NBLK_S used)
    int*      bcur      = bsum + 256;                   // 256
    float*    wsum      = (float*)(bcur + 256);         // NPAD
    unsigned* inter     = (unsigned*)(wsum + NPAD);     // NE u32 (3.2 MB)
    float2*   edata     = (float2*)(inter + NE);        // NE float2 (6.4 MB)
    float*    vbuf      = (float*)(edata + NE);         // 256
    ushort*   W0tH      = (ushort*)(vbuf + 256);        // [256][128]
    ushort*   W0tL      = W0tH + 256 * 128;
    ushort*   W1tH      = W0tL + 256 * 128;             // [256][256]
    // aggx split planes (25.6 MB total) -> later reused as linb (bf16 lin1)
    ushort*   aggxH     = W1tH + 256 * 256;             // [NN2][128]
    ushort*   aggxL     = aggxH + (size_t)NN2 * 128;
    ushort*   linb      = aggxH;                        // [NN2][256] bf16 (aggx dead)
    // h0 plane (25.6 MB) -> later reused as a1 plane
    ushort*   h0H       = aggxL + (size_t)NN2 * 128;    // [NN2][256]
    ushort*   a1H       = h0H;                          // (h0 dead after GEMM1)

    const int nblk_n = (NN + 255) / 256;
    const int nblk_e = (NE + 255) / 256;
    const dim3 gemm_grid((NN + 127) / 128, 2);
    const int nblk_g = (NN + 3) / 4;

    // ---- CSR build (hist, scan) + edge sort (binA/binB) + weight split ----
    cnt_zero_kernel<<<nblk_n, 256, 0, stream>>>(cnt, wsum);
    cnt_count_kernel<<<nblk_e, 256, 0, stream>>>(cnt, dst);
    inv_kernel<<<nblk_n, 256, 0, stream>>>(cnt, inv);
    bsum_kernel<<<NBLK_S, 256, 0, stream>>>(cnt, bsum);
    bscan_kernel<<<1, 256, 0, stream>>>(bsum);
    emit_kernel<<<NBLK_S, 256, 0, stream>>>(cnt, bsum, row_start);
    bcur_init_kernel<<<1, 256, 0, stream>>>(row_start, bcur);
    binA_kernel<<<NBLK_A, 256, 0, stream>>>(src, dst, bcur, inter);
    binB_kernel<<<NB, 256, 0, stream>>>(inter, row_start, inv, edata, wsum);
    wsplit_kernel<<<(FIN * FH + 255) / 256, 256, 0, stream>>>(W0, FIN, FH, W0tH, W0tL);
    wsplit_kernel<<<(FH * FH + 255) / 256, 256, 0, stream>>>(W1, FH, FH, W1tH, nullptr);

    // layer 0: aggx = agg(x) [split]; h0 = bf16(relu(aggx @ W0 + b0))   (3-term, fp32-accurate)
    gather_x_kernel<<<nblk_g, 256, 0, stream>>>(x, edata, row_start, inv, aggxH, aggxL);
    gemm_mfma_kernel<3, true><<<gemm_grid, 256, 0, stream>>>(aggxH, aggxL, W0tH, W0tL, b0,
                                                             h0H, NN, FIN);

    // layer 1: lin1 = bf16(h0 @ W1); a1 = bf16(relu(agg(lin1) + b1))
    gemm_mfma_kernel<1, false><<<gemm_grid, 256, 0, stream>>>(h0H, nullptr, W1tH, nullptr, nullptr,
                                                              linb, NN, FH);
    gather_bf_kernel<<<nblk_g, 256, 0, stream>>>(linb, edata, row_start, inv, b1, a1H);

    // collapsed layer 2 + mean pool + head
    vzero_kernel<<<1, 256, 0, stream>>>(vbuf);
    colsumw_kernel<<<NBLK_S, 256, 0, stream>>>(a1H, wsum, inv, vbuf);
    head2_kernel<<<1, 256, 0, stream>>>(vbuf, W2, b2, Wh, bh, out);
}

// Round 10
// 314.912 us; speedup vs baseline: 2.8760x; 1.1035x over previous
//
#include <hip/hip_runtime.h>

#define NN 50000
#define NE 800000
#define FIN 128
#define FH 256
#define FOUT 40
#define NPAD 50432   // > NN+1, multiple of 64
#define NN2 50048    // NN rounded up to 128
#define NB 256       // dst buckets for the edge sort
#define BSPAN 196    // ceil(NN/NB)
#define EBLK 4096    // edges per binA block
#define NBLK_A 196   // ceil(NE/EBLK)
#define NBLK_S 196   // ceil((NN+1)/256) -- colsumw grid

typedef float f32x4 __attribute__((ext_vector_type(4)));
typedef short bf16x8 __attribute__((ext_vector_type(8)));

__device__ __forceinline__ ushort f2bf(float f) {
    unsigned u = __float_as_uint(f);
    unsigned r = (u + 0x7FFFu + ((u >> 16) & 1u)) >> 16;   // RNE
    return (ushort)r;
}
__device__ __forceinline__ float bf2f(ushort b) {
    return __uint_as_float(((unsigned)b) << 16);
}

// ---------------- edge sort + CSR build (no per-node global atomics) ----------------

// K1: per-block LDS bucket histogram -> 256 global counters
__global__ __launch_bounds__(256) void bucket_cnt_kernel(const int* __restrict__ dst,
                                                         int* __restrict__ bcnt) {
    __shared__ int h[NB];
    const int t = threadIdx.x;
    h[t] = 0;
    __syncthreads();
    const int e0 = blockIdx.x * EBLK;
    const int n  = min(EBLK, NE - e0);
    for (int i = t; i < n; i += 256)
        atomicAdd(&h[dst[e0 + i] / BSPAN], 1);
    __syncthreads();
    if (h[t] > 0) atomicAdd(&bcnt[t], h[t]);
}

// K2: exclusive scan of 256 bucket counts -> bbase[257], bcur; zero vbuf
__global__ __launch_bounds__(256) void bucket_scan_kernel(const int* __restrict__ bcnt,
                                                          int* __restrict__ bbase,
                                                          int* __restrict__ bcur,
                                                          float* __restrict__ vbuf) {
    __shared__ int sh[256];
    int t = threadIdx.x;
    int v = bcnt[t];
    sh[t] = v;
    __syncthreads();
    #pragma unroll
    for (int off = 1; off < 256; off <<= 1) {
        int u = (t >= off) ? sh[t - off] : 0;
        __syncthreads();
        sh[t] += u;
        __syncthreads();
    }
    int excl = sh[t] - v;
    bbase[t] = excl;
    bcur[t]  = excl;
    if (t == 255) bbase[256] = sh[255];   // == NE
    vbuf[t] = 0.0f;
}

// K3: bucket edges by dst/BSPAN; all global writes coalesced (4B records grouped per bucket)
__global__ __launch_bounds__(256) void binA_kernel(const int* __restrict__ src,
                                                   const int* __restrict__ dst,
                                                   int* __restrict__ bcur,
                                                   unsigned* __restrict__ inter) {
    __shared__ int hcnt[NB];
    __shared__ int hoff[NB];           // block-local exclusive bucket start
    __shared__ int lcur[NB];           // running cursor for regroup
    __shared__ int gbase[NB];          // global base of this block's chunk
    __shared__ unsigned stage[EBLK];   // records grouped by bucket (16 KB)

    const int t  = threadIdx.x;
    const int e0 = blockIdx.x * EBLK;
    const int n  = min(EBLK, NE - e0);

    hcnt[t] = 0;
    __syncthreads();
    for (int i = t; i < n; i += 256)
        atomicAdd(&hcnt[dst[e0 + i] / BSPAN], 1);
    __syncthreads();
    int v = hcnt[t];
    hoff[t] = v;
    __syncthreads();
    #pragma unroll
    for (int off = 1; off < NB; off <<= 1) {
        int u = (t >= off) ? hoff[t - off] : 0;
        __syncthreads();
        hoff[t] += u;
        __syncthreads();
    }
    int excl = hoff[t] - v;
    __syncthreads();
    hoff[t] = excl;
    lcur[t] = excl;
    if (v > 0) gbase[t] = atomicAdd(&bcur[t], v);
    __syncthreads();
    for (int i = t; i < n; i += 256) {
        int d = dst[e0 + i];
        int s = src[e0 + i];
        int b = d / BSPAN;
        int idx = atomicAdd(&lcur[b], 1);
        stage[idx] = ((unsigned)d << 16) | (unsigned)s;   // both < 65536
    }
    __syncthreads();
    for (int i = t; i < n; i += 256) {
        unsigned rec = stage[i];
        int b = (int)(rec >> 16) / BSPAN;
        inter[gbase[b] + (i - hoff[b])] = rec;
    }
}

// K4: per bucket: per-node counts in LDS -> row_start, inv, wsum=0 (all coalesced writes)
__global__ __launch_bounds__(256) void binB1_kernel(const unsigned* __restrict__ inter,
                                                    const int* __restrict__ bbase,
                                                    int* __restrict__ row_start,
                                                    float* __restrict__ inv,
                                                    float* __restrict__ wsum) {
    __shared__ int lcnt[BSPAN];
    __shared__ int sh[256];
    const int b   = blockIdx.x;
    const int nlo = b * BSPAN;
    const int nhi = min(nlo + BSPAN, NN);
    const int nn  = nhi - nlo;
    const int base = bbase[b];
    const int cnt  = bbase[b + 1] - base;
    const int t = threadIdx.x;

    for (int i = t; i < nn; i += 256) lcnt[i] = 0;
    __syncthreads();
    for (int i = t; i < cnt; i += 256)
        atomicAdd(&lcnt[(int)(inter[base + i] >> 16) - nlo], 1);
    __syncthreads();
    int c = (t < nn) ? lcnt[t] : 0;
    sh[t] = c;
    __syncthreads();
    #pragma unroll
    for (int off = 1; off < 256; off <<= 1) {
        int u = (t >= off) ? sh[t - off] : 0;
        __syncthreads();
        sh[t] += u;
        __syncthreads();
    }
    if (t < nn) {
        row_start[nlo + t] = base + sh[t] - c;      // exclusive prefix
        inv[nlo + t]  = rsqrtf((float)(c + 1));     // +1 self-loop
        wsum[nlo + t] = 0.0f;
    }
    if (b == NB - 1 && t == 0) row_start[NN] = NE;
}

// K5: per bucket: place edata at final positions (LDS cursors), coef + wsum
__global__ __launch_bounds__(256) void binB2_kernel(const unsigned* __restrict__ inter,
                                                    const int* __restrict__ bbase,
                                                    const int* __restrict__ row_start,
                                                    const float* __restrict__ inv,
                                                    float2* __restrict__ edata,
                                                    float* __restrict__ wsum) {
    __shared__ int lcur[BSPAN];
    const int b   = blockIdx.x;
    const int nlo = b * BSPAN;
    const int nhi = min(nlo + BSPAN, NN);
    const int nn  = nhi - nlo;
    const int base = bbase[b];
    const int cnt  = bbase[b + 1] - base;
    const int t = threadIdx.x;

    for (int i = t; i < nn; i += 256) lcur[i] = row_start[nlo + i];
    __syncthreads();
    for (int i = t; i < cnt; i += 256) {
        unsigned rec = inter[base + i];
        int d = (int)(rec >> 16);
        int s = (int)(rec & 0xFFFFu);
        float coef = inv[s] * inv[d];
        int pos = atomicAdd(&lcur[d - nlo], 1);
        edata[pos] = make_float2(__int_as_float(s), coef);
        unsafeAtomicAdd(&wsum[s], coef);
    }
}

// ---------------- weight split / transpose ----------------

__global__ void wsplit_kernel(const float* __restrict__ W, int K, int N,
                              ushort* __restrict__ WtH, ushort* __restrict__ WtL) {
    int idx = blockIdx.x * 256 + threadIdx.x;
    if (idx >= K * N) return;
    int n = idx % N;
    int k = idx / N;
    float f = W[idx];
    ushort h = f2bf(f);
    WtH[(size_t)n * K + k] = h;
    if (WtL) WtL[(size_t)n * K + k] = f2bf(f - bf2f(h));
}

// ---------------- MFMA GEMM: out_bf16 = A @ Bt^T ----------------

template<int TERMS, bool BIAS_RELU>
__global__ __launch_bounds__(256) void gemm_mfma_kernel(
    const ushort* __restrict__ AH, const ushort* __restrict__ AL,
    const ushort* __restrict__ BH, const ushort* __restrict__ BL,
    const float* __restrict__ bias,
    ushort* __restrict__ outB,
    int M, int K) {
    constexpr int NARR = (TERMS == 3) ? 4 : 2;
    __shared__ ushort smem[NARR * 128 * 40];   // pad 40 -> spread banks
    ushort* Ah = smem;
    ushort* Bh = smem + 128 * 40;
    ushort* Al = (TERMS == 3) ? smem + 2 * 128 * 40 : nullptr;
    ushort* Bl = (TERMS == 3) ? smem + 3 * 128 * 40 : nullptr;

    const int tid  = threadIdx.x;
    const int lane = tid & 63;
    const int w    = tid >> 6;
    const int wr   = w >> 1;
    const int wc   = w & 1;
    const int row0 = blockIdx.x * 128;
    const int col0 = blockIdx.y * 128;

    f32x4 acc[4][4] = {};

    for (int k0 = 0; k0 < K; k0 += 32) {
        #pragma unroll
        for (int i = 0; i < 2; ++i) {
            int c  = i * 256 + tid;
            int r  = c >> 2;
            int cb = c & 3;
            int gr = row0 + r;
            uint4 vh = make_uint4(0u, 0u, 0u, 0u);
            if (gr < M)
                vh = *reinterpret_cast<const uint4*>(AH + (size_t)gr * K + k0 + cb * 8);
            *reinterpret_cast<uint4*>(&Ah[r * 40 + cb * 8]) = vh;
            *reinterpret_cast<uint4*>(&Bh[r * 40 + cb * 8]) =
                *reinterpret_cast<const uint4*>(BH + (size_t)(col0 + r) * K + k0 + cb * 8);
            if (TERMS == 3) {
                uint4 vl = make_uint4(0u, 0u, 0u, 0u);
                if (gr < M)
                    vl = *reinterpret_cast<const uint4*>(AL + (size_t)gr * K + k0 + cb * 8);
                *reinterpret_cast<uint4*>(&Al[r * 40 + cb * 8]) = vl;
                *reinterpret_cast<uint4*>(&Bl[r * 40 + cb * 8]) =
                    *reinterpret_cast<const uint4*>(BL + (size_t)(col0 + r) * K + k0 + cb * 8);
            }
        }
        __syncthreads();

        const int rsel = lane & 15;
        const int ksel = (lane >> 4) * 8;
        bf16x8 ah[4], bh[4];
        #pragma unroll
        for (int m = 0; m < 4; ++m)
            ah[m] = *reinterpret_cast<const bf16x8*>(&Ah[(wr * 64 + m * 16 + rsel) * 40 + ksel]);
        #pragma unroll
        for (int n = 0; n < 4; ++n)
            bh[n] = *reinterpret_cast<const bf16x8*>(&Bh[(wc * 64 + n * 16 + rsel) * 40 + ksel]);

        if (TERMS == 3) {
            bf16x8 al[4], bl[4];
            #pragma unroll
            for (int m = 0; m < 4; ++m)
                al[m] = *reinterpret_cast<const bf16x8*>(&Al[(wr * 64 + m * 16 + rsel) * 40 + ksel]);
            #pragma unroll
            for (int n = 0; n < 4; ++n)
                bl[n] = *reinterpret_cast<const bf16x8*>(&Bl[(wc * 64 + n * 16 + rsel) * 40 + ksel]);
            #pragma unroll
            for (int m = 0; m < 4; ++m)
                #pragma unroll
                for (int n = 0; n < 4; ++n) {
                    acc[m][n] = __builtin_amdgcn_mfma_f32_16x16x32_bf16(ah[m], bh[n], acc[m][n], 0, 0, 0);
                    acc[m][n] = __builtin_amdgcn_mfma_f32_16x16x32_bf16(ah[m], bl[n], acc[m][n], 0, 0, 0);
                    acc[m][n] = __builtin_amdgcn_mfma_f32_16x16x32_bf16(al[m], bh[n], acc[m][n], 0, 0, 0);
                }
        } else {
            #pragma unroll
            for (int m = 0; m < 4; ++m)
                #pragma unroll
                for (int n = 0; n < 4; ++n)
                    acc[m][n] = __builtin_amdgcn_mfma_f32_16x16x32_bf16(ah[m], bh[n], acc[m][n], 0, 0, 0);
        }
        __syncthreads();
    }

    const int cl = lane & 15;
    const int rg = lane >> 4;
    #pragma unroll
    for (int m = 0; m < 4; ++m) {
        #pragma unroll
        for (int i = 0; i < 4; ++i) {
            int gr = row0 + wr * 64 + m * 16 + rg * 4 + i;
            if (gr < M) {
                #pragma unroll
                for (int n = 0; n < 4; ++n) {
                    int gc = col0 + wc * 64 + n * 16 + cl;
                    float o = acc[m][n][i];
                    if (BIAS_RELU) o = fmaxf(o + bias[gc], 0.0f);
                    outB[(size_t)gr * FH + gc] = f2bf(o);
                }
            }
        }
    }
}

// ---------------- gather_x (FIN=128): fp32 in, split-bf16 out; x8-deep MLP ----------------

__global__ __launch_bounds__(256) void gather_x_kernel(const float* __restrict__ x,
                                                       const float2* __restrict__ edata,
                                                       const int* __restrict__ row_start,
                                                       const float* __restrict__ inv,
                                                       ushort* __restrict__ outH,
                                                       ushort* __restrict__ outL) {
    int node = blockIdx.x * 4 + (threadIdx.x >> 6);
    int lane = threadIdx.x & 63;
    if (node >= NN) return;

    int beg = row_start[node];
    int end = row_start[node + 1];

    float iv = inv[node];
    float c  = iv * iv;
    float2 v = *reinterpret_cast<const float2*>(x + (size_t)node * FIN + lane * 2);
    float2 a0 = make_float2(v.x * c, v.y * c);
    float2 a1 = make_float2(0.f, 0.f);
    float2 a2 = make_float2(0.f, 0.f);
    float2 a3 = make_float2(0.f, 0.f);

    int i = beg;
    if ((i & 1) && i < end) {            // align to even for float4 edata loads
        float2 ed = edata[i];
        float2 w = *reinterpret_cast<const float2*>(x + (size_t)__float_as_int(ed.x) * FIN + lane * 2);
        a0.x += w.x * ed.y; a0.y += w.y * ed.y;
        ++i;
    }
    for (; i + 8 <= end; i += 8) {
        float4 e01 = *reinterpret_cast<const float4*>(&edata[i]);
        float4 e23 = *reinterpret_cast<const float4*>(&edata[i + 2]);
        float4 e45 = *reinterpret_cast<const float4*>(&edata[i + 4]);
        float4 e67 = *reinterpret_cast<const float4*>(&edata[i + 6]);
        float2 w0 = *reinterpret_cast<const float2*>(x + (size_t)__float_as_int(e01.x) * FIN + lane * 2);
        float2 w1 = *reinterpret_cast<const float2*>(x + (size_t)__float_as_int(e01.z) * FIN + lane * 2);
        float2 w2 = *reinterpret_cast<const float2*>(x + (size_t)__float_as_int(e23.x) * FIN + lane * 2);
        float2 w3 = *reinterpret_cast<const float2*>(x + (size_t)__float_as_int(e23.z) * FIN + lane * 2);
        float2 w4 = *reinterpret_cast<const float2*>(x + (size_t)__float_as_int(e45.x) * FIN + lane * 2);
        float2 w5 = *reinterpret_cast<const float2*>(x + (size_t)__float_as_int(e45.z) * FIN + lane * 2);
        float2 w6 = *reinterpret_cast<const float2*>(x + (size_t)__float_as_int(e67.x) * FIN + lane * 2);
        float2 w7 = *reinterpret_cast<const float2*>(x + (size_t)__float_as_int(e67.z) * FIN + lane * 2);
        a0.x += w0.x * e01.y; a0.y += w0.y * e01.y;
        a1.x += w1.x * e01.w; a1.y += w1.y * e01.w;
        a2.x += w2.x * e23.y; a2.y += w2.y * e23.y;
        a3.x += w3.x * e23.w; a3.y += w3.y * e23.w;
        a0.x += w4.x * e45.y; a0.y += w4.y * e45.y;
        a1.x += w5.x * e45.w; a1.y += w5.y * e45.w;
        a2.x += w6.x * e67.y; a2.y += w6.y * e67.y;
        a3.x += w7.x * e67.w; a3.y += w7.y * e67.w;
    }
    for (; i + 2 <= end; i += 2) {
        float4 e01 = *reinterpret_cast<const float4*>(&edata[i]);
        float2 w0 = *reinterpret_cast<const float2*>(x + (size_t)__float_as_int(e01.x) * FIN + lane * 2);
        float2 w1 = *reinterpret_cast<const float2*>(x + (size_t)__float_as_int(e01.z) * FIN + lane * 2);
        a0.x += w0.x * e01.y; a0.y += w0.y * e01.y;
        a1.x += w1.x * e01.w; a1.y += w1.y * e01.w;
    }
    if (i < end) {
        float2 ed = edata[i];
        float2 w = *reinterpret_cast<const float2*>(x + (size_t)__float_as_int(ed.x) * FIN + lane * 2);
        a0.x += w.x * ed.y; a0.y += w.y * ed.y;
    }

    float ax = a0.x + a1.x + a2.x + a3.x;
    float ay = a0.y + a1.y + a2.y + a3.y;
    ushort h0 = f2bf(ax), h1 = f2bf(ay);
    ushort l0 = f2bf(ax - bf2f(h0)), l1 = f2bf(ay - bf2f(h1));
    size_t o = (size_t)node * FIN + lane * 2;
    *reinterpret_cast<ushort2*>(outH + o) = make_ushort2(h0, h1);
    *reinterpret_cast<ushort2*>(outL + o) = make_ushort2(l0, l1);
}

// ---------------- gather (FH=256): bf16 in, fp32 accumulate; x8-deep MLP; bf16 relu out ----------------

__global__ __launch_bounds__(256) void gather_bf_kernel(const ushort* __restrict__ lin,
                                                        const float2* __restrict__ edata,
                                                        const int* __restrict__ row_start,
                                                        const float* __restrict__ inv,
                                                        const float* __restrict__ bias,
                                                        ushort* __restrict__ outB) {
    int node = blockIdx.x * 4 + (threadIdx.x >> 6);
    int lane = threadIdx.x & 63;
    if (node >= NN) return;

    int beg = row_start[node];
    int end = row_start[node + 1];

    float iv = inv[node];
    float c  = iv * iv;
    ushort4 sv = *reinterpret_cast<const ushort4*>(lin + (size_t)node * FH + lane * 4);
    float4 b = *reinterpret_cast<const float4*>(bias + lane * 4);
    float4 a0 = make_float4(bf2f(sv.x) * c + b.x, bf2f(sv.y) * c + b.y,
                            bf2f(sv.z) * c + b.z, bf2f(sv.w) * c + b.w);
    float4 a1 = make_float4(0.f, 0.f, 0.f, 0.f);
    float4 a2 = make_float4(0.f, 0.f, 0.f, 0.f);
    float4 a3 = make_float4(0.f, 0.f, 0.f, 0.f);

    int i = beg;
    if ((i & 1) && i < end) {
        float2 ed = edata[i];
        float cf = ed.y;
        ushort4 wv = *reinterpret_cast<const ushort4*>(lin + (size_t)__float_as_int(ed.x) * FH + lane * 4);
        a0.x += bf2f(wv.x) * cf; a0.y += bf2f(wv.y) * cf;
        a0.z += bf2f(wv.z) * cf; a0.w += bf2f(wv.w) * cf;
        ++i;
    }
    for (; i + 8 <= end; i += 8) {
        float4 e01 = *reinterpret_cast<const float4*>(&edata[i]);
        float4 e23 = *reinterpret_cast<const float4*>(&edata[i + 2]);
        float4 e45 = *reinterpret_cast<const float4*>(&edata[i + 4]);
        float4 e67 = *reinterpret_cast<const float4*>(&edata[i + 6]);
        ushort4 w0 = *reinterpret_cast<const ushort4*>(lin + (size_t)__float_as_int(e01.x) * FH + lane * 4);
        ushort4 w1 = *reinterpret_cast<const ushort4*>(lin + (size_t)__float_as_int(e01.z) * FH + lane * 4);
        ushort4 w2 = *reinterpret_cast<const ushort4*>(lin + (size_t)__float_as_int(e23.x) * FH + lane * 4);
        ushort4 w3 = *reinterpret_cast<const ushort4*>(lin + (size_t)__float_as_int(e23.z) * FH + lane * 4);
        ushort4 w4 = *reinterpret_cast<const ushort4*>(lin + (size_t)__float_as_int(e45.x) * FH + lane * 4);
        ushort4 w5 = *reinterpret_cast<const ushort4*>(lin + (size_t)__float_as_int(e45.z) * FH + lane * 4);
        ushort4 w6 = *reinterpret_cast<const ushort4*>(lin + (size_t)__float_as_int(e67.x) * FH + lane * 4);
        ushort4 w7 = *reinterpret_cast<const ushort4*>(lin + (size_t)__float_as_int(e67.z) * FH + lane * 4);
        a0.x += bf2f(w0.x) * e01.y; a0.y += bf2f(w0.y) * e01.y;
        a0.z += bf2f(w0.z) * e01.y; a0.w += bf2f(w0.w) * e01.y;
        a1.x += bf2f(w1.x) * e01.w; a1.y += bf2f(w1.y) * e01.w;
        a1.z += bf2f(w1.z) * e01.w; a1.w += bf2f(w1.w) * e01.w;
        a2.x += bf2f(w2.x) * e23.y; a2.y += bf2f(w2.y) * e23.y;
        a2.z += bf2f(w2.z) * e23.y; a2.w += bf2f(w2.w) * e23.y;
        a3.x += bf2f(w3.x) * e23.w; a3.y += bf2f(w3.y) * e23.w;
        a3.z += bf2f(w3.z) * e23.w; a3.w += bf2f(w3.w) * e23.w;
        a0.x += bf2f(w4.x) * e45.y; a0.y += bf2f(w4.y) * e45.y;
        a0.z += bf2f(w4.z) * e45.y; a0.w += bf2f(w4.w) * e45.y;
        a1.x += bf2f(w5.x) * e45.w; a1.y += bf2f(w5.y) * e45.w;
        a1.z += bf2f(w5.z) * e45.w; a1.w += bf2f(w5.w) * e45.w;
        a2.x += bf2f(w6.x) * e67.y; a2.y += bf2f(w6.y) * e67.y;
        a2.z += bf2f(w6.z) * e67.y; a2.w += bf2f(w6.w) * e67.y;
        a3.x += bf2f(w7.x) * e67.w; a3.y += bf2f(w7.y) * e67.w;
        a3.z += bf2f(w7.z) * e67.w; a3.w += bf2f(w7.w) * e67.w;
    }
    for (; i + 2 <= end; i += 2) {
        float4 e01 = *reinterpret_cast<const float4*>(&edata[i]);
        ushort4 w0 = *reinterpret_cast<const ushort4*>(lin + (size_t)__float_as_int(e01.x) * FH + lane * 4);
        ushort4 w1 = *reinterpret_cast<const ushort4*>(lin + (size_t)__float_as_int(e01.z) * FH + lane * 4);
        a0.x += bf2f(w0.x) * e01.y; a0.y += bf2f(w0.y) * e01.y;
        a0.z += bf2f(w0.z) * e01.y; a0.w += bf2f(w0.w) * e01.y;
        a1.x += bf2f(w1.x) * e01.w; a1.y += bf2f(w1.y) * e01.w;
        a1.z += bf2f(w1.z) * e01.w; a1.w += bf2f(w1.w) * e01.w;
    }
    if (i < end) {
        float2 ed = edata[i];
        float cf = ed.y;
        ushort4 wv = *reinterpret_cast<const ushort4*>(lin + (size_t)__float_as_int(ed.x) * FH + lane * 4);
        a0.x += bf2f(wv.x) * cf; a0.y += bf2f(wv.y) * cf;
        a0.z += bf2f(wv.z) * cf; a0.w += bf2f(wv.w) * cf;
    }

    float4 acc = make_float4(a0.x + a1.x + a2.x + a3.x,
                             a0.y + a1.y + a2.y + a3.y,
                             a0.z + a1.z + a2.z + a3.z,
                             a0.w + a1.w + a2.w + a3.w);

    float r0 = fmaxf(acc.x, 0.f), r1 = fmaxf(acc.y, 0.f);
    float r2 = fmaxf(acc.z, 0.f), r3 = fmaxf(acc.w, 0.f);
    *reinterpret_cast<ushort4*>(outB + (size_t)node * FH + lane * 4) =
        make_ushort4(f2bf(r0), f2bf(r1), f2bf(r2), f2bf(r3));
}

// ---------------- collapsed layer 2 + mean pool: v[f] = sum_n w_n * a1[n][f] ----------------

__global__ __launch_bounds__(256) void colsumw_kernel(const ushort* __restrict__ a1,
                                                      const float* __restrict__ wsum,
                                                      const float* __restrict__ inv,
                                                      float* __restrict__ v) {
    __shared__ float sh[4][256];
    int wid  = threadIdx.x >> 6;
    int lane = threadIdx.x & 63;
    int r0 = blockIdx.x * 256;
    int r1 = r0 + 256; if (r1 > NN) r1 = NN;

    float4 acc = make_float4(0.f, 0.f, 0.f, 0.f);
    for (int r = r0 + wid; r < r1; r += 4) {
        float iv = inv[r];
        float wr = wsum[r] + iv * iv;
        ushort4 u = *reinterpret_cast<const ushort4*>(a1 + (size_t)r * FH + lane * 4);
        acc.x += bf2f(u.x) * wr;
        acc.y += bf2f(u.y) * wr;
        acc.z += bf2f(u.z) * wr;
        acc.w += bf2f(u.w) * wr;
    }
    *reinterpret_cast<float4*>(&sh[wid][lane * 4]) = acc;
    __syncthreads();
    if (wid == 0) {
        float4 s1 = *reinterpret_cast<const float4*>(&sh[1][lane * 4]);
        float4 s2 = *reinterpret_cast<const float4*>(&sh[2][lane * 4]);
        float4 s3 = *reinterpret_cast<const float4*>(&sh[3][lane * 4]);
        unsafeAtomicAdd(&v[lane * 4 + 0], acc.x + s1.x + s2.x + s3.x);
        unsafeAtomicAdd(&v[lane * 4 + 1], acc.y + s1.y + s2.y + s3.y);
        unsafeAtomicAdd(&v[lane * 4 + 2], acc.z + s1.z + s2.z + s3.z);
        unsafeAtomicAdd(&v[lane * 4 + 3], acc.w + s1.w + s2.w + s3.w);
    }
}

// out = ((v/NN) @ W2 + b2) @ Wh + bh
__global__ __launch_bounds__(256) void head2_kernel(const float* __restrict__ v,
                                                    const float* __restrict__ W2,
                                                    const float* __restrict__ b2,
                                                    const float* __restrict__ Wh,
                                                    const float* __restrict__ bh,
                                                    float* __restrict__ out) {
    __shared__ float m[FH];
    int t = threadIdx.x;
    const float scale = 1.0f / (float)NN;
    float s = 0.0f;
    for (int f = 0; f < FH; ++f)
        s += v[f] * W2[f * FH + t];
    m[t] = s * scale + b2[t];
    __syncthreads();
    if (t < FOUT) {
        float o = 0.0f;
        for (int f = 0; f < FH; ++f)
            o += m[f] * Wh[f * FOUT + t];
        out[t] = o + bh[t];
    }
}

// ---------------- launch ----------------

extern "C" void kernel_launch(void* const* d_in, const int* in_sizes, int n_in,
                              void* d_out, int out_size, void* d_ws, size_t ws_size,
                              hipStream_t stream) {
    const float* x   = (const float*)d_in[0];
    const int*   ei  = (const int*)d_in[1];
    const float* W0  = (const float*)d_in[2];
    const float* b0  = (const float*)d_in[3];
    const float* W1  = (const float*)d_in[4];
    const float* b1  = (const float*)d_in[5];
    const float* W2  = (const float*)d_in[6];
    const float* b2  = (const float*)d_in[7];
    const float* Wh  = (const float*)d_in[8];
    const float* bh  = (const float*)d_in[9];
    float* out = (float*)d_out;

    const int* src = ei;        // edge_index[0,:]
    const int* dst = ei + NE;   // edge_index[1,:]

    // workspace layout (16B-aligned blocks)
    float*    inv       = (float*)d_ws;                 // NPAD
    int*      row_start = (int*)(inv + NPAD);           // NPAD (NN+1 used)
    float*    wsum      = (float*)(row_start + NPAD);   // NPAD
    int*      bcnt      = (int*)(wsum + NPAD);          // 256
    int*      bbase     = bcnt + 256;                   // 320 (257 used)
    int*      bcur      = bbase + 320;                  // 256
    float*    vbuf      = (float*)(bcur + 256);         // 256
    unsigned* inter     = (unsigned*)(vbuf + 256);      // NE u32 (3.2 MB)
    float2*   edata     = (float2*)(inter + NE);        // NE float2 (6.4 MB)
    ushort*   W0tH      = (ushort*)(edata + NE);        // [256][128]
    ushort*   W0tL      = W0tH + 256 * 128;
    ushort*   W1tH      = W0tL + 256 * 128;             // [256][256]
    // aggx split planes (25.6 MB) -> later reused as linb (bf16 lin1)
    ushort*   aggxH     = W1tH + 256 * 256;             // [NN2][128]
    ushort*   aggxL     = aggxH + (size_t)NN2 * 128;
    ushort*   linb      = aggxH;                        // [NN2][256] bf16 (aggx dead)
    // h0 plane (25.6 MB) -> later reused as a1 plane
    ushort*   h0H       = aggxL + (size_t)NN2 * 128;    // [NN2][256]
    ushort*   a1H       = h0H;                          // (h0 dead after GEMM1)

    const dim3 gemm_grid((NN + 127) / 128, 2);
    const int nblk_g = (NN + 3) / 4;

    // ---- edge sort + CSR build ----
    hipMemsetAsync(bcnt, 0, NB * sizeof(int), stream);
    bucket_cnt_kernel<<<NBLK_A, 256, 0, stream>>>(dst, bcnt);
    bucket_scan_kernel<<<1, 256, 0, stream>>>(bcnt, bbase, bcur, vbuf);
    binA_kernel<<<NBLK_A, 256, 0, stream>>>(src, dst, bcur, inter);
    binB1_kernel<<<NB, 256, 0, stream>>>(inter, bbase, row_start, inv, wsum);
    binB2_kernel<<<NB, 256, 0, stream>>>(inter, bbase, row_start, inv, edata, wsum);
    wsplit_kernel<<<(FIN * FH + 255) / 256, 256, 0, stream>>>(W0, FIN, FH, W0tH, W0tL);
    wsplit_kernel<<<(FH * FH + 255) / 256, 256, 0, stream>>>(W1, FH, FH, W1tH, nullptr);

    // layer 0: aggx = agg(x) [split]; h0 = bf16(relu(aggx @ W0 + b0))   (3-term, fp32-accurate)
    gather_x_kernel<<<nblk_g, 256, 0, stream>>>(x, edata, row_start, inv, aggxH, aggxL);
    gemm_mfma_kernel<3, true><<<gemm_grid, 256, 0, stream>>>(aggxH, aggxL, W0tH, W0tL, b0,
                                                             h0H, NN, FIN);

    // layer 1: lin1 = bf16(h0 @ W1); a1 = bf16(relu(agg(lin1) + b1))
    gemm_mfma_kernel<1, false><<<gemm_grid, 256, 0, stream>>>(h0H, nullptr, W1tH, nullptr, nullptr,
                                                              linb, NN, FH);
    gather_bf_kernel<<<nblk_g, 256, 0, stream>>>(linb, edata, row_start, inv, b1, a1H);

    // collapsed layer 2 + mean pool + head
    colsumw_kernel<<<NBLK_S, 256, 0, stream>>>(a1H, wsum, inv, vbuf);
    head2_kernel<<<1, 256, 0, stream>>>(vbuf, W2, b2, Wh, bh, out);
}

// Round 11
// 300.621 us; speedup vs baseline: 3.0127x; 1.0475x over previous
//
#include <hip/hip_runtime.h>

#define NN 50000
#define NE 800000
#define FIN 128
#define FH 256
#define FOUT 40
#define NPAD 50432   // > NN+1, multiple of 64
#define NN2 50048    // NN rounded up to 128
#define NB 256       // dst buckets for the edge sort
#define BSPAN 196    // ceil(NN/NB)
#define EBLK 4096    // edges per binA block
#define NBLK_A 196   // ceil(NE/EBLK)
#define NBLK_S 196   // colsumw grid

typedef float f32x4 __attribute__((ext_vector_type(4)));
typedef short bf16x8 __attribute__((ext_vector_type(8)));

__device__ __forceinline__ ushort f2bf(float f) {
    unsigned u = __float_as_uint(f);
    unsigned r = (u + 0x7FFFu + ((u >> 16) & 1u)) >> 16;   // RNE
    return (ushort)r;
}
__device__ __forceinline__ float bf2f(ushort b) {
    return __uint_as_float(((unsigned)b) << 16);
}

// ---------------- edge sort + CSR build ----------------

__global__ __launch_bounds__(256) void bucket_cnt_kernel(const int* __restrict__ dst,
                                                         int* __restrict__ bcnt) {
    __shared__ int h[NB];
    const int t = threadIdx.x;
    h[t] = 0;
    __syncthreads();
    const int e0 = blockIdx.x * EBLK;
    const int n  = min(EBLK, NE - e0);
    for (int i = t; i < n; i += 256)
        atomicAdd(&h[dst[e0 + i] / BSPAN], 1);
    __syncthreads();
    if (h[t] > 0) atomicAdd(&bcnt[t], h[t]);
}

__global__ __launch_bounds__(256) void bucket_scan_kernel(const int* __restrict__ bcnt,
                                                          int* __restrict__ bbase,
                                                          int* __restrict__ bcur,
                                                          float* __restrict__ vbuf) {
    __shared__ int sh[256];
    int t = threadIdx.x;
    int v = bcnt[t];
    sh[t] = v;
    __syncthreads();
    #pragma unroll
    for (int off = 1; off < 256; off <<= 1) {
        int u = (t >= off) ? sh[t - off] : 0;
        __syncthreads();
        sh[t] += u;
        __syncthreads();
    }
    int excl = sh[t] - v;
    bbase[t] = excl;
    bcur[t]  = excl;
    if (t == 255) bbase[256] = sh[255];   // == NE
    vbuf[t] = 0.0f;
}

__global__ __launch_bounds__(256) void binA_kernel(const int* __restrict__ src,
                                                   const int* __restrict__ dst,
                                                   int* __restrict__ bcur,
                                                   unsigned* __restrict__ inter) {
    __shared__ int hcnt[NB];
    __shared__ int hoff[NB];
    __shared__ int lcur[NB];
    __shared__ int gbase[NB];
    __shared__ unsigned stage[EBLK];   // 16 KB

    const int t  = threadIdx.x;
    const int e0 = blockIdx.x * EBLK;
    const int n  = min(EBLK, NE - e0);

    hcnt[t] = 0;
    __syncthreads();
    for (int i = t; i < n; i += 256)
        atomicAdd(&hcnt[dst[e0 + i] / BSPAN], 1);
    __syncthreads();
    int v = hcnt[t];
    hoff[t] = v;
    __syncthreads();
    #pragma unroll
    for (int off = 1; off < NB; off <<= 1) {
        int u = (t >= off) ? hoff[t - off] : 0;
        __syncthreads();
        hoff[t] += u;
        __syncthreads();
    }
    int excl = hoff[t] - v;
    __syncthreads();
    hoff[t] = excl;
    lcur[t] = excl;
    if (v > 0) gbase[t] = atomicAdd(&bcur[t], v);
    __syncthreads();
    for (int i = t; i < n; i += 256) {
        int d = dst[e0 + i];
        int s = src[e0 + i];
        int b = d / BSPAN;
        int idx = atomicAdd(&lcur[b], 1);
        stage[idx] = ((unsigned)d << 16) | (unsigned)s;   // both < 65536
    }
    __syncthreads();
    for (int i = t; i < n; i += 256) {
        unsigned rec = stage[i];
        int b = (int)(rec >> 16) / BSPAN;
        inter[gbase[b] + (i - hoff[b])] = rec;
    }
}

__global__ __launch_bounds__(256) void binB1_kernel(const unsigned* __restrict__ inter,
                                                    const int* __restrict__ bbase,
                                                    int* __restrict__ row_start,
                                                    float* __restrict__ inv,
                                                    float* __restrict__ wsum) {
    __shared__ int lcnt[BSPAN];
    __shared__ int sh[256];
    const int b   = blockIdx.x;
    const int nlo = b * BSPAN;
    const int nhi = min(nlo + BSPAN, NN);
    const int nn  = nhi - nlo;
    const int base = bbase[b];
    const int cnt  = bbase[b + 1] - base;
    const int t = threadIdx.x;

    for (int i = t; i < nn; i += 256) lcnt[i] = 0;
    __syncthreads();
    for (int i = t; i < cnt; i += 256)
        atomicAdd(&lcnt[(int)(inter[base + i] >> 16) - nlo], 1);
    __syncthreads();
    int c = (t < nn) ? lcnt[t] : 0;
    sh[t] = c;
    __syncthreads();
    #pragma unroll
    for (int off = 1; off < 256; off <<= 1) {
        int u = (t >= off) ? sh[t - off] : 0;
        __syncthreads();
        sh[t] += u;
        __syncthreads();
    }
    if (t < nn) {
        row_start[nlo + t] = base + sh[t] - c;
        inv[nlo + t]  = rsqrtf((float)(c + 1));
        wsum[nlo + t] = 0.0f;
    }
    if (b == NB - 1 && t == 0) row_start[NN] = NE;
}

__global__ __launch_bounds__(256) void binB2_kernel(const unsigned* __restrict__ inter,
                                                    const int* __restrict__ bbase,
                                                    const int* __restrict__ row_start,
                                                    const float* __restrict__ inv,
                                                    float2* __restrict__ edata,
                                                    float* __restrict__ wsum) {
    __shared__ int lcur[BSPAN];
    const int b   = blockIdx.x;
    const int nlo = b * BSPAN;
    const int nhi = min(nlo + BSPAN, NN);
    const int nn  = nhi - nlo;
    const int base = bbase[b];
    const int cnt  = bbase[b + 1] - base;
    const int t = threadIdx.x;

    for (int i = t; i < nn; i += 256) lcur[i] = row_start[nlo + i];
    __syncthreads();
    for (int i = t; i < cnt; i += 256) {
        unsigned rec = inter[base + i];
        int d = (int)(rec >> 16);
        int s = (int)(rec & 0xFFFFu);
        float coef = inv[s] * inv[d];
        int pos = atomicAdd(&lcur[d - nlo], 1);
        edata[pos] = make_float2(__int_as_float(s), coef);
        unsafeAtomicAdd(&wsum[s], coef);
    }
}

// ---------------- weight split (fused W0 split + W1 hi) ----------------

__global__ void wsplit_all_kernel(const float* __restrict__ W0, const float* __restrict__ W1,
                                  ushort* __restrict__ W0tH, ushort* __restrict__ W0tL,
                                  ushort* __restrict__ W1tH) {
    int idx = blockIdx.x * 256 + threadIdx.x;
    if (idx < FIN * FH) {
        int n = idx % FH;
        int k = idx / FH;
        float f = W0[idx];
        ushort h = f2bf(f);
        W0tH[n * FIN + k] = h;
        W0tL[n * FIN + k] = f2bf(f - bf2f(h));
    }
    int j = idx - FIN * FH;
    if (j >= 0 && j < FH * FH) {
        int n = j % FH;
        int k = j / FH;
        W1tH[n * FH + k] = f2bf(W1[j]);
    }
}

// ---------------- x -> bf16 plane (zero-padded to NN2 rows) ----------------

__global__ void xcvt_kernel(const float* __restrict__ x, ushort* __restrict__ xb) {
    int t = blockIdx.x * 256 + threadIdx.x;   // over NN2*32 ushort4 groups
    if (t >= NN2 * 32) return;
    int row = t >> 5;
    int c4  = t & 31;
    ushort4 o = make_ushort4(0, 0, 0, 0);
    if (row < NN) {
        float4 v = *reinterpret_cast<const float4*>(x + (size_t)row * FIN + c4 * 4);
        o = make_ushort4(f2bf(v.x), f2bf(v.y), f2bf(v.z), f2bf(v.w));
    }
    *reinterpret_cast<ushort4*>(xb + (size_t)row * FIN + c4 * 4) = o;
}

// ---------------- MFMA GEMM: out_bf16[NN2][256] = A @ Bt^T, BN=256 single col-block ----------------
// 128x256 tile, 4 waves (2x2), each wave 64x128 via 4x8 frags of 16x16x32. No M guards
// (grid covers exactly NN2 rows; all A buffers are NN2-row workspace, fully initialized).

template<int TERMS, bool BIAS_RELU>
__global__ __launch_bounds__(256) void gemm_mfma_kernel(
    const ushort* __restrict__ AH, const ushort* __restrict__ AL,
    const ushort* __restrict__ BH, const ushort* __restrict__ BL,
    const float* __restrict__ bias,
    ushort* __restrict__ outB,
    int K) {
    constexpr int NARR = (TERMS == 3) ? 2 : 1;
    __shared__ ushort smem[(128 + 256) * 40 * NARR];
    ushort* Ah = smem;
    ushort* Bh = smem + 128 * 40;
    ushort* Al = (TERMS == 3) ? smem + 384 * 40 : nullptr;
    ushort* Bl = (TERMS == 3) ? smem + 384 * 40 + 128 * 40 : nullptr;

    const int tid  = threadIdx.x;
    const int lane = tid & 63;
    const int w    = tid >> 6;
    const int wr   = w >> 1;          // row half
    const int wc   = w & 1;           // col half
    const int row0 = blockIdx.x * 128;

    f32x4 acc[4][8] = {};

    for (int k0 = 0; k0 < K; k0 += 32) {
        #pragma unroll
        for (int i = 0; i < 2; ++i) {          // A: 128 rows x 32 k
            int c  = i * 256 + tid;
            int r  = c >> 2;
            int cb = c & 3;
            *reinterpret_cast<uint4*>(&Ah[r * 40 + cb * 8]) =
                *reinterpret_cast<const uint4*>(AH + (size_t)(row0 + r) * K + k0 + cb * 8);
            if (TERMS == 3)
                *reinterpret_cast<uint4*>(&Al[r * 40 + cb * 8]) =
                    *reinterpret_cast<const uint4*>(AL + (size_t)(row0 + r) * K + k0 + cb * 8);
        }
        #pragma unroll
        for (int i = 0; i < 4; ++i) {          // B: 256 rows x 32 k
            int c  = i * 256 + tid;
            int r  = c >> 2;
            int cb = c & 3;
            *reinterpret_cast<uint4*>(&Bh[r * 40 + cb * 8]) =
                *reinterpret_cast<const uint4*>(BH + (size_t)r * K + k0 + cb * 8);
            if (TERMS == 3)
                *reinterpret_cast<uint4*>(&Bl[r * 40 + cb * 8]) =
                    *reinterpret_cast<const uint4*>(BL + (size_t)r * K + k0 + cb * 8);
        }
        __syncthreads();

        const int rsel = lane & 15;
        const int ksel = (lane >> 4) * 8;
        bf16x8 ah[4], bh[8];
        #pragma unroll
        for (int m = 0; m < 4; ++m)
            ah[m] = *reinterpret_cast<const bf16x8*>(&Ah[(wr * 64 + m * 16 + rsel) * 40 + ksel]);
        #pragma unroll
        for (int n = 0; n < 8; ++n)
            bh[n] = *reinterpret_cast<const bf16x8*>(&Bh[(wc * 128 + n * 16 + rsel) * 40 + ksel]);

        if (TERMS == 3) {
            bf16x8 al[4], bl[8];
            #pragma unroll
            for (int m = 0; m < 4; ++m)
                al[m] = *reinterpret_cast<const bf16x8*>(&Al[(wr * 64 + m * 16 + rsel) * 40 + ksel]);
            #pragma unroll
            for (int n = 0; n < 8; ++n)
                bl[n] = *reinterpret_cast<const bf16x8*>(&Bl[(wc * 128 + n * 16 + rsel) * 40 + ksel]);
            #pragma unroll
            for (int m = 0; m < 4; ++m)
                #pragma unroll
                for (int n = 0; n < 8; ++n) {
                    acc[m][n] = __builtin_amdgcn_mfma_f32_16x16x32_bf16(ah[m], bh[n], acc[m][n], 0, 0, 0);
                    acc[m][n] = __builtin_amdgcn_mfma_f32_16x16x32_bf16(ah[m], bl[n], acc[m][n], 0, 0, 0);
                    acc[m][n] = __builtin_amdgcn_mfma_f32_16x16x32_bf16(al[m], bh[n], acc[m][n], 0, 0, 0);
                }
        } else {
            #pragma unroll
            for (int m = 0; m < 4; ++m)
                #pragma unroll
                for (int n = 0; n < 8; ++n)
                    acc[m][n] = __builtin_amdgcn_mfma_f32_16x16x32_bf16(ah[m], bh[n], acc[m][n], 0, 0, 0);
        }
        __syncthreads();
    }

    // epilogue: C/D layout col=lane&15, row=4*(lane>>4)+i
    const int cl = lane & 15;
    const int rg = lane >> 4;
    float bn[8];
    if (BIAS_RELU) {
        #pragma unroll
        for (int n = 0; n < 8; ++n) bn[n] = bias[wc * 128 + n * 16 + cl];
    }
    #pragma unroll
    for (int m = 0; m < 4; ++m) {
        #pragma unroll
        for (int i = 0; i < 4; ++i) {
            int gr = row0 + wr * 64 + m * 16 + rg * 4 + i;
            #pragma unroll
            for (int n = 0; n < 8; ++n) {
                int gc = wc * 128 + n * 16 + cl;
                float o = acc[m][n][i];
                if (BIAS_RELU) o = fmaxf(o + bn[n], 0.0f);
                outB[(size_t)gr * FH + gc] = f2bf(o);
            }
        }
    }
}

// ---------------- gather_x (FIN=128): bf16 in, fp32 acc, split-bf16 out; zero-pads to NN2 ----------------

__global__ __launch_bounds__(256) void gather_x_kernel(const ushort* __restrict__ xb,
                                                       const float2* __restrict__ edata,
                                                       const int* __restrict__ row_start,
                                                       const float* __restrict__ inv,
                                                       ushort* __restrict__ outH,
                                                       ushort* __restrict__ outL) {
    int node = blockIdx.x * 4 + (threadIdx.x >> 6);
    int lane = threadIdx.x & 63;
    if (node >= NN2) return;
    size_t o = (size_t)node * FIN + lane * 2;
    if (node >= NN) {   // zero-pad tail rows for the guard-free GEMM0
        *reinterpret_cast<ushort2*>(outH + o) = make_ushort2(0, 0);
        *reinterpret_cast<ushort2*>(outL + o) = make_ushort2(0, 0);
        return;
    }

    int beg = row_start[node];
    int end = row_start[node + 1];

    float iv = inv[node];
    float c  = iv * iv;
    ushort2 sv = *reinterpret_cast<const ushort2*>(xb + o);
    float2 a0 = make_float2(bf2f(sv.x) * c, bf2f(sv.y) * c);
    float2 a1 = make_float2(0.f, 0.f);
    float2 a2 = make_float2(0.f, 0.f);
    float2 a3 = make_float2(0.f, 0.f);

    int i = beg;
    if ((i & 1) && i < end) {
        float2 ed = edata[i];
        ushort2 u = *reinterpret_cast<const ushort2*>(xb + (size_t)__float_as_int(ed.x) * FIN + lane * 2);
        a0.x += bf2f(u.x) * ed.y; a0.y += bf2f(u.y) * ed.y;
        ++i;
    }
    for (; i + 8 <= end; i += 8) {
        float4 e01 = *reinterpret_cast<const float4*>(&edata[i]);
        float4 e23 = *reinterpret_cast<const float4*>(&edata[i + 2]);
        float4 e45 = *reinterpret_cast<const float4*>(&edata[i + 4]);
        float4 e67 = *reinterpret_cast<const float4*>(&edata[i + 6]);
        ushort2 u0 = *reinterpret_cast<const ushort2*>(xb + (size_t)__float_as_int(e01.x) * FIN + lane * 2);
        ushort2 u1 = *reinterpret_cast<const ushort2*>(xb + (size_t)__float_as_int(e01.z) * FIN + lane * 2);
        ushort2 u2 = *reinterpret_cast<const ushort2*>(xb + (size_t)__float_as_int(e23.x) * FIN + lane * 2);
        ushort2 u3 = *reinterpret_cast<const ushort2*>(xb + (size_t)__float_as_int(e23.z) * FIN + lane * 2);
        ushort2 u4 = *reinterpret_cast<const ushort2*>(xb + (size_t)__float_as_int(e45.x) * FIN + lane * 2);
        ushort2 u5 = *reinterpret_cast<const ushort2*>(xb + (size_t)__float_as_int(e45.z) * FIN + lane * 2);
        ushort2 u6 = *reinterpret_cast<const ushort2*>(xb + (size_t)__float_as_int(e67.x) * FIN + lane * 2);
        ushort2 u7 = *reinterpret_cast<const ushort2*>(xb + (size_t)__float_as_int(e67.z) * FIN + lane * 2);
        a0.x += bf2f(u0.x) * e01.y; a0.y += bf2f(u0.y) * e01.y;
        a1.x += bf2f(u1.x) * e01.w; a1.y += bf2f(u1.y) * e01.w;
        a2.x += bf2f(u2.x) * e23.y; a2.y += bf2f(u2.y) * e23.y;
        a3.x += bf2f(u3.x) * e23.w; a3.y += bf2f(u3.y) * e23.w;
        a0.x += bf2f(u4.x) * e45.y; a0.y += bf2f(u4.y) * e45.y;
        a1.x += bf2f(u5.x) * e45.w; a1.y += bf2f(u5.y) * e45.w;
        a2.x += bf2f(u6.x) * e67.y; a2.y += bf2f(u6.y) * e67.y;
        a3.x += bf2f(u7.x) * e67.w; a3.y += bf2f(u7.y) * e67.w;
    }
    for (; i + 2 <= end; i += 2) {
        float4 e01 = *reinterpret_cast<const float4*>(&edata[i]);
        ushort2 u0 = *reinterpret_cast<const ushort2*>(xb + (size_t)__float_as_int(e01.x) * FIN + lane * 2);
        ushort2 u1 = *reinterpret_cast<const ushort2*>(xb + (size_t)__float_as_int(e01.z) * FIN + lane * 2);
        a0.x += bf2f(u0.x) * e01.y; a0.y += bf2f(u0.y) * e01.y;
        a1.x += bf2f(u1.x) * e01.w; a1.y += bf2f(u1.y) * e01.w;
    }
    if (i < end) {
        float2 ed = edata[i];
        ushort2 u = *reinterpret_cast<const ushort2*>(xb + (size_t)__float_as_int(ed.x) * FIN + lane * 2);
        a0.x += bf2f(u.x) * ed.y; a0.y += bf2f(u.y) * ed.y;
    }

    float ax = a0.x + a1.x + a2.x + a3.x;
    float ay = a0.y + a1.y + a2.y + a3.y;
    ushort h0 = f2bf(ax), h1 = f2bf(ay);
    ushort l0 = f2bf(ax - bf2f(h0)), l1 = f2bf(ay - bf2f(h1));
    *reinterpret_cast<ushort2*>(outH + o) = make_ushort2(h0, h1);
    *reinterpret_cast<ushort2*>(outL + o) = make_ushort2(l0, l1);
}

// ---------------- gather (FH=256): bf16 in, fp32 accumulate; bf16 relu out ----------------

__global__ __launch_bounds__(256) void gather_bf_kernel(const ushort* __restrict__ lin,
                                                        const float2* __restrict__ edata,
                                                        const int* __restrict__ row_start,
                                                        const float* __restrict__ inv,
                                                        const float* __restrict__ bias,
                                                        ushort* __restrict__ outB) {
    int node = blockIdx.x * 4 + (threadIdx.x >> 6);
    int lane = threadIdx.x & 63;
    if (node >= NN) return;

    int beg = row_start[node];
    int end = row_start[node + 1];

    float iv = inv[node];
    float c  = iv * iv;
    ushort4 sv = *reinterpret_cast<const ushort4*>(lin + (size_t)node * FH + lane * 4);
    float4 b = *reinterpret_cast<const float4*>(bias + lane * 4);
    float4 a0 = make_float4(bf2f(sv.x) * c + b.x, bf2f(sv.y) * c + b.y,
                            bf2f(sv.z) * c + b.z, bf2f(sv.w) * c + b.w);
    float4 a1 = make_float4(0.f, 0.f, 0.f, 0.f);
    float4 a2 = make_float4(0.f, 0.f, 0.f, 0.f);
    float4 a3 = make_float4(0.f, 0.f, 0.f, 0.f);

    int i = beg;
    if ((i & 1) && i < end) {
        float2 ed = edata[i];
        float cf = ed.y;
        ushort4 wv = *reinterpret_cast<const ushort4*>(lin + (size_t)__float_as_int(ed.x) * FH + lane * 4);
        a0.x += bf2f(wv.x) * cf; a0.y += bf2f(wv.y) * cf;
        a0.z += bf2f(wv.z) * cf; a0.w += bf2f(wv.w) * cf;
        ++i;
    }
    for (; i + 8 <= end; i += 8) {
        float4 e01 = *reinterpret_cast<const float4*>(&edata[i]);
        float4 e23 = *reinterpret_cast<const float4*>(&edata[i + 2]);
        float4 e45 = *reinterpret_cast<const float4*>(&edata[i + 4]);
        float4 e67 = *reinterpret_cast<const float4*>(&edata[i + 6]);
        ushort4 w0 = *reinterpret_cast<const ushort4*>(lin + (size_t)__float_as_int(e01.x) * FH + lane * 4);
        ushort4 w1 = *reinterpret_cast<const ushort4*>(lin + (size_t)__float_as_int(e01.z) * FH + lane * 4);
        ushort4 w2 = *reinterpret_cast<const ushort4*>(lin + (size_t)__float_as_int(e23.x) * FH + lane * 4);
        ushort4 w3 = *reinterpret_cast<const ushort4*>(lin + (size_t)__float_as_int(e23.z) * FH + lane * 4);
        ushort4 w4 = *reinterpret_cast<const ushort4*>(lin + (size_t)__float_as_int(e45.x) * FH + lane * 4);
        ushort4 w5 = *reinterpret_cast<const ushort4*>(lin + (size_t)__float_as_int(e45.z) * FH + lane * 4);
        ushort4 w6 = *reinterpret_cast<const ushort4*>(lin + (size_t)__float_as_int(e67.x) * FH + lane * 4);
        ushort4 w7 = *reinterpret_cast<const ushort4*>(lin + (size_t)__float_as_int(e67.z) * FH + lane * 4);
        a0.x += bf2f(w0.x) * e01.y; a0.y += bf2f(w0.y) * e01.y;
        a0.z += bf2f(w0.z) * e01.y; a0.w += bf2f(w0.w) * e01.y;
        a1.x += bf2f(w1.x) * e01.w; a1.y += bf2f(w1.y) * e01.w;
        a1.z += bf2f(w1.z) * e01.w; a1.w += bf2f(w1.w) * e01.w;
        a2.x += bf2f(w2.x) * e23.y; a2.y += bf2f(w2.y) * e23.y;
        a2.z += bf2f(w2.z) * e23.y; a2.w += bf2f(w2.w) * e23.y;
        a3.x += bf2f(w3.x) * e23.w; a3.y += bf2f(w3.y) * e23.w;
        a3.z += bf2f(w3.z) * e23.w; a3.w += bf2f(w3.w) * e23.w;
        a0.x += bf2f(w4.x) * e45.y; a0.y += bf2f(w4.y) * e45.y;
        a0.z += bf2f(w4.z) * e45.y; a0.w += bf2f(w4.w) * e45.y;
        a1.x += bf2f(w5.x) * e45.w; a1.y += bf2f(w5.y) * e45.w;
        a1.z += bf2f(w5.z) * e45.w; a1.w += bf2f(w5.w) * e45.w;
        a2.x += bf2f(w6.x) * e67.y; a2.y += bf2f(w6.y) * e67.y;
        a2.z += bf2f(w6.z) * e67.y; a2.w += bf2f(w6.w) * e67.y;
        a3.x += bf2f(w7.x) * e67.w; a3.y += bf2f(w7.y) * e67.w;
        a3.z += bf2f(w7.z) * e67.w; a3.w += bf2f(w7.w) * e67.w;
    }
    for (; i + 2 <= end; i += 2) {
        float4 e01 = *reinterpret_cast<const float4*>(&edata[i]);
        ushort4 w0 = *reinterpret_cast<const ushort4*>(lin + (size_t)__float_as_int(e01.x) * FH + lane * 4);
        ushort4 w1 = *reinterpret_cast<const ushort4*>(lin + (size_t)__float_as_int(e01.z) * FH + lane * 4);
        a0.x += bf2f(w0.x) * e01.y; a0.y += bf2f(w0.y) * e01.y;
        a0.z += bf2f(w0.z) * e01.y; a0.w += bf2f(w0.w) * e01.y;
        a1.x += bf2f(w1.x) * e01.w; a1.y += bf2f(w1.y) * e01.w;
        a1.z += bf2f(w1.z) * e01.w; a1.w += bf2f(w1.w) * e01.w;
    }
    if (i < end) {
        float2 ed = edata[i];
        float cf = ed.y;
        ushort4 wv = *reinterpret_cast<const ushort4*>(lin + (size_t)__float_as_int(ed.x) * FH + lane * 4);
        a0.x += bf2f(wv.x) * cf; a0.y += bf2f(wv.y) * cf;
        a0.z += bf2f(wv.z) * cf; a0.w += bf2f(wv.w) * cf;
    }

    float4 acc = make_float4(a0.x + a1.x + a2.x + a3.x,
                             a0.y + a1.y + a2.y + a3.y,
                             a0.z + a1.z + a2.z + a3.z,
                             a0.w + a1.w + a2.w + a3.w);

    float r0 = fmaxf(acc.x, 0.f), r1 = fmaxf(acc.y, 0.f);
    float r2 = fmaxf(acc.z, 0.f), r3 = fmaxf(acc.w, 0.f);
    *reinterpret_cast<ushort4*>(outB + (size_t)node * FH + lane * 4) =
        make_ushort4(f2bf(r0), f2bf(r1), f2bf(r2), f2bf(r3));
}

// ---------------- collapsed layer 2 + mean pool ----------------

__global__ __launch_bounds__(256) void colsumw_kernel(const ushort* __restrict__ a1,
                                                      const float* __restrict__ wsum,
                                                      const float* __restrict__ inv,
                                                      float* __restrict__ v) {
    __shared__ float sh[4][256];
    int wid  = threadIdx.x >> 6;
    int lane = threadIdx.x & 63;
    int r0 = blockIdx.x * 256;
    int r1 = r0 + 256; if (r1 > NN) r1 = NN;

    float4 acc = make_float4(0.f, 0.f, 0.f, 0.f);
    for (int r = r0 + wid; r < r1; r += 4) {
        float iv = inv[r];
        float wr = wsum[r] + iv * iv;
        ushort4 u = *reinterpret_cast<const ushort4*>(a1 + (size_t)r * FH + lane * 4);
        acc.x += bf2f(u.x) * wr;
        acc.y += bf2f(u.y) * wr;
        acc.z += bf2f(u.z) * wr;
        acc.w += bf2f(u.w) * wr;
    }
    *reinterpret_cast<float4*>(&sh[wid][lane * 4]) = acc;
    __syncthreads();
    if (wid == 0) {
        float4 s1 = *reinterpret_cast<const float4*>(&sh[1][lane * 4]);
        float4 s2 = *reinterpret_cast<const float4*>(&sh[2][lane * 4]);
        float4 s3 = *reinterpret_cast<const float4*>(&sh[3][lane * 4]);
        unsafeAtomicAdd(&v[lane * 4 + 0], acc.x + s1.x + s2.x + s3.x);
        unsafeAtomicAdd(&v[lane * 4 + 1], acc.y + s1.y + s2.y + s3.y);
        unsafeAtomicAdd(&v[lane * 4 + 2], acc.z + s1.z + s2.z + s3.z);
        unsafeAtomicAdd(&v[lane * 4 + 3], acc.w + s1.w + s2.w + s3.w);
    }
}

__global__ __launch_bounds__(256) void head2_kernel(const float* __restrict__ v,
                                                    const float* __restrict__ W2,
                                                    const float* __restrict__ b2,
                                                    const float* __restrict__ Wh,
                                                    const float* __restrict__ bh,
                                                    float* __restrict__ out) {
    __shared__ float m[FH];
    int t = threadIdx.x;
    const float scale = 1.0f / (float)NN;
    float s = 0.0f;
    for (int f = 0; f < FH; ++f)
        s += v[f] * W2[f * FH + t];
    m[t] = s * scale + b2[t];
    __syncthreads();
    if (t < FOUT) {
        float o = 0.0f;
        for (int f = 0; f < FH; ++f)
            o += m[f] * Wh[f * FOUT + t];
        out[t] = o + bh[t];
    }
}

// ---------------- launch ----------------

extern "C" void kernel_launch(void* const* d_in, const int* in_sizes, int n_in,
                              void* d_out, int out_size, void* d_ws, size_t ws_size,
                              hipStream_t stream) {
    const float* x   = (const float*)d_in[0];
    const int*   ei  = (const int*)d_in[1];
    const float* W0  = (const float*)d_in[2];
    const float* b0  = (const float*)d_in[3];
    const float* W1  = (const float*)d_in[4];
    const float* b1  = (const float*)d_in[5];
    const float* W2  = (const float*)d_in[6];
    const float* b2  = (const float*)d_in[7];
    const float* Wh  = (const float*)d_in[8];
    const float* bh  = (const float*)d_in[9];
    float* out = (float*)d_out;

    const int* src = ei;        // edge_index[0,:]
    const int* dst = ei + NE;   // edge_index[1,:]

    // workspace layout (16B-aligned blocks)
    float*    inv       = (float*)d_ws;                 // NPAD
    int*      row_start = (int*)(inv + NPAD);           // NPAD (NN+1 used)
    float*    wsum      = (float*)(row_start + NPAD);   // NPAD
    int*      bcnt      = (int*)(wsum + NPAD);          // 256
    int*      bbase     = bcnt + 256;                   // 320 (257 used)
    int*      bcur      = bbase + 320;                  // 256
    float*    vbuf      = (float*)(bcur + 256);         // 256
    unsigned* inter     = (unsigned*)(vbuf + 256);      // NE u32 (3.2 MB)
    float2*   edata     = (float2*)(inter + NE);        // NE float2 (6.4 MB)
    ushort*   W0tH      = (ushort*)(edata + NE);        // [256][128]
    ushort*   W0tL      = W0tH + 256 * 128;
    ushort*   W1tH      = W0tL + 256 * 128;             // [256][256]
    ushort*   xb        = W1tH + 256 * 256;             // [NN2][128] bf16 (12.8 MB)
    // aggx split planes (25.6 MB) -> later reused as linb (bf16 lin1)
    ushort*   aggxH     = xb + (size_t)NN2 * 128;       // [NN2][128]
    ushort*   aggxL     = aggxH + (size_t)NN2 * 128;
    ushort*   linb      = aggxH;                        // [NN2][256] bf16 (aggx dead)
    // h0 plane (25.6 MB) -> later reused as a1 plane
    ushort*   h0H       = aggxL + (size_t)NN2 * 128;    // [NN2][256]
    ushort*   a1H       = h0H;                          // (h0 dead after GEMM1)

    const int gemm_grid = NN2 / 128;                    // 391
    const int nblk_gx = NN2 / 4;
    const int nblk_g  = (NN + 3) / 4;

    // ---- edge sort + CSR build + weight/x conversion ----
    hipMemsetAsync(bcnt, 0, NB * sizeof(int), stream);
    bucket_cnt_kernel<<<NBLK_A, 256, 0, stream>>>(dst, bcnt);
    bucket_scan_kernel<<<1, 256, 0, stream>>>(bcnt, bbase, bcur, vbuf);
    binA_kernel<<<NBLK_A, 256, 0, stream>>>(src, dst, bcur, inter);
    binB1_kernel<<<NB, 256, 0, stream>>>(inter, bbase, row_start, inv, wsum);
    binB2_kernel<<<NB, 256, 0, stream>>>(inter, bbase, row_start, inv, edata, wsum);
    wsplit_all_kernel<<<(FIN * FH + FH * FH + 255) / 256, 256, 0, stream>>>(W0, W1, W0tH, W0tL, W1tH);
    xcvt_kernel<<<(NN2 * 32 + 255) / 256, 256, 0, stream>>>(x, xb);

    // layer 0: aggx = agg(xb) [split]; h0 = bf16(relu(aggx @ W0 + b0))   (3-term)
    gather_x_kernel<<<nblk_gx, 256, 0, stream>>>(xb, edata, row_start, inv, aggxH, aggxL);
    gemm_mfma_kernel<3, true><<<gemm_grid, 256, 0, stream>>>(aggxH, aggxL, W0tH, W0tL, b0,
                                                             h0H, FIN);

    // layer 1: lin1 = bf16(h0 @ W1); a1 = bf16(relu(agg(lin1) + b1))
    gemm_mfma_kernel<1, false><<<gemm_grid, 256, 0, stream>>>(h0H, nullptr, W1tH, nullptr, nullptr,
                                                              linb, FH);
    gather_bf_kernel<<<nblk_g, 256, 0, stream>>>(linb, edata, row_start, inv, b1, a1H);

    // collapsed layer 2 + mean pool + head
    colsumw_kernel<<<NBLK_S, 256, 0, stream>>>(a1H, wsum, inv, vbuf);
    head2_kernel<<<1, 256, 0, stream>>>(vbuf, W2, b2, Wh, bh, out);
}